// Round 1
// baseline (2027.394 us; speedup 1.0000x reference)
//
#include <hip/hip_runtime.h>
#include <math.h>

constexpr int kC   = 192;
constexpr int kNH  = 8;
constexpr int kHC  = 64;
constexpr int kHID = 512;
constexpr int kP   = 16;
constexpr int kB   = 2;
constexpr int kH   = 128;
constexpr int kW   = 128;
constexpr int kHW  = kH * kW;      // 16384
constexpr int kN   = kB * kHW;     // 32768
constexpr float kEPS = 1e-5f;

// ---------------------------------------------------------------------------
// LayerNorm over channel dim. Input layout parameterized; output is always
// channel-major: out[c*kN + b*kHW + hw].
// ---------------------------------------------------------------------------
__global__ void ln_ch_kernel(const float* __restrict__ in, size_t inCS, size_t inBS,
                             float* __restrict__ out,
                             const float* __restrict__ g, const float* __restrict__ bb)
{
    int t = blockIdx.x * blockDim.x + threadIdx.x;
    if (t >= kB * kHW) return;
    int b = t / kHW, hw = t % kHW;
    const float* ip = in + (size_t)b * inBS + hw;
    float s = 0.f, ss = 0.f;
    for (int c = 0; c < kC; ++c) { float v = ip[(size_t)c * inCS]; s += v; ss += v * v; }
    float m  = s * (1.0f / kC);
    float var = ss * (1.0f / kC) - m * m;
    float rs = rsqrtf(var + kEPS);
    float* op = out + (size_t)b * kHW + hw;
    for (int c = 0; c < kC; ++c) {
        float v = ip[(size_t)c * inCS];
        op[(size_t)c * kN] = (v - m) * rs * g[c] + bb[c];
    }
}

// ---------------------------------------------------------------------------
// Generic fp32 GEMM: Cm[o][n] = sum_k A[o][k] * Bm[k][n] (+bias) (+x residual)
// A row-major [O][K], Bm rows have stride kN, Cm rows stride kN.
// resx (if set) is the original x with NCHW layout: x[((n>>14)*kC + o)*kHW + (n&16383)]
// ---------------------------------------------------------------------------
__global__ __launch_bounds__(256) void gemm_kernel(
    const float* __restrict__ A, const float* __restrict__ Bm,
    float* __restrict__ Cm, int K,
    const float* __restrict__ bias, const float* __restrict__ resx)
{
    __shared__ float As[16][68];
    __shared__ float Bs[16][68];
    int tid = threadIdx.x;
    int tx = tid & 15, ty = tid >> 4;
    int nBase = blockIdx.x * 64;
    int oBase = blockIdx.y * 64;
    float acc[4][4] = {};
    for (int k0 = 0; k0 < K; k0 += 16) {
        {
            int kk = tid & 15, o = tid >> 4;
#pragma unroll
            for (int m = 0; m < 4; ++m)
                As[kk][o + 16 * m] = A[(size_t)(oBase + o + 16 * m) * K + k0 + kk];
        }
        {
            int n = tid & 63, kk4 = tid >> 6;
#pragma unroll
            for (int m = 0; m < 4; ++m)
                Bs[kk4 + 4 * m][n] = Bm[(size_t)(k0 + kk4 + 4 * m) * kN + nBase + n];
        }
        __syncthreads();
#pragma unroll
        for (int kk = 0; kk < 16; ++kk) {
            float a[4], b[4];
#pragma unroll
            for (int i = 0; i < 4; ++i) a[i] = As[kk][ty + 16 * i];
#pragma unroll
            for (int j = 0; j < 4; ++j) b[j] = Bs[kk][tx + 16 * j];
#pragma unroll
            for (int i = 0; i < 4; ++i)
#pragma unroll
                for (int j = 0; j < 4; ++j)
                    acc[i][j] += a[i] * b[j];
        }
        __syncthreads();
    }
#pragma unroll
    for (int i = 0; i < 4; ++i) {
        int o = oBase + ty + 16 * i;
        float bv = bias ? bias[o] : 0.f;
#pragma unroll
        for (int j = 0; j < 4; ++j) {
            int n = nBase + tx + 16 * j;
            float v = acc[i][j] + bv;
            if (resx) v += resx[(size_t)((n >> 14) * kC + o) * kHW + (n & (kHW - 1))];
            Cm[(size_t)o * kN + n] = v;
        }
    }
}

// ---------------------------------------------------------------------------
// In-place L2 norm over the 64 head-channels of q/k. One thread per (head, n).
// ---------------------------------------------------------------------------
__global__ void l2norm_kernel(float* __restrict__ buf)
{
    int t = blockIdx.x * blockDim.x + threadIdx.x;   // over kNH*kN
    int nh = t >> 15;
    int n  = t & (kN - 1);
    float* p = buf + (size_t)(nh * kHC) * kN + n;
    float ss = 0.f;
#pragma unroll
    for (int hc = 0; hc < kHC; ++hc) { float v = p[(size_t)hc * kN]; ss += v * v; }
    float sc = 1.0f / fmaxf(sqrtf(ss), 1e-12f);
#pragma unroll
    for (int hc = 0; hc < kHC; ++hc) p[(size_t)hc * kN] *= sc;
}

// out[bh][h][hc] = sum_w buf[head-row hc][b,h,w]
__global__ void sum_w_kernel(const float* __restrict__ buf, float* __restrict__ out)
{
    int h = blockIdx.x, bh = blockIdx.y, hc = threadIdx.x;
    int b = bh >> 3, nh = bh & 7;
    const float* p = buf + (size_t)(nh * kHC + hc) * kN + b * kHW + h * kW;
    float s = 0.f;
    for (int w = 0; w < kW; ++w) s += p[w];
    out[((size_t)bh * kH + h) * kHC + hc] = s;
}

// out[bh][w][hc] = sum_h
__global__ void sum_h_kernel(const float* __restrict__ buf, float* __restrict__ out)
{
    int w = blockIdx.x, bh = blockIdx.y, hc = threadIdx.x;
    int b = bh >> 3, nh = bh & 7;
    const float* p = buf + (size_t)(nh * kHC + hc) * kN + b * kHW + w;
    float s = 0.f;
    for (int h = 0; h < kH; ++h) s += p[(size_t)h * kW];
    out[((size_t)bh * kW + w) * kHC + hc] = s;
}

__global__ void qs_kernel(const float* __restrict__ qsum_h, float* __restrict__ qs)
{
    int bh = blockIdx.x, hc = threadIdx.x;
    float s = 0.f;
    for (int h = 0; h < kH; ++h) s += qsum_h[((size_t)bh * kH + h) * kHC + hc];
    qs[bh * kHC + hc] = s;
}

__global__ void score_kernel(const float* __restrict__ qs, const float* __restrict__ ks,
                             float* __restrict__ sc)
{
    int bh = blockIdx.x; int i = threadIdx.x;   // 128 threads
    float s = 0.f;
    for (int hc = 0; hc < kHC; ++hc) s += qs[bh * kHC + hc] * ks[((size_t)bh * 128 + i) * kHC + hc];
    sc[bh * 128 + i] = s;
}

__global__ void topk_kernel(const float* __restrict__ hsc, const float* __restrict__ wsc,
                            int* __restrict__ hidx, int* __restrict__ widx)
{
    int t = threadIdx.x;
    if (t >= 32) return;
    int bh = t >> 1, sel = t & 1;
    const float* s = (sel ? wsc : hsc) + bh * 128;
    int* out = (sel ? widx : hidx) + bh * kP;
    unsigned long long taken[2] = {0ull, 0ull};
    for (int p = 0; p < kP; ++p) {
        float best = -INFINITY; int bi = 0;
        for (int j = 0; j < 128; ++j) {
            if ((taken[j >> 6] >> (j & 63)) & 1ull) continue;
            if (s[j] > best) { best = s[j]; bi = j; }
        }
        taken[bi >> 6] |= 1ull << (bi & 63);
        out[p] = bi;
    }
}

// Gather kf from normalized k; compute vf = wv * xn lazily at gathered pixels.
__global__ void gather_kv_kernel(const float* __restrict__ kbuf, const float* __restrict__ xn,
                                 const float* __restrict__ wv,
                                 const int* __restrict__ hidx, const int* __restrict__ widx,
                                 float* __restrict__ kf, float* __restrict__ vf)
{
    int bh = blockIdx.y, p1 = blockIdx.x;
    int b = bh >> 3, nh = bh & 7;
    int hc = threadIdx.x & 63, pg = threadIdx.x >> 6;
    int hrow = hidx[bh * kP + p1];
    int o = nh * kHC + hc;
    for (int p2 = pg; p2 < kP; p2 += 4) {
        int wcol = widx[bh * kP + p2];
        int n = b * kHW + hrow * kW + wcol;
        kf[(((size_t)bh * kP + p1) * kP + p2) * kHC + hc] =
            kbuf[(size_t)(nh * kHC + hc) * kN + n];
        float s = 0.f;
        for (int c = 0; c < kC; ++c) s += wv[(size_t)o * kC + c] * xn[(size_t)c * kN + n];
        vf[(((size_t)bh * kP + p1) * kP + p2) * kHC + hc] = s;
    }
}

// ---------------------------------------------------------------------------
// Attention: per (head, 256-query block). q read into regs, overwritten with
// softmax(q k^T) v in place. 256 keys processed in 4 LDS tiles of 64.
// ---------------------------------------------------------------------------
__global__ __launch_bounds__(256) void attn_kernel(
    float* __restrict__ q, const float* __restrict__ kf, const float* __restrict__ vf)
{
    __shared__ float kfs[64][kHC];
    __shared__ float vfs[64][kHC];
    int bh = blockIdx.y; int b = bh >> 3, nh = bh & 7;
    int n = b * kHW + blockIdx.x * 256 + threadIdx.x;
    float* qp = q + (size_t)(nh * kHC) * kN + n;
    float qr[kHC];
#pragma unroll
    for (int hc = 0; hc < kHC; ++hc) qr[hc] = qp[(size_t)hc * kN];
    float acc[kHC] = {};
    float m = -INFINITY, l = 0.f;
#pragma unroll 1
    for (int kt = 0; kt < 4; ++kt) {
        __syncthreads();
        const float* kfp = kf + ((size_t)bh * 256 + kt * 64) * kHC;
        const float* vfp = vf + ((size_t)bh * 256 + kt * 64) * kHC;
        for (int i = threadIdx.x; i < 64 * kHC; i += 256) {
            kfs[i >> 6][i & 63] = kfp[i];
            vfs[i >> 6][i & 63] = vfp[i];
        }
        __syncthreads();
#pragma unroll 2
        for (int kk = 0; kk < 64; ++kk) {
            float s = 0.f;
#pragma unroll
            for (int hc = 0; hc < kHC; ++hc) s += qr[hc] * kfs[kk][hc];
            if (s > m) {
                float alpha = __expf(m - s);
                l *= alpha;
#pragma unroll
                for (int hc = 0; hc < kHC; ++hc) acc[hc] *= alpha;
                m = s;
            }
            float pexp = __expf(s - m);
            l += pexp;
#pragma unroll
            for (int hc = 0; hc < kHC; ++hc) acc[hc] += pexp * vfs[kk][hc];
        }
    }
    float inv = 1.0f / l;
#pragma unroll
    for (int hc = 0; hc < kHC; ++hc) qp[(size_t)hc * kN] = acc[hc] * inv;
}

// ---------------------------------------------------------------------------
// Depthwise 3x3 SAME conv. Input layout parameterized; output channel-major.
// ---------------------------------------------------------------------------
__global__ void dwconv_kernel(const float* __restrict__ in, size_t inCS, size_t inBS,
                              float* __restrict__ out,
                              const float* __restrict__ wt, const float* __restrict__ bias)
{
    int t = blockIdx.x * 256 + threadIdx.x;
    if (t >= kC * kB * kHW) return;
    int hw = t & (kHW - 1);
    int cb = t >> 14;
    int b = cb & 1, c = cb >> 1;
    int h = hw >> 7, w = hw & 127;
    const float* ip = in + (size_t)c * inCS + (size_t)b * inBS;
    const float* wp = wt + c * 9;
    float s = bias[c];
#pragma unroll
    for (int dy = -1; dy <= 1; ++dy) {
#pragma unroll
        for (int dx = -1; dx <= 1; ++dx) {
            int hh = h + dy, ww = w + dx;
            if (hh >= 0 && hh < kH && ww >= 0 && ww < kW)
                s += wp[(dy + 1) * 3 + (dx + 1)] * ip[hh * kW + ww];
        }
    }
    out[(size_t)c * kN + b * kHW + hw] = s;
}

// Instance-norm stats per (c,b) over contiguous 16384 floats.
__global__ __launch_bounds__(256) void istats_kernel(const float* __restrict__ in,
                                                     float* __restrict__ stats)
{
    int cb = blockIdx.x; int b = cb & 1, c = cb >> 1;
    const float* p = in + (size_t)c * kN + (size_t)b * kHW;
    float s = 0.f, ss = 0.f;
    for (int i = threadIdx.x; i < kHW; i += 256) { float v = p[i]; s += v; ss += v * v; }
    __shared__ float red[2][4];
    for (int off = 32; off > 0; off >>= 1) {
        s  += __shfl_down(s, off, 64);
        ss += __shfl_down(ss, off, 64);
    }
    int wid = threadIdx.x >> 6, lane = threadIdx.x & 63;
    if (lane == 0) { red[0][wid] = s; red[1][wid] = ss; }
    __syncthreads();
    if (threadIdx.x == 0) {
        s  = red[0][0] + red[0][1] + red[0][2] + red[0][3];
        ss = red[1][0] + red[1][1] + red[1][2] + red[1][3];
        float m = s * (1.0f / kHW);
        float var = ss * (1.0f / kHW) - m * m;
        stats[cb * 2]     = m;
        stats[cb * 2 + 1] = rsqrtf(var + kEPS);
    }
}

// out = gelu_or_identity(inorm(in)) (+ addsrc). Channel-major layouts.
__global__ void apply_inorm_kernel(const float* __restrict__ in, const float* __restrict__ stats,
                                   float* __restrict__ out, const float* __restrict__ addsrc,
                                   int doGelu)
{
    int t = blockIdx.x * 256 + threadIdx.x;
    if (t >= kC * kN) return;
    int c = t >> 15;
    int n = t & (kN - 1);
    int b = n >> 14;
    int cb = c * 2 + b;
    float m = stats[cb * 2], r = stats[cb * 2 + 1];
    float v = (in[t] - m) * r;
    if (doGelu) v = 0.5f * v * (1.0f + erff(v * 0.70710678118654752f));
    if (addsrc) v += addsrc[t];
    out[t] = v;
}

// Final inorm + transpose channel-major -> NCHW into d_out.
__global__ void final_kernel(const float* __restrict__ in, const float* __restrict__ stats,
                             float* __restrict__ out)
{
    int t = blockIdx.x * 256 + threadIdx.x;
    if (t >= kC * kN) return;
    int c = t >> 15;
    int n = t & (kN - 1);
    int b = n >> 14, hw = n & (kHW - 1);
    int cb = c * 2 + b;
    float m = stats[cb * 2], r = stats[cb * 2 + 1];
    out[(size_t)(b * kC + c) * kHW + hw] = (in[t] - m) * r;
}

// ---------------------------------------------------------------------------
extern "C" void kernel_launch(void* const* d_in, const int* in_sizes, int n_in,
                              void* d_out, int out_size, void* d_ws, size_t ws_size,
                              hipStream_t stream)
{
    const float* x     = (const float*)d_in[0];
    const float* ln1_g = (const float*)d_in[1];
    const float* ln1_b = (const float*)d_in[2];
    const float* wq    = (const float*)d_in[3];
    const float* wk    = (const float*)d_in[4];
    const float* wv    = (const float*)d_in[5];
    const float* wo    = (const float*)d_in[6];
    const float* bo    = (const float*)d_in[7];
    const float* dw_w  = (const float*)d_in[8];
    const float* dw_b  = (const float*)d_in[9];
    const float* mlp_w = (const float*)d_in[10];
    const float* mlp_b = (const float*)d_in[11];
    const float* ln2_g = (const float*)d_in[12];
    const float* ln2_b = (const float*)d_in[13];
    const float* c1_w  = (const float*)d_in[14];
    const float* c1_b  = (const float*)d_in[15];
    const float* res_w = (const float*)d_in[16];
    const float* res_b = (const float*)d_in[17];
    const float* c2_w  = (const float*)d_in[18];
    const float* c2_b  = (const float*)d_in[19];

    float* wsf = (float*)d_ws;
    float* XN  = wsf;                              // kC*kN   (also F, t1/r/t2)
    float* Q   = XN + (size_t)kC * kN;             // kHID*kN (also attention out)
    float* Kb  = Q  + (size_t)kHID * kN;           // kHID*kN
    float* CAT = Kb + (size_t)kHID * kN;           // 2*kC*kN (also y3)
    float* B1  = CAT + (size_t)2 * kC * kN;        // kC*kN   (y1/y2)
    float* SM  = B1 + (size_t)kC * kN;
    float* qsum_h = SM;                 // 16*128*64
    float* ksum_h = qsum_h + 16*128*64;
    float* ksum_w = ksum_h + 16*128*64;
    float* qs     = ksum_w + 16*128*64; // 16*64
    float* hsc    = qs + 16*64;         // 16*128
    float* wsc    = hsc + 16*128;
    float* kf     = wsc + 16*128;       // 16*256*64
    float* vf     = kf + 16*256*64;
    float* stats  = vf + 16*256*64;     // 384*2
    int*   hidx   = (int*)(stats + 384*2);  // 16*16
    int*   widx   = hidx + 16*kP;

    const size_t xCS = kHW, xBS = (size_t)kC * kHW;   // x: NCHW strides
    const size_t cCS = kN,  cBS = kHW;                // channel-major strides

    // 1. ln1: xn = ln_ch(x)
    ln_ch_kernel<<<(kB*kHW + 255)/256, 256, 0, stream>>>(x, xCS, xBS, XN, ln1_g, ln1_b);
    // 2. q/k projection GEMMs
    gemm_kernel<<<dim3(kN/64, kHID/64), 256, 0, stream>>>(wq, XN, Q,  kC, nullptr, nullptr);
    gemm_kernel<<<dim3(kN/64, kHID/64), 256, 0, stream>>>(wk, XN, Kb, kC, nullptr, nullptr);
    // 3. l2 normalize q, k in place
    l2norm_kernel<<<(kNH*kN)/256, 256, 0, stream>>>(Q);
    l2norm_kernel<<<(kNH*kN)/256, 256, 0, stream>>>(Kb);
    // 4. reductions for scores
    sum_w_kernel<<<dim3(kH, 16), 64, 0, stream>>>(Q,  qsum_h);
    sum_w_kernel<<<dim3(kH, 16), 64, 0, stream>>>(Kb, ksum_h);
    sum_h_kernel<<<dim3(kW, 16), 64, 0, stream>>>(Kb, ksum_w);
    qs_kernel<<<16, 64, 0, stream>>>(qsum_h, qs);
    score_kernel<<<16, 128, 0, stream>>>(qs, ksum_h, hsc);
    score_kernel<<<16, 128, 0, stream>>>(qs, ksum_w, wsc);
    // 5. top-16 row/col indices
    topk_kernel<<<1, 64, 0, stream>>>(hsc, wsc, hidx, widx);
    // 6. gather kf; lazy-project vf
    gather_kv_kernel<<<dim3(kP, 16), 256, 0, stream>>>(Kb, XN, wv, hidx, widx, kf, vf);
    // 7. attention (in-place on Q)
    attn_kernel<<<dim3(kHW/256, 16), 256, 0, stream>>>(Q, kf, vf);
    // 8. wo GEMM -> CAT rows 192..383
    gemm_kernel<<<dim3(kN/64, kC/64), 256, 0, stream>>>(wo, Q, CAT + (size_t)kC * kN, kHID, bo, nullptr);
    // 9. local branch dwconv -> CAT rows 0..191
    dwconv_kernel<<<(kC*kB*kHW)/256, 256, 0, stream>>>(x, xCS, xBS, CAT, dw_w, dw_b);
    // 10. mlp GEMM + bias + residual x -> F (reuses XN)
    gemm_kernel<<<dim3(kN/64, kC/64), 256, 0, stream>>>(mlp_w, CAT, XN, 2*kC, mlp_b, x);
    // 11. ln2 -> y1 (B1)
    ln_ch_kernel<<<(kB*kHW + 255)/256, 256, 0, stream>>>(XN, cCS, cBS, B1, ln2_g, ln2_b);
    // 12. c1 GEMM -> t1 (XN)
    gemm_kernel<<<dim3(kN/64, kC/64), 256, 0, stream>>>(c1_w, B1, XN, kC, c1_b, nullptr);
    // 13-14. inorm + gelu -> y2 (B1)
    istats_kernel<<<kC*kB, 256, 0, stream>>>(XN, stats);
    apply_inorm_kernel<<<(kC*kN)/256, 256, 0, stream>>>(XN, stats, B1, nullptr, 1);
    // 15. res dwconv -> r (XN)
    dwconv_kernel<<<(kC*kB*kHW)/256, 256, 0, stream>>>(B1, cCS, cBS, XN, res_w, res_b);
    // 16-17. inorm + gelu + residual y2 -> y3 (CAT)
    istats_kernel<<<kC*kB, 256, 0, stream>>>(XN, stats);
    apply_inorm_kernel<<<(kC*kN)/256, 256, 0, stream>>>(XN, stats, CAT, B1, 1);
    // 18. c2 GEMM -> t2 (XN)
    gemm_kernel<<<dim3(kN/64, kC/64), 256, 0, stream>>>(c2_w, CAT, XN, kC, c2_b, nullptr);
    // 19-20. final inorm -> d_out (NCHW)
    istats_kernel<<<kC*kB, 256, 0, stream>>>(XN, stats);
    final_kernel<<<(kC*kN)/256, 256, 0, stream>>>(XN, stats, (float*)d_out);
}

// Round 2
// 1268.495 us; speedup vs baseline: 1.5983x; 1.5983x over previous
//
#include <hip/hip_runtime.h>
#include <math.h>

constexpr int kC   = 192;
constexpr int kNH  = 8;
constexpr int kHC  = 64;
constexpr int kHID = 512;
constexpr int kP   = 16;
constexpr int kB   = 2;
constexpr int kH   = 128;
constexpr int kW   = 128;
constexpr int kHW  = kH * kW;      // 16384
constexpr int kN   = kB * kHW;     // 32768
constexpr float kEPS = 1e-5f;

typedef __attribute__((ext_vector_type(8))) short bf16x8;
typedef __attribute__((ext_vector_type(4))) float f32x4;

__device__ inline unsigned short f2bf(float f) {
    unsigned int u = __builtin_bit_cast(unsigned int, f);
    unsigned int r = (u + 0x7FFFu + ((u >> 16) & 1u)) >> 16;   // RNE
    return (unsigned short)r;
}

// ---------------------------------------------------------------------------
// LayerNorm over channel dim. Output channel-major: out[c*kN + b*kHW + hw].
// ---------------------------------------------------------------------------
__global__ void ln_ch_kernel(const float* __restrict__ in, size_t inCS, size_t inBS,
                             float* __restrict__ out,
                             const float* __restrict__ g, const float* __restrict__ bb)
{
    int t = blockIdx.x * blockDim.x + threadIdx.x;
    if (t >= kB * kHW) return;
    int b = t / kHW, hw = t % kHW;
    const float* ip = in + (size_t)b * inBS + hw;
    float s = 0.f, ss = 0.f;
    for (int c = 0; c < kC; ++c) { float v = ip[(size_t)c * inCS]; s += v; ss += v * v; }
    float m  = s * (1.0f / kC);
    float var = ss * (1.0f / kC) - m * m;
    float rs = rsqrtf(var + kEPS);
    float* op = out + (size_t)b * kHW + hw;
    for (int c = 0; c < kC; ++c) {
        float v = ip[(size_t)c * inCS];
        op[(size_t)c * kN] = (v - m) * rs * g[c] + bb[c];
    }
}

// ---------------------------------------------------------------------------
// Generic fp32 GEMM: Cm[o][n] = sum_k A[o][k] * Bm[k][n] (+bias) (+x residual)
// ---------------------------------------------------------------------------
__global__ __launch_bounds__(256) void gemm_kernel(
    const float* __restrict__ A, const float* __restrict__ Bm,
    float* __restrict__ Cm, int K,
    const float* __restrict__ bias, const float* __restrict__ resx)
{
    __shared__ float As[16][68];
    __shared__ float Bs[16][68];
    int tid = threadIdx.x;
    int tx = tid & 15, ty = tid >> 4;
    int nBase = blockIdx.x * 64;
    int oBase = blockIdx.y * 64;
    float acc[4][4] = {};
    for (int k0 = 0; k0 < K; k0 += 16) {
        {
            int kk = tid & 15, o = tid >> 4;
#pragma unroll
            for (int m = 0; m < 4; ++m)
                As[kk][o + 16 * m] = A[(size_t)(oBase + o + 16 * m) * K + k0 + kk];
        }
        {
            int n = tid & 63, kk4 = tid >> 6;
#pragma unroll
            for (int m = 0; m < 4; ++m)
                Bs[kk4 + 4 * m][n] = Bm[(size_t)(k0 + kk4 + 4 * m) * kN + nBase + n];
        }
        __syncthreads();
#pragma unroll
        for (int kk = 0; kk < 16; ++kk) {
            float a[4], b[4];
#pragma unroll
            for (int i = 0; i < 4; ++i) a[i] = As[kk][ty + 16 * i];
#pragma unroll
            for (int j = 0; j < 4; ++j) b[j] = Bs[kk][tx + 16 * j];
#pragma unroll
            for (int i = 0; i < 4; ++i)
#pragma unroll
                for (int j = 0; j < 4; ++j)
                    acc[i][j] += a[i] * b[j];
        }
        __syncthreads();
    }
#pragma unroll
    for (int i = 0; i < 4; ++i) {
        int o = oBase + ty + 16 * i;
        float bv = bias ? bias[o] : 0.f;
#pragma unroll
        for (int j = 0; j < 4; ++j) {
            int n = nBase + tx + 16 * j;
            float v = acc[i][j] + bv;
            if (resx) v += resx[(size_t)((n >> 14) * kC + o) * kHW + (n & (kHW - 1))];
            Cm[(size_t)o * kN + n] = v;
        }
    }
}

// ---------------------------------------------------------------------------
// In-place L2 norm over the 64 head-channels of q/k.
// ---------------------------------------------------------------------------
__global__ void l2norm_kernel(float* __restrict__ buf)
{
    int t = blockIdx.x * blockDim.x + threadIdx.x;   // over kNH*kN
    int nh = t >> 15;
    int n  = t & (kN - 1);
    float* p = buf + (size_t)(nh * kHC) * kN + n;
    float ss = 0.f;
#pragma unroll
    for (int hc = 0; hc < kHC; ++hc) { float v = p[(size_t)hc * kN]; ss += v * v; }
    float sc = 1.0f / fmaxf(sqrtf(ss), 1e-12f);
#pragma unroll
    for (int hc = 0; hc < kHC; ++hc) p[(size_t)hc * kN] *= sc;
}

__global__ void sum_w_kernel(const float* __restrict__ buf, float* __restrict__ out)
{
    int h = blockIdx.x, bh = blockIdx.y, hc = threadIdx.x;
    int b = bh >> 3, nh = bh & 7;
    const float* p = buf + (size_t)(nh * kHC + hc) * kN + b * kHW + h * kW;
    float s = 0.f;
    for (int w = 0; w < kW; ++w) s += p[w];
    out[((size_t)bh * kH + h) * kHC + hc] = s;
}

__global__ void sum_h_kernel(const float* __restrict__ buf, float* __restrict__ out)
{
    int w = blockIdx.x, bh = blockIdx.y, hc = threadIdx.x;
    int b = bh >> 3, nh = bh & 7;
    const float* p = buf + (size_t)(nh * kHC + hc) * kN + b * kHW + w;
    float s = 0.f;
    for (int h = 0; h < kH; ++h) s += p[(size_t)h * kW];
    out[((size_t)bh * kW + w) * kHC + hc] = s;
}

__global__ void qs_kernel(const float* __restrict__ qsum_h, float* __restrict__ qs)
{
    int bh = blockIdx.x, hc = threadIdx.x;
    float s = 0.f;
    for (int h = 0; h < kH; ++h) s += qsum_h[((size_t)bh * kH + h) * kHC + hc];
    qs[bh * kHC + hc] = s;
}

__global__ void score_kernel(const float* __restrict__ qs, const float* __restrict__ ks,
                             float* __restrict__ sc)
{
    int bh = blockIdx.x; int i = threadIdx.x;   // 128 threads
    float s = 0.f;
    for (int hc = 0; hc < kHC; ++hc) s += qs[bh * kHC + hc] * ks[((size_t)bh * 128 + i) * kHC + hc];
    sc[bh * 128 + i] = s;
}

__global__ void topk_kernel(const float* __restrict__ hsc, const float* __restrict__ wsc,
                            int* __restrict__ hidx, int* __restrict__ widx)
{
    int t = threadIdx.x;
    if (t >= 32) return;
    int bh = t >> 1, sel = t & 1;
    const float* s = (sel ? wsc : hsc) + bh * 128;
    int* out = (sel ? widx : hidx) + bh * kP;
    unsigned long long taken[2] = {0ull, 0ull};
    for (int p = 0; p < kP; ++p) {
        float best = -INFINITY; int bi = 0;
        for (int j = 0; j < 128; ++j) {
            if ((taken[j >> 6] >> (j & 63)) & 1ull) continue;
            if (s[j] > best) { best = s[j]; bi = j; }
        }
        taken[bi >> 6] |= 1ull << (bi & 63);
        out[p] = bi;
    }
}

// Gather kf (bf16, [bh][256][64]) from normalized k; lazy-project vf and store
// TRANSPOSED as bf16 vfT[bh][64 hc][256 k] so PV A-fragments are contiguous.
__global__ void gather_kv_kernel(const float* __restrict__ kbuf, const float* __restrict__ xn,
                                 const float* __restrict__ wv,
                                 const int* __restrict__ hidx, const int* __restrict__ widx,
                                 unsigned short* __restrict__ kf, unsigned short* __restrict__ vfT)
{
    int bh = blockIdx.y, p1 = blockIdx.x;
    int b = bh >> 3, nh = bh & 7;
    int hc = threadIdx.x & 63, pg = threadIdx.x >> 6;
    int hrow = hidx[bh * kP + p1];
    int o = nh * kHC + hc;
    for (int p2 = pg; p2 < kP; p2 += 4) {
        int wcol = widx[bh * kP + p2];
        int n = b * kHW + hrow * kW + wcol;
        int kidx = p1 * kP + p2;
        kf[((size_t)bh * 256 + kidx) * 64 + hc] =
            f2bf(kbuf[(size_t)(nh * kHC + hc) * kN + n]);
        float s = 0.f;
        for (int c = 0; c < kC; ++c) s += wv[(size_t)o * kC + c] * xn[(size_t)c * kN + n];
        vfT[((size_t)bh * 64 + hc) * 256 + kidx] = f2bf(s);
    }
}

// ---------------------------------------------------------------------------
// MFMA attention. Block = 64 queries of one head, 4 waves.
// Wave w: S-phase owns keys [w*64, w*64+64); PV-phase owns hc [w*16, w*16+16).
// S^T = K·Q^T (m=key, n=query), P = exp(S) (no max needed: |s|<=1),
// O^T = V^T·P (m=hc, n=query). P bounced through XOR-swizzled LDS.
// ---------------------------------------------------------------------------
__global__ __launch_bounds__(256) void attn_kernel(
    float* __restrict__ q, const unsigned short* __restrict__ kf,
    const unsigned short* __restrict__ vfT)
{
    __shared__ unsigned short qls[64][72];      // [q][hc] bf16, padded
    __shared__ unsigned short pls[64 * 264];    // [q][k^swz] bf16
    __shared__ float lred[4][4][16];            // [wave][nt][q15]

    int bh = blockIdx.y; int b = bh >> 3, nh = bh & 7;
    int n0 = b * kHW + blockIdx.x * 64;
    int tid = threadIdx.x;
    int w = tid >> 6;
    int lane = tid & 63;
    int l15 = lane & 15;
    int g = lane >> 4;

    // stage Q tile (64 hc x 64 q) -> qls[q][hc] bf16 (coalesced global reads)
    {
        int qq = tid & 63;
        for (int hc = tid >> 6; hc < 64; hc += 4)
            qls[qq][hc] = f2bf(q[(size_t)(nh * kHC + hc) * kN + n0 + qq]);
    }
    __syncthreads();

    // ---- S phase: acc[mt][nt] = K[w*64+mt*16 .. ][:] x Q^T[:][nt*16 ..] ----
    bf16x8 bq[4][2];
#pragma unroll
    for (int nt = 0; nt < 4; ++nt)
#pragma unroll
        for (int kt = 0; kt < 2; ++kt)
            bq[nt][kt] = *(const bf16x8*)&qls[nt * 16 + l15][kt * 32 + 8 * g];

    const unsigned short* kfb = kf + (size_t)bh * 256 * 64;
    bf16x8 ak[4][2];
#pragma unroll
    for (int mt = 0; mt < 4; ++mt)
#pragma unroll
        for (int kt = 0; kt < 2; ++kt)
            ak[mt][kt] = *(const bf16x8*)&kfb[(size_t)(w * 64 + mt * 16 + l15) * 64 + kt * 32 + 8 * g];

    f32x4 acc[4][4];
#pragma unroll
    for (int mt = 0; mt < 4; ++mt)
#pragma unroll
        for (int nt = 0; nt < 4; ++nt)
            acc[mt][nt] = (f32x4){0.f, 0.f, 0.f, 0.f};

#pragma unroll
    for (int kt = 0; kt < 2; ++kt)
#pragma unroll
        for (int mt = 0; mt < 4; ++mt)
#pragma unroll
            for (int nt = 0; nt < 4; ++nt)
                acc[mt][nt] = __builtin_amdgcn_mfma_f32_16x16x32_bf16(
                    ak[mt][kt], bq[nt][kt], acc[mt][nt], 0, 0, 0);

    // ---- exp, partial softmax denominators, pack P to swizzled LDS ----
    float lpart[4] = {0.f, 0.f, 0.f, 0.f};
#pragma unroll
    for (int mt = 0; mt < 4; ++mt)
#pragma unroll
        for (int nt = 0; nt < 4; ++nt) {
            float e0 = __expf(acc[mt][nt][0]);
            float e1 = __expf(acc[mt][nt][1]);
            float e2 = __expf(acc[mt][nt][2]);
            float e3 = __expf(acc[mt][nt][3]);
            lpart[nt] += (e0 + e1) + (e2 + e3);
            int qq = nt * 16 + l15;
            int k0 = w * 64 + mt * 16 + 4 * g;
            int kx = k0 ^ ((qq & 7) << 3);
            unsigned int lo = f2bf(e0) | ((unsigned int)f2bf(e1) << 16);
            unsigned int hi = f2bf(e2) | ((unsigned int)f2bf(e3) << 16);
            unsigned int* p = (unsigned int*)&pls[qq * 264 + kx];
            p[0] = lo; p[1] = hi;
        }
#pragma unroll
    for (int nt = 0; nt < 4; ++nt) {
        lpart[nt] += __shfl_xor(lpart[nt], 16);
        lpart[nt] += __shfl_xor(lpart[nt], 32);
    }
    if (g == 0)
#pragma unroll
        for (int nt = 0; nt < 4; ++nt) lred[w][nt][l15] = lpart[nt];
    __syncthreads();

    // ---- PV phase: oacc[nt] (16 hc x 16 q per tile) ----
    const unsigned short* vfb = vfT + (size_t)bh * 64 * 256;
    f32x4 oacc[4];
#pragma unroll
    for (int nt = 0; nt < 4; ++nt) oacc[nt] = (f32x4){0.f, 0.f, 0.f, 0.f};

#pragma unroll
    for (int ks = 0; ks < 8; ++ks) {
        bf16x8 av = *(const bf16x8*)&vfb[(size_t)(w * 16 + l15) * 256 + ks * 32 + 8 * g];
#pragma unroll
        for (int nt = 0; nt < 4; ++nt) {
            int qq = nt * 16 + l15;
            int kx = (ks * 32 + 8 * g) ^ ((qq & 7) << 3);
            bf16x8 bp = *(const bf16x8*)&pls[qq * 264 + kx];
            oacc[nt] = __builtin_amdgcn_mfma_f32_16x16x32_bf16(av, bp, oacc[nt], 0, 0, 0);
        }
    }

    // ---- epilogue: divide by l, store O^T back into q (channel-major) ----
#pragma unroll
    for (int nt = 0; nt < 4; ++nt) {
        float l = lred[0][nt][l15] + lred[1][nt][l15] + lred[2][nt][l15] + lred[3][nt][l15];
        float inv = 1.0f / l;
        int qq = nt * 16 + l15;
#pragma unroll
        for (int r = 0; r < 4; ++r) {
            int hc = w * 16 + 4 * g + r;
            q[(size_t)(nh * kHC + hc) * kN + n0 + qq] = oacc[nt][r] * inv;
        }
    }
}

// ---------------------------------------------------------------------------
// Depthwise 3x3 SAME conv.
// ---------------------------------------------------------------------------
__global__ void dwconv_kernel(const float* __restrict__ in, size_t inCS, size_t inBS,
                              float* __restrict__ out,
                              const float* __restrict__ wt, const float* __restrict__ bias)
{
    int t = blockIdx.x * 256 + threadIdx.x;
    if (t >= kC * kB * kHW) return;
    int hw = t & (kHW - 1);
    int cb = t >> 14;
    int b = cb & 1, c = cb >> 1;
    int h = hw >> 7, w = hw & 127;
    const float* ip = in + (size_t)c * inCS + (size_t)b * inBS;
    const float* wp = wt + c * 9;
    float s = bias[c];
#pragma unroll
    for (int dy = -1; dy <= 1; ++dy) {
#pragma unroll
        for (int dx = -1; dx <= 1; ++dx) {
            int hh = h + dy, ww = w + dx;
            if (hh >= 0 && hh < kH && ww >= 0 && ww < kW)
                s += wp[(dy + 1) * 3 + (dx + 1)] * ip[hh * kW + ww];
        }
    }
    out[(size_t)c * kN + b * kHW + hw] = s;
}

__global__ __launch_bounds__(256) void istats_kernel(const float* __restrict__ in,
                                                     float* __restrict__ stats)
{
    int cb = blockIdx.x; int b = cb & 1, c = cb >> 1;
    const float* p = in + (size_t)c * kN + (size_t)b * kHW;
    float s = 0.f, ss = 0.f;
    for (int i = threadIdx.x; i < kHW; i += 256) { float v = p[i]; s += v; ss += v * v; }
    __shared__ float red[2][4];
    for (int off = 32; off > 0; off >>= 1) {
        s  += __shfl_down(s, off, 64);
        ss += __shfl_down(ss, off, 64);
    }
    int wid = threadIdx.x >> 6, lane = threadIdx.x & 63;
    if (lane == 0) { red[0][wid] = s; red[1][wid] = ss; }
    __syncthreads();
    if (threadIdx.x == 0) {
        s  = red[0][0] + red[0][1] + red[0][2] + red[0][3];
        ss = red[1][0] + red[1][1] + red[1][2] + red[1][3];
        float m = s * (1.0f / kHW);
        float var = ss * (1.0f / kHW) - m * m;
        stats[cb * 2]     = m;
        stats[cb * 2 + 1] = rsqrtf(var + kEPS);
    }
}

__global__ void apply_inorm_kernel(const float* __restrict__ in, const float* __restrict__ stats,
                                   float* __restrict__ out, const float* __restrict__ addsrc,
                                   int doGelu)
{
    int t = blockIdx.x * 256 + threadIdx.x;
    if (t >= kC * kN) return;
    int c = t >> 15;
    int n = t & (kN - 1);
    int b = n >> 14;
    int cb = c * 2 + b;
    float m = stats[cb * 2], r = stats[cb * 2 + 1];
    float v = (in[t] - m) * r;
    if (doGelu) v = 0.5f * v * (1.0f + erff(v * 0.70710678118654752f));
    if (addsrc) v += addsrc[t];
    out[t] = v;
}

__global__ void final_kernel(const float* __restrict__ in, const float* __restrict__ stats,
                             float* __restrict__ out)
{
    int t = blockIdx.x * 256 + threadIdx.x;
    if (t >= kC * kN) return;
    int c = t >> 15;
    int n = t & (kN - 1);
    int b = n >> 14, hw = n & (kHW - 1);
    int cb = c * 2 + b;
    float m = stats[cb * 2], r = stats[cb * 2 + 1];
    out[(size_t)(b * kC + c) * kHW + hw] = (in[t] - m) * r;
}

// ---------------------------------------------------------------------------
extern "C" void kernel_launch(void* const* d_in, const int* in_sizes, int n_in,
                              void* d_out, int out_size, void* d_ws, size_t ws_size,
                              hipStream_t stream)
{
    const float* x     = (const float*)d_in[0];
    const float* ln1_g = (const float*)d_in[1];
    const float* ln1_b = (const float*)d_in[2];
    const float* wq    = (const float*)d_in[3];
    const float* wk    = (const float*)d_in[4];
    const float* wv    = (const float*)d_in[5];
    const float* wo    = (const float*)d_in[6];
    const float* bo    = (const float*)d_in[7];
    const float* dw_w  = (const float*)d_in[8];
    const float* dw_b  = (const float*)d_in[9];
    const float* mlp_w = (const float*)d_in[10];
    const float* mlp_b = (const float*)d_in[11];
    const float* ln2_g = (const float*)d_in[12];
    const float* ln2_b = (const float*)d_in[13];
    const float* c1_w  = (const float*)d_in[14];
    const float* c1_b  = (const float*)d_in[15];
    const float* res_w = (const float*)d_in[16];
    const float* res_b = (const float*)d_in[17];
    const float* c2_w  = (const float*)d_in[18];
    const float* c2_b  = (const float*)d_in[19];

    float* wsf = (float*)d_ws;
    float* XN  = wsf;                              // kC*kN
    float* Q   = XN + (size_t)kC * kN;             // kHID*kN (attention in/out)
    float* Kb  = Q  + (size_t)kHID * kN;           // kHID*kN
    float* CAT = Kb + (size_t)kHID * kN;           // 2*kC*kN
    float* B1  = CAT + (size_t)2 * kC * kN;        // kC*kN
    float* SM  = B1 + (size_t)kC * kN;
    float* qsum_h = SM;                 // 16*128*64
    float* ksum_h = qsum_h + 16*128*64;
    float* ksum_w = ksum_h + 16*128*64;
    float* qs     = ksum_w + 16*128*64; // 16*64
    float* hsc    = qs + 16*64;         // 16*128
    float* wsc    = hsc + 16*128;
    unsigned short* kf  = (unsigned short*)(wsc + 16*128);  // bf16 16*256*64
    unsigned short* vfT = kf + 16*256*64;                   // bf16 16*64*256
    float* stats  = (float*)(vfT + 16*256*64);  // 384*2
    int*   hidx   = (int*)(stats + 384*2);      // 16*16
    int*   widx   = hidx + 16*kP;

    const size_t xCS = kHW, xBS = (size_t)kC * kHW;   // x: NCHW strides
    const size_t cCS = kN,  cBS = kHW;                // channel-major strides

    // 1. ln1
    ln_ch_kernel<<<(kB*kHW + 255)/256, 256, 0, stream>>>(x, xCS, xBS, XN, ln1_g, ln1_b);
    // 2. q/k projection GEMMs
    gemm_kernel<<<dim3(kN/64, kHID/64), 256, 0, stream>>>(wq, XN, Q,  kC, nullptr, nullptr);
    gemm_kernel<<<dim3(kN/64, kHID/64), 256, 0, stream>>>(wk, XN, Kb, kC, nullptr, nullptr);
    // 3. l2 normalize
    l2norm_kernel<<<(kNH*kN)/256, 256, 0, stream>>>(Q);
    l2norm_kernel<<<(kNH*kN)/256, 256, 0, stream>>>(Kb);
    // 4. score reductions
    sum_w_kernel<<<dim3(kH, 16), 64, 0, stream>>>(Q,  qsum_h);
    sum_w_kernel<<<dim3(kH, 16), 64, 0, stream>>>(Kb, ksum_h);
    sum_h_kernel<<<dim3(kW, 16), 64, 0, stream>>>(Kb, ksum_w);
    qs_kernel<<<16, 64, 0, stream>>>(qsum_h, qs);
    score_kernel<<<16, 128, 0, stream>>>(qs, ksum_h, hsc);
    score_kernel<<<16, 128, 0, stream>>>(qs, ksum_w, wsc);
    // 5. top-16
    topk_kernel<<<1, 64, 0, stream>>>(hsc, wsc, hidx, widx);
    // 6. gather kf (bf16) + lazy vfT (bf16, transposed)
    gather_kv_kernel<<<dim3(kP, 16), 256, 0, stream>>>(Kb, XN, wv, hidx, widx, kf, vfT);
    // 7. MFMA attention (in-place on Q)
    attn_kernel<<<dim3(kHW/64, 16), 256, 0, stream>>>(Q, kf, vfT);
    // 8. wo GEMM -> CAT rows 192..383
    gemm_kernel<<<dim3(kN/64, kC/64), 256, 0, stream>>>(wo, Q, CAT + (size_t)kC * kN, kHID, bo, nullptr);
    // 9. local branch dwconv -> CAT rows 0..191
    dwconv_kernel<<<(kC*kB*kHW)/256, 256, 0, stream>>>(x, xCS, xBS, CAT, dw_w, dw_b);
    // 10. mlp GEMM + bias + residual x
    gemm_kernel<<<dim3(kN/64, kC/64), 256, 0, stream>>>(mlp_w, CAT, XN, 2*kC, mlp_b, x);
    // 11. ln2
    ln_ch_kernel<<<(kB*kHW + 255)/256, 256, 0, stream>>>(XN, cCS, cBS, B1, ln2_g, ln2_b);
    // 12. c1 GEMM
    gemm_kernel<<<dim3(kN/64, kC/64), 256, 0, stream>>>(c1_w, B1, XN, kC, c1_b, nullptr);
    // 13-14. inorm + gelu
    istats_kernel<<<kC*kB, 256, 0, stream>>>(XN, stats);
    apply_inorm_kernel<<<(kC*kN)/256, 256, 0, stream>>>(XN, stats, B1, nullptr, 1);
    // 15. res dwconv
    dwconv_kernel<<<(kC*kB*kHW)/256, 256, 0, stream>>>(B1, cCS, cBS, XN, res_w, res_b);
    // 16-17. inorm + gelu + residual
    istats_kernel<<<kC*kB, 256, 0, stream>>>(XN, stats);
    apply_inorm_kernel<<<(kC*kN)/256, 256, 0, stream>>>(XN, stats, CAT, B1, 1);
    // 18. c2 GEMM
    gemm_kernel<<<dim3(kN/64, kC/64), 256, 0, stream>>>(c2_w, CAT, XN, kC, c2_b, nullptr);
    // 19-20. final inorm -> d_out (NCHW)
    istats_kernel<<<kC*kB, 256, 0, stream>>>(XN, stats);
    final_kernel<<<(kC*kN)/256, 256, 0, stream>>>(XN, stats, (float*)d_out);
}

// Round 3
// 752.901 us; speedup vs baseline: 2.6928x; 1.6848x over previous
//
#include <hip/hip_runtime.h>
#include <math.h>

constexpr int kC   = 192;
constexpr int kNH  = 8;
constexpr int kHC  = 64;
constexpr int kHID = 512;
constexpr int kP   = 16;
constexpr int kB   = 2;
constexpr int kH   = 128;
constexpr int kW   = 128;
constexpr int kHW  = kH * kW;      // 16384
constexpr int kN   = kB * kHW;     // 32768
constexpr float kEPS = 1e-5f;

typedef __attribute__((ext_vector_type(8))) short bf16x8;
typedef __attribute__((ext_vector_type(4))) float f32x4;

__device__ inline unsigned short f2bf(float f) {
    unsigned int u = __builtin_bit_cast(unsigned int, f);
    unsigned int r = (u + 0x7FFFu + ((u >> 16) & 1u)) >> 16;   // RNE
    return (unsigned short)r;
}
__device__ inline float bf2f(unsigned short u) {
    return __builtin_bit_cast(float, (unsigned int)u << 16);
}

// ---------------------------------------------------------------------------
// Zero the istats accumulators (re-run every launch: ws is not re-poisoned).
// ---------------------------------------------------------------------------
__global__ void zero_kernel(float* __restrict__ p, int n)
{
    int i = blockIdx.x * 256 + threadIdx.x;
    if (i < n) p[i] = 0.f;
}

// fp32 -> bf16 weight conversion
__global__ void cvt_kernel(const float* __restrict__ src, unsigned short* __restrict__ dst, int n)
{
    int i = blockIdx.x * 256 + threadIdx.x;
    if (i < n) dst[i] = f2bf(src[i]);
}

// ---------------------------------------------------------------------------
// Transpose x NCHW fp32 -> XP pixel-major fp32 [n][192]
// ---------------------------------------------------------------------------
__global__ __launch_bounds__(256) void transpose_x_kernel(const float* __restrict__ x,
                                                          float* __restrict__ xp)
{
    __shared__ float tile[64][65];
    int hw0 = blockIdx.x * 64;
    int c0  = blockIdx.y * 64;
    int b   = blockIdx.z;
    int tid = threadIdx.x;
    for (int i = tid; i < 64 * 64; i += 256) {
        int row = i >> 6, p = i & 63;
        tile[row][p] = x[((size_t)(b * kC + c0 + row)) * kHW + hw0 + p];
    }
    __syncthreads();
    for (int i = tid; i < 64 * 64; i += 256) {
        int pp = i >> 6, cc = i & 63;
        xp[((size_t)(b * kHW + hw0 + pp)) * kC + c0 + cc] = tile[cc][pp];
    }
}

// ---------------------------------------------------------------------------
// LayerNorm over channels, pixel-major fp32 in -> bf16 out.
// ---------------------------------------------------------------------------
__global__ void ln_pm_kernel(const float* __restrict__ in, unsigned short* __restrict__ out,
                             const float* __restrict__ g, const float* __restrict__ bb)
{
    int n = blockIdx.x * 256 + threadIdx.x;
    if (n >= kN) return;
    const f32x4* ip = (const f32x4*)(in + (size_t)n * kC);
    float s = 0.f, ss = 0.f;
#pragma unroll
    for (int r = 0; r < 48; ++r) {
        f32x4 v = ip[r];
        s  += (v[0] + v[1]) + (v[2] + v[3]);
        ss += (v[0]*v[0] + v[1]*v[1]) + (v[2]*v[2] + v[3]*v[3]);
    }
    float m  = s * (1.0f / kC);
    float var = ss * (1.0f / kC) - m * m;
    float rs = rsqrtf(var + kEPS);
    unsigned short* op = out + (size_t)n * kC;
#pragma unroll
    for (int r = 0; r < 48; ++r) {
        f32x4 v = ip[r];
        f32x4 gg = *(const f32x4*)(g + r * 4);
        f32x4 bv = *(const f32x4*)(bb + r * 4);
        unsigned long long pk =
            (unsigned long long)f2bf((v[0]-m)*rs*gg[0] + bv[0])
          | ((unsigned long long)f2bf((v[1]-m)*rs*gg[1] + bv[1]) << 16)
          | ((unsigned long long)f2bf((v[2]-m)*rs*gg[2] + bv[2]) << 32)
          | ((unsigned long long)f2bf((v[3]-m)*rs*gg[3] + bv[3]) << 48);
        *(unsigned long long*)(op + r * 4) = pk;
    }
}

// ---------------------------------------------------------------------------
// MFMA GEMM, LDS-free. A [O][K] bf16 (weights), B [n][K] bf16 pixel-major.
// D[o][n]. Block: 256 thr = 4 waves (2x2), tile BM=64 o x BN=128 n.
// MODE: 0 = f32 out; 1 = f32+bias; 2 = f32+bias+res(fp32 [n][192]); 3 = bf16+bias.
// ---------------------------------------------------------------------------
template<int MODE>
__global__ __launch_bounds__(256) void mgemm_kernel(
    const unsigned short* __restrict__ A, const unsigned short* __restrict__ B,
    const int K, void* __restrict__ out, const int ldOut, const int colOff,
    const float* __restrict__ bias, const float* __restrict__ res)
{
    int nB = blockIdx.x * 128, oB = blockIdx.y * 64;
    int w = threadIdx.x >> 6, lane = threadIdx.x & 63;
    int l15 = lane & 15, g = lane >> 4;
    int wm = w & 1, wn = w >> 1;
    const unsigned short* Ap = A + (size_t)(oB + wm * 32 + l15) * K + 8 * g;
    const unsigned short* Bp = B + (size_t)(nB + wn * 64 + l15) * K + 8 * g;

    f32x4 acc[2][4];
#pragma unroll
    for (int mt = 0; mt < 2; ++mt)
#pragma unroll
        for (int nt = 0; nt < 4; ++nt) acc[mt][nt] = (f32x4){0.f,0.f,0.f,0.f};

#pragma unroll 2
    for (int k = 0; k < K; k += 32) {
        bf16x8 a0 = *(const bf16x8*)(Ap + k);
        bf16x8 a1 = *(const bf16x8*)(Ap + (size_t)16 * K + k);
        bf16x8 b0 = *(const bf16x8*)(Bp + k);
        bf16x8 b1 = *(const bf16x8*)(Bp + (size_t)16 * K + k);
        bf16x8 b2 = *(const bf16x8*)(Bp + (size_t)32 * K + k);
        bf16x8 b3 = *(const bf16x8*)(Bp + (size_t)48 * K + k);
        acc[0][0] = __builtin_amdgcn_mfma_f32_16x16x32_bf16(a0, b0, acc[0][0], 0, 0, 0);
        acc[0][1] = __builtin_amdgcn_mfma_f32_16x16x32_bf16(a0, b1, acc[0][1], 0, 0, 0);
        acc[0][2] = __builtin_amdgcn_mfma_f32_16x16x32_bf16(a0, b2, acc[0][2], 0, 0, 0);
        acc[0][3] = __builtin_amdgcn_mfma_f32_16x16x32_bf16(a0, b3, acc[0][3], 0, 0, 0);
        acc[1][0] = __builtin_amdgcn_mfma_f32_16x16x32_bf16(a1, b0, acc[1][0], 0, 0, 0);
        acc[1][1] = __builtin_amdgcn_mfma_f32_16x16x32_bf16(a1, b1, acc[1][1], 0, 0, 0);
        acc[1][2] = __builtin_amdgcn_mfma_f32_16x16x32_bf16(a1, b2, acc[1][2], 0, 0, 0);
        acc[1][3] = __builtin_amdgcn_mfma_f32_16x16x32_bf16(a1, b3, acc[1][3], 0, 0, 0);
    }

#pragma unroll
    for (int mt = 0; mt < 2; ++mt)
#pragma unroll
        for (int nt = 0; nt < 4; ++nt) {
            int o = oB + wm * 32 + mt * 16 + 4 * g;
            int n = nB + wn * 64 + nt * 16 + l15;
            f32x4 v = acc[mt][nt];
            if (MODE >= 1) v += *(const f32x4*)(bias + o);
            if (MODE == 2) v += *(const f32x4*)(res + (size_t)n * 192 + o);
            if (MODE == 3) {
                unsigned short* op = (unsigned short*)out + (size_t)n * ldOut + colOff + o;
                unsigned long long pk =
                    (unsigned long long)f2bf(v[0])
                  | ((unsigned long long)f2bf(v[1]) << 16)
                  | ((unsigned long long)f2bf(v[2]) << 32)
                  | ((unsigned long long)f2bf(v[3]) << 48);
                *(unsigned long long*)op = pk;
            } else {
                float* op = (float*)out + (size_t)n * ldOut + colOff + o;
                *(f32x4*)op = v;
            }
        }
}

// ---------------------------------------------------------------------------
// In-place L2 norm over 64 head-channels, fp32 pixel-major [n][512].
// ---------------------------------------------------------------------------
__global__ void l2norm_kernel(float* __restrict__ buf)
{
    int t = blockIdx.x * 256 + threadIdx.x;      // kNH*kN threads
    int nh = t & 7, n = t >> 3;
    float* p = buf + (size_t)n * kHID + nh * kHC;
    f32x4 v[16];
    float ss = 0.f;
#pragma unroll
    for (int r = 0; r < 16; ++r) {
        v[r] = *(const f32x4*)(p + r * 4);
        ss += (v[r][0]*v[r][0] + v[r][1]*v[r][1]) + (v[r][2]*v[r][2] + v[r][3]*v[r][3]);
    }
    float sc = 1.0f / fmaxf(sqrtf(ss), 1e-12f);
#pragma unroll
    for (int r = 0; r < 16; ++r) {
        f32x4 o = v[r] * sc;
        *(f32x4*)(p + r * 4) = o;
    }
}

// out[bh][h][hc] = sum_w buf[n][nh*64+hc]
__global__ void sum_w_kernel(const float* __restrict__ buf, float* __restrict__ out)
{
    int h = blockIdx.x, bh = blockIdx.y, hc = threadIdx.x;
    int b = bh >> 3, nh = bh & 7;
    const float* p = buf + (size_t)(b * kHW + h * kW) * kHID + nh * kHC + hc;
    float s = 0.f;
    for (int w = 0; w < kW; ++w) s += p[(size_t)w * kHID];
    out[((size_t)bh * kH + h) * kHC + hc] = s;
}

// out[bh][w][hc] = sum_h
__global__ void sum_h_kernel(const float* __restrict__ buf, float* __restrict__ out)
{
    int w = blockIdx.x, bh = blockIdx.y, hc = threadIdx.x;
    int b = bh >> 3, nh = bh & 7;
    const float* p = buf + (size_t)(b * kHW + w) * kHID + nh * kHC + hc;
    float s = 0.f;
    for (int h = 0; h < kH; ++h) s += p[(size_t)h * kW * kHID];
    out[((size_t)bh * kW + w) * kHC + hc] = s;
}

__global__ void qs_kernel(const float* __restrict__ qsum_h, float* __restrict__ qs)
{
    int bh = blockIdx.x, hc = threadIdx.x;
    float s = 0.f;
    for (int h = 0; h < kH; ++h) s += qsum_h[((size_t)bh * kH + h) * kHC + hc];
    qs[bh * kHC + hc] = s;
}

__global__ void score_kernel(const float* __restrict__ qs, const float* __restrict__ ks,
                             float* __restrict__ sc)
{
    int bh = blockIdx.x; int i = threadIdx.x;   // 128 threads
    float s = 0.f;
    for (int hc = 0; hc < kHC; ++hc) s += qs[bh * kHC + hc] * ks[((size_t)bh * 128 + i) * kHC + hc];
    sc[bh * 128 + i] = s;
}

// ---------------------------------------------------------------------------
// Parallel top-16: block per (bh,sel), 64 lanes, scores in regs, 16 rounds of
// butterfly argmax (tie -> lower index, matching lax.top_k).
// ---------------------------------------------------------------------------
__global__ void topk_kernel(const float* __restrict__ hsc, const float* __restrict__ wsc,
                            int* __restrict__ hidx, int* __restrict__ widx)
{
    int bh = blockIdx.x >> 1, sel = blockIdx.x & 1;
    const float* s = (sel ? wsc : hsc) + bh * 128;
    int* out = (sel ? widx : hidx) + bh * kP;
    int lane = threadIdx.x;
    float v0 = s[lane], v1 = s[lane + 64];
    int i0 = lane, i1 = lane + 64;
    for (int p = 0; p < kP; ++p) {
        float bv; int bi;
        if (v1 > v0) { bv = v1; bi = i1; } else { bv = v0; bi = i0; }
#pragma unroll
        for (int off = 1; off < 64; off <<= 1) {
            float ov = __shfl_xor(bv, off);
            int   oi = __shfl_xor(bi, off);
            if (ov > bv || (ov == bv && oi < bi)) { bv = ov; bi = oi; }
        }
        if (lane == 0) out[p] = bi;
        if (i0 == bi) v0 = -INFINITY;
        if (i1 == bi) v1 = -INFINITY;
    }
}

// ---------------------------------------------------------------------------
// Gather kf bf16 [bh][256][64] from fp32 KP; lazy-project vfT bf16 [bh][64][256].
// ---------------------------------------------------------------------------
__global__ void gather_kv_kernel(const float* __restrict__ kp, const unsigned short* __restrict__ xnb,
                                 const float* __restrict__ wv,
                                 const int* __restrict__ hidx, const int* __restrict__ widx,
                                 unsigned short* __restrict__ kf, unsigned short* __restrict__ vfT)
{
    int bh = blockIdx.y, p1 = blockIdx.x;
    int b = bh >> 3, nh = bh & 7;
    int hc = threadIdx.x & 63, pg = threadIdx.x >> 6;
    int hrow = hidx[bh * kP + p1];
    int o = nh * kHC + hc;
    const float* wvp = wv + (size_t)o * kC;
    for (int p2 = pg; p2 < kP; p2 += 4) {
        int wcol = widx[bh * kP + p2];
        int n = b * kHW + hrow * kW + wcol;
        int kidx = p1 * kP + p2;
        kf[((size_t)bh * 256 + kidx) * 64 + hc] =
            f2bf(kp[(size_t)n * kHID + nh * kHC + hc]);
        const unsigned int* xr = (const unsigned int*)(xnb + (size_t)n * kC);
        float s = 0.f;
        for (int c2 = 0; c2 < kC / 2; ++c2) {
            unsigned int u = xr[c2];
            s += wvp[c2 * 2]     * bf2f((unsigned short)(u & 0xffff));
            s += wvp[c2 * 2 + 1] * bf2f((unsigned short)(u >> 16));
        }
        vfT[((size_t)bh * 64 + hc) * 256 + kidx] = f2bf(s);
    }
}

// ---------------------------------------------------------------------------
// MFMA attention. Block = 64 queries x 1 head, 4 waves.
// S^T = K.Q^T, P = exp(S) (|s|<=1, no max), O^T = V^T.P. Q read directly from
// global fp32 (L1-shared across waves); P bounced via XOR-swizzled LDS.
// Output written bf16 pixel-major into OB [n][512].
// ---------------------------------------------------------------------------
__global__ __launch_bounds__(256) void attn_kernel(
    const float* __restrict__ qp, unsigned short* __restrict__ ob,
    const unsigned short* __restrict__ kf, const unsigned short* __restrict__ vfT)
{
    __shared__ unsigned short pls[64 * 264];
    __shared__ float lred[4][4][16];

    int bh = blockIdx.y; int b = bh >> 3, nh = bh & 7;
    int n0 = b * kHW + blockIdx.x * 64;
    int tid = threadIdx.x;
    int w = tid >> 6, lane = tid & 63, l15 = lane & 15, g = lane >> 4;

    // B-fragments of Q^T straight from global fp32 -> bf16
    bf16x8 bq[4][2];
#pragma unroll
    for (int nt = 0; nt < 4; ++nt)
#pragma unroll
        for (int kt = 0; kt < 2; ++kt) {
            const float* src = qp + (size_t)(n0 + nt * 16 + l15) * kHID + nh * kHC + kt * 32 + 8 * g;
            f32x4 f0 = *(const f32x4*)src;
            f32x4 f1 = *(const f32x4*)(src + 4);
            bf16x8 r;
            r[0] = (short)f2bf(f0[0]); r[1] = (short)f2bf(f0[1]);
            r[2] = (short)f2bf(f0[2]); r[3] = (short)f2bf(f0[3]);
            r[4] = (short)f2bf(f1[0]); r[5] = (short)f2bf(f1[1]);
            r[6] = (short)f2bf(f1[2]); r[7] = (short)f2bf(f1[3]);
            bq[nt][kt] = r;
        }

    const unsigned short* kfb = kf + (size_t)bh * 256 * 64;
    bf16x8 ak[4][2];
#pragma unroll
    for (int mt = 0; mt < 4; ++mt)
#pragma unroll
        for (int kt = 0; kt < 2; ++kt)
            ak[mt][kt] = *(const bf16x8*)&kfb[(size_t)(w * 64 + mt * 16 + l15) * 64 + kt * 32 + 8 * g];

    f32x4 acc[4][4];
#pragma unroll
    for (int mt = 0; mt < 4; ++mt)
#pragma unroll
        for (int nt = 0; nt < 4; ++nt) acc[mt][nt] = (f32x4){0.f,0.f,0.f,0.f};

#pragma unroll
    for (int kt = 0; kt < 2; ++kt)
#pragma unroll
        for (int mt = 0; mt < 4; ++mt)
#pragma unroll
            for (int nt = 0; nt < 4; ++nt)
                acc[mt][nt] = __builtin_amdgcn_mfma_f32_16x16x32_bf16(
                    ak[mt][kt], bq[nt][kt], acc[mt][nt], 0, 0, 0);

    float lpart[4] = {0.f, 0.f, 0.f, 0.f};
#pragma unroll
    for (int mt = 0; mt < 4; ++mt)
#pragma unroll
        for (int nt = 0; nt < 4; ++nt) {
            float e0 = __expf(acc[mt][nt][0]);
            float e1 = __expf(acc[mt][nt][1]);
            float e2 = __expf(acc[mt][nt][2]);
            float e3 = __expf(acc[mt][nt][3]);
            lpart[nt] += (e0 + e1) + (e2 + e3);
            int qq = nt * 16 + l15;
            int k0 = w * 64 + mt * 16 + 4 * g;
            int kx = k0 ^ ((qq & 7) << 3);
            unsigned int lo = f2bf(e0) | ((unsigned int)f2bf(e1) << 16);
            unsigned int hi = f2bf(e2) | ((unsigned int)f2bf(e3) << 16);
            unsigned int* p = (unsigned int*)&pls[qq * 264 + kx];
            p[0] = lo; p[1] = hi;
        }
#pragma unroll
    for (int nt = 0; nt < 4; ++nt) {
        lpart[nt] += __shfl_xor(lpart[nt], 16);
        lpart[nt] += __shfl_xor(lpart[nt], 32);
    }
    if (g == 0)
#pragma unroll
        for (int nt = 0; nt < 4; ++nt) lred[w][nt][l15] = lpart[nt];
    __syncthreads();

    const unsigned short* vfb = vfT + (size_t)bh * 64 * 256;
    f32x4 oacc[4];
#pragma unroll
    for (int nt = 0; nt < 4; ++nt) oacc[nt] = (f32x4){0.f,0.f,0.f,0.f};

#pragma unroll
    for (int ks = 0; ks < 8; ++ks) {
        bf16x8 av = *(const bf16x8*)&vfb[(size_t)(w * 16 + l15) * 256 + ks * 32 + 8 * g];
#pragma unroll
        for (int nt = 0; nt < 4; ++nt) {
            int qq = nt * 16 + l15;
            int kx = (ks * 32 + 8 * g) ^ ((qq & 7) << 3);
            bf16x8 bp = *(const bf16x8*)&pls[qq * 264 + kx];
            oacc[nt] = __builtin_amdgcn_mfma_f32_16x16x32_bf16(av, bp, oacc[nt], 0, 0, 0);
        }
    }

#pragma unroll
    for (int nt = 0; nt < 4; ++nt) {
        float l = lred[0][nt][l15] + lred[1][nt][l15] + lred[2][nt][l15] + lred[3][nt][l15];
        float inv = 1.0f / l;
        int qq = nt * 16 + l15;
        int hc0 = w * 16 + 4 * g;
        unsigned long long pk =
            (unsigned long long)f2bf(oacc[nt][0] * inv)
          | ((unsigned long long)f2bf(oacc[nt][1] * inv) << 16)
          | ((unsigned long long)f2bf(oacc[nt][2] * inv) << 32)
          | ((unsigned long long)f2bf(oacc[nt][3] * inv) << 48);
        *(unsigned long long*)(ob + (size_t)(n0 + qq) * kHID + nh * kHC + hc0) = pk;
    }
}

// ---------------------------------------------------------------------------
// Depthwise 3x3 SAME conv, pixel-major. In fp32 [n][192]; out bf16 (to CAT) or
// fp32. Thread = (pixel, 4-channel group).
// ---------------------------------------------------------------------------
template<int OUTBF16>
__global__ void dwconv_pm_kernel(const float* __restrict__ in, void* __restrict__ out,
                                 const int ldOut, const int colOff,
                                 const float* __restrict__ wt, const float* __restrict__ bias)
{
    int idx = blockIdx.x * 256 + threadIdx.x;      // kN*48
    int n = idx / 48;
    int c0 = (idx - n * 48) * 4;
    int hw = n & (kHW - 1);
    int h = hw >> 7, ww = hw & 127;
    f32x4 s = *(const f32x4*)(bias + c0);
#pragma unroll
    for (int dy = -1; dy <= 1; ++dy) {
        int hh = h + dy;
        if (hh < 0 || hh >= kH) continue;
#pragma unroll
        for (int dx = -1; dx <= 1; ++dx) {
            int wx = ww + dx;
            if (wx < 0 || wx >= kW) continue;
            f32x4 v = *(const f32x4*)(in + (size_t)(n + dy * kW + dx) * kC + c0);
            int t = (dy + 1) * 3 + (dx + 1);
            s[0] += v[0] * wt[(c0 + 0) * 9 + t];
            s[1] += v[1] * wt[(c0 + 1) * 9 + t];
            s[2] += v[2] * wt[(c0 + 2) * 9 + t];
            s[3] += v[3] * wt[(c0 + 3) * 9 + t];
        }
    }
    if (OUTBF16) {
        unsigned short* op = (unsigned short*)out + (size_t)n * ldOut + colOff + c0;
        unsigned long long pk =
            (unsigned long long)f2bf(s[0])
          | ((unsigned long long)f2bf(s[1]) << 16)
          | ((unsigned long long)f2bf(s[2]) << 32)
          | ((unsigned long long)f2bf(s[3]) << 48);
        *(unsigned long long*)op = pk;
    } else {
        *(f32x4*)((float*)out + (size_t)n * ldOut + colOff + c0) = s;
    }
}

// ---------------------------------------------------------------------------
// Instance-norm stats, pixel-major input: per-64-pixel-chunk partial sums,
// atomically accumulated into acc[b][c][2]. Block = 192 threads (one per c).
// ---------------------------------------------------------------------------
__global__ void istats_pm_kernel(const float* __restrict__ in, float* __restrict__ acc)
{
    int n0 = blockIdx.x * 64;
    int b = n0 >> 14;
    int c = threadIdx.x;
    float s = 0.f, ss = 0.f;
    for (int p = 0; p < 64; ++p) {
        float v = in[(size_t)(n0 + p) * kC + c];
        s += v; ss += v * v;
    }
    atomicAdd(&acc[(size_t)(b * kC + c) * 2],     s);
    atomicAdd(&acc[(size_t)(b * kC + c) * 2 + 1], ss);
}

__global__ void istats_fin_kernel(const float* __restrict__ acc, float* __restrict__ stats)
{
    int t = threadIdx.x;           // 384
    int c = t >> 1, b = t & 1;
    float s  = acc[(size_t)(b * kC + c) * 2];
    float ss = acc[(size_t)(b * kC + c) * 2 + 1];
    float m = s * (1.0f / kHW);
    float var = ss * (1.0f / kHW) - m * m;
    stats[(c * 2 + b) * 2]     = m;
    stats[(c * 2 + b) * 2 + 1] = rsqrtf(var + kEPS);
}

// ---------------------------------------------------------------------------
// apply: MODE 0: gelu(inorm(in)) -> fp32 out.  MODE 1: gelu(inorm(in)) + add -> bf16 out.
// ---------------------------------------------------------------------------
template<int MODE>
__global__ void apply_pm_kernel(const float* __restrict__ in, const float* __restrict__ stats,
                                void* __restrict__ out, const float* __restrict__ addsrc)
{
    int idx = blockIdx.x * 256 + threadIdx.x;      // kN*48
    int n = idx / 48;
    int c0 = (idx - n * 48) * 4;
    int b = n >> 14;
    f32x4 v = *(const f32x4*)(in + (size_t)n * kC + c0);
    f32x4 r;
#pragma unroll
    for (int j = 0; j < 4; ++j) {
        int cb = (c0 + j) * 2 + b;
        float m = stats[cb * 2], rs = stats[cb * 2 + 1];
        float x = (v[j] - m) * rs;
        r[j] = 0.5f * x * (1.0f + erff(x * 0.70710678118654752f));
    }
    if (MODE == 1) {
        r += *(const f32x4*)(addsrc + (size_t)n * kC + c0);
        unsigned short* op = (unsigned short*)out + (size_t)n * kC + c0;
        unsigned long long pk =
            (unsigned long long)f2bf(r[0])
          | ((unsigned long long)f2bf(r[1]) << 16)
          | ((unsigned long long)f2bf(r[2]) << 32)
          | ((unsigned long long)f2bf(r[3]) << 48);
        *(unsigned long long*)op = pk;
    } else {
        *(f32x4*)((float*)out + (size_t)n * kC + c0) = r;
    }
}

// Final inorm, pixel-major fp32 in -> NCHW fp32 d_out (coalesced writes).
__global__ void final_kernel(const float* __restrict__ in, const float* __restrict__ stats,
                             float* __restrict__ out)
{
    int id = blockIdx.x * 256 + threadIdx.x;       // kC*kN/4
    int oid = id * 4;
    int q = oid >> 14;            // b*192 + c
    int hw = oid & (kHW - 1);
    int b = (q >= kC) ? 1 : 0;
    int c = q - b * kC;
    int cb = c * 2 + b;
    float m = stats[cb * 2], rs = stats[cb * 2 + 1];
    int n = b * kHW + hw;
    f32x4 o;
#pragma unroll
    for (int j = 0; j < 4; ++j)
        o[j] = (in[(size_t)(n + j) * kC + c] - m) * rs;
    *(f32x4*)(out + (size_t)oid) = o;
}

// ---------------------------------------------------------------------------
extern "C" void kernel_launch(void* const* d_in, const int* in_sizes, int n_in,
                              void* d_out, int out_size, void* d_ws, size_t ws_size,
                              hipStream_t stream)
{
    const float* x     = (const float*)d_in[0];
    const float* ln1_g = (const float*)d_in[1];
    const float* ln1_b = (const float*)d_in[2];
    const float* wq    = (const float*)d_in[3];
    const float* wk    = (const float*)d_in[4];
    const float* wv    = (const float*)d_in[5];
    const float* wo    = (const float*)d_in[6];
    const float* bo    = (const float*)d_in[7];
    const float* dw_w  = (const float*)d_in[8];
    const float* dw_b  = (const float*)d_in[9];
    const float* mlp_w = (const float*)d_in[10];
    const float* mlp_b = (const float*)d_in[11];
    const float* ln2_g = (const float*)d_in[12];
    const float* ln2_b = (const float*)d_in[13];
    const float* c1_w  = (const float*)d_in[14];
    const float* c1_b  = (const float*)d_in[15];
    const float* res_w = (const float*)d_in[16];
    const float* res_b = (const float*)d_in[17];
    const float* c2_w  = (const float*)d_in[18];
    const float* c2_b  = (const float*)d_in[19];

    char* base = (char*)d_ws;
    float* XP   = (float*)(base);                        // 25165824 B fp32 [n][192]
    unsigned short* XNb = (unsigned short*)(base + 25165824);   // 12582912 B bf16 [n][192]
    float* QP   = (float*)(base + 37748736);             // 67108864 B fp32 [n][512]
    float* F    = QP;                                    // fp32 [n][192] (after attn)
    float* T2   = QP;                                    // fp32 [n][192] (after ln2)
    float* Y2   = (float*)(base + 62914560);             // fp32 [n][192]
    float* KP   = (float*)(base + 104857600);            // 67108864 B fp32 [n][512]
    unsigned short* OB = (unsigned short*)KP;            // bf16 [n][512] (after gather)
    float* T1   = (float*)(base + 138412032);            // fp32 [n][192]; later R
    unsigned short* CATb = (unsigned short*)(base + 171966464); // 25165824 B bf16 [n][384]
    unsigned short* Y3   = CATb;                         // bf16 [n][192] (after mlp)
    char* sm = base + 197132288;
    float* qsum_h = (float*)(sm);                 sm += 524288;
    float* ksum_h = (float*)(sm);                 sm += 524288;
    float* ksum_w = (float*)(sm);                 sm += 524288;
    float* qs     = (float*)(sm);                 sm += 4096;
    float* hsc    = (float*)(sm);                 sm += 8192;
    float* wsc    = (float*)(sm);                 sm += 8192;
    float* stats  = (float*)(sm);                 sm += 3072;
    float* acc0   = (float*)(sm);                 sm += 3072;
    float* acc1   = (float*)(sm);                 sm += 3072;
    float* acc2   = (float*)(sm);                 sm += 3072;
    unsigned short* kf   = (unsigned short*)(sm); sm += 524288;
    unsigned short* vfT  = (unsigned short*)(sm); sm += 524288;
    unsigned short* wqb  = (unsigned short*)(sm); sm += 196608;
    unsigned short* wkb  = (unsigned short*)(sm); sm += 196608;
    unsigned short* wob  = (unsigned short*)(sm); sm += 196608;
    unsigned short* mlpb = (unsigned short*)(sm); sm += 147456;
    unsigned short* c1b  = (unsigned short*)(sm); sm += 73728;
    unsigned short* c2b  = (unsigned short*)(sm); sm += 73728;
    int* hidx = (int*)(sm);                       sm += 1024;
    int* widx = (int*)(sm);

    // --- prep ---
    zero_kernel<<<9, 256, 0, stream>>>(acc0, 2304);   // acc0..acc2 contiguous
    cvt_kernel<<<384, 256, 0, stream>>>(wq,    wqb,  kHID * kC);
    cvt_kernel<<<384, 256, 0, stream>>>(wk,    wkb,  kHID * kC);
    cvt_kernel<<<384, 256, 0, stream>>>(wo,    wob,  kC * kHID);
    cvt_kernel<<<288, 256, 0, stream>>>(mlp_w, mlpb, kC * 2 * kC);
    cvt_kernel<<<144, 256, 0, stream>>>(c1_w,  c1b,  kC * kC);
    cvt_kernel<<<144, 256, 0, stream>>>(c2_w,  c2b,  kC * kC);
    transpose_x_kernel<<<dim3(kHW / 64, 3, kB), 256, 0, stream>>>(x, XP);

    // --- attention branch ---
    ln_pm_kernel<<<kN / 256, 256, 0, stream>>>(XP, XNb, ln1_g, ln1_b);
    mgemm_kernel<0><<<dim3(kN / 128, kHID / 64), 256, 0, stream>>>(wqb, XNb, kC, QP, kHID, 0, nullptr, nullptr);
    mgemm_kernel<0><<<dim3(kN / 128, kHID / 64), 256, 0, stream>>>(wkb, XNb, kC, KP, kHID, 0, nullptr, nullptr);
    l2norm_kernel<<<(kNH * kN) / 256, 256, 0, stream>>>(QP);
    l2norm_kernel<<<(kNH * kN) / 256, 256, 0, stream>>>(KP);
    sum_w_kernel<<<dim3(kH, 16), 64, 0, stream>>>(QP, qsum_h);
    sum_w_kernel<<<dim3(kH, 16), 64, 0, stream>>>(KP, ksum_h);
    sum_h_kernel<<<dim3(kW, 16), 64, 0, stream>>>(KP, ksum_w);
    qs_kernel<<<16, 64, 0, stream>>>(qsum_h, qs);
    score_kernel<<<16, 128, 0, stream>>>(qs, ksum_h, hsc);
    score_kernel<<<16, 128, 0, stream>>>(qs, ksum_w, wsc);
    topk_kernel<<<32, 64, 0, stream>>>(hsc, wsc, hidx, widx);
    gather_kv_kernel<<<dim3(kP, 16), 256, 0, stream>>>(KP, XNb, wv, hidx, widx, kf, vfT);
    attn_kernel<<<dim3(kHW / 64, 16), 256, 0, stream>>>(QP, OB, kf, vfT);
    mgemm_kernel<3><<<dim3(kN / 128, kC / 64), 256, 0, stream>>>(wob, OB, kHID, CATb, 2 * kC, kC, bo, nullptr);

    // --- local branch + mlp ---
    dwconv_pm_kernel<1><<<(kN * 48) / 256, 256, 0, stream>>>(XP, CATb, 2 * kC, 0, dw_w, dw_b);
    mgemm_kernel<2><<<dim3(kN / 128, kC / 64), 256, 0, stream>>>(mlpb, CATb, 2 * kC, F, kC, 0, mlp_b, XP);

    // --- tail ---
    ln_pm_kernel<<<kN / 256, 256, 0, stream>>>(F, XNb, ln2_g, ln2_b);          // Y1 = XNb
    mgemm_kernel<1><<<dim3(kN / 128, kC / 64), 256, 0, stream>>>(c1b, XNb, kC, T1, kC, 0, c1_b, nullptr);
    istats_pm_kernel<<<kN / 64, 192, 0, stream>>>(T1, acc0);
    istats_fin_kernel<<<1, 384, 0, stream>>>(acc0, stats);
    apply_pm_kernel<0><<<(kN * 48) / 256, 256, 0, stream>>>(T1, stats, Y2, nullptr);
    dwconv_pm_kernel<0><<<(kN * 48) / 256, 256, 0, stream>>>(Y2, T1, kC, 0, res_w, res_b);  // R = T1
    istats_pm_kernel<<<kN / 64, 192, 0, stream>>>(T1, acc1);
    istats_fin_kernel<<<1, 384, 0, stream>>>(acc1, stats);
    apply_pm_kernel<1><<<(kN * 48) / 256, 256, 0, stream>>>(T1, stats, Y3, Y2);
    mgemm_kernel<1><<<dim3(kN / 128, kC / 64), 256, 0, stream>>>(c2b, Y3, kC, T2, kC, 0, c2_b, nullptr);
    istats_pm_kernel<<<kN / 64, 192, 0, stream>>>(T2, acc2);
    istats_fin_kernel<<<1, 384, 0, stream>>>(acc2, stats);
    final_kernel<<<(kC * kN / 4) / 256, 256, 0, stream>>>(T2, stats, (float*)d_out);
}

// Round 4
// 614.612 us; speedup vs baseline: 3.2987x; 1.2250x over previous
//
#include <hip/hip_runtime.h>
#include <math.h>

constexpr int kC   = 192;
constexpr int kNH  = 8;
constexpr int kHC  = 64;
constexpr int kHID = 512;
constexpr int kP   = 16;
constexpr int kB   = 2;
constexpr int kH   = 128;
constexpr int kW   = 128;
constexpr int kHW  = kH * kW;      // 16384
constexpr int kN   = kB * kHW;     // 32768
constexpr float kEPS = 1e-5f;

typedef __attribute__((ext_vector_type(8))) short bf16x8;
typedef __attribute__((ext_vector_type(4))) float f32x4;

__device__ inline unsigned short f2bf(float f) {
    unsigned int u = __builtin_bit_cast(unsigned int, f);
    unsigned int r = (u + 0x7FFFu + ((u >> 16) & 1u)) >> 16;   // RNE
    return (unsigned short)r;
}
__device__ inline float bf2f(unsigned short u) {
    return __builtin_bit_cast(float, (unsigned int)u << 16);
}
__device__ inline unsigned long long pk4(float a, float b, float c, float d) {
    return (unsigned long long)f2bf(a)
         | ((unsigned long long)f2bf(b) << 16)
         | ((unsigned long long)f2bf(c) << 32)
         | ((unsigned long long)f2bf(d) << 48);
}

__global__ void zero_kernel(float* __restrict__ p, int n)
{
    int i = blockIdx.x * 256 + threadIdx.x;
    if (i < n) p[i] = 0.f;
}

__global__ void cvt_kernel(const float* __restrict__ src, unsigned short* __restrict__ dst, int n)
{
    int i = blockIdx.x * 256 + threadIdx.x;
    if (i < n) dst[i] = f2bf(src[i]);
}

// ---------------------------------------------------------------------------
// Transpose x NCHW fp32 -> XP pixel-major fp32 [n][192]
// ---------------------------------------------------------------------------
__global__ __launch_bounds__(256) void transpose_x_kernel(const float* __restrict__ x,
                                                          float* __restrict__ xp)
{
    __shared__ float tile[64][65];
    int hw0 = blockIdx.x * 64;
    int c0  = blockIdx.y * 64;
    int b   = blockIdx.z;
    int tid = threadIdx.x;
    for (int i = tid; i < 64 * 64; i += 256) {
        int row = i >> 6, p = i & 63;
        tile[row][p] = x[((size_t)(b * kC + c0 + row)) * kHW + hw0 + p];
    }
    __syncthreads();
    for (int i = tid; i < 64 * 64; i += 256) {
        int pp = i >> 6, cc = i & 63;
        xp[((size_t)(b * kHW + hw0 + pp)) * kC + c0 + cc] = tile[cc][pp];
    }
}

// ---------------------------------------------------------------------------
// LayerNorm over channels, pixel-major fp32 in -> bf16 out.
// ---------------------------------------------------------------------------
__global__ void ln_pm_kernel(const float* __restrict__ in, unsigned short* __restrict__ out,
                             const float* __restrict__ g, const float* __restrict__ bb)
{
    int n = blockIdx.x * 256 + threadIdx.x;
    if (n >= kN) return;
    const f32x4* ip = (const f32x4*)(in + (size_t)n * kC);
    float s = 0.f, ss = 0.f;
#pragma unroll
    for (int r = 0; r < 48; ++r) {
        f32x4 v = ip[r];
        s  += (v[0] + v[1]) + (v[2] + v[3]);
        ss += (v[0]*v[0] + v[1]*v[1]) + (v[2]*v[2] + v[3]*v[3]);
    }
    float m  = s * (1.0f / kC);
    float var = ss * (1.0f / kC) - m * m;
    float rs = rsqrtf(var + kEPS);
    unsigned short* op = out + (size_t)n * kC;
#pragma unroll
    for (int r = 0; r < 48; ++r) {
        f32x4 v = ip[r];
        f32x4 gg = *(const f32x4*)(g + r * 4);
        f32x4 bv = *(const f32x4*)(bb + r * 4);
        *(unsigned long long*)(op + r * 4) =
            pk4((v[0]-m)*rs*gg[0] + bv[0], (v[1]-m)*rs*gg[1] + bv[1],
                (v[2]-m)*rs*gg[2] + bv[2], (v[3]-m)*rs*gg[3] + bv[3]);
    }
}

// ---------------------------------------------------------------------------
// MFMA GEMM, LDS-free. A [O][K] bf16 (weights), B [n][K] bf16 pixel-major.
// Block: 4 waves (2 o x 2 n), tile 64 o x 128 n.
// MODE: 1 = f32+bias; 2 = f32+bias+res(fp32 [n][192]); 3 = bf16+bias.
// ---------------------------------------------------------------------------
template<int MODE>
__global__ __launch_bounds__(256) void mgemm_kernel(
    const unsigned short* __restrict__ A, const unsigned short* __restrict__ B,
    const int K, void* __restrict__ out, const int ldOut, const int colOff,
    const float* __restrict__ bias, const float* __restrict__ res)
{
    int nB = blockIdx.x * 128, oB = blockIdx.y * 64;
    int w = threadIdx.x >> 6, lane = threadIdx.x & 63;
    int l15 = lane & 15, g = lane >> 4;
    int wm = w & 1, wn = w >> 1;
    const unsigned short* Ap = A + (size_t)(oB + wm * 32 + l15) * K + 8 * g;
    const unsigned short* Bp = B + (size_t)(nB + wn * 64 + l15) * K + 8 * g;

    f32x4 acc[2][4];
#pragma unroll
    for (int mt = 0; mt < 2; ++mt)
#pragma unroll
        for (int nt = 0; nt < 4; ++nt) acc[mt][nt] = (f32x4){0.f,0.f,0.f,0.f};

#pragma unroll 2
    for (int k = 0; k < K; k += 32) {
        bf16x8 a0 = *(const bf16x8*)(Ap + k);
        bf16x8 a1 = *(const bf16x8*)(Ap + (size_t)16 * K + k);
        bf16x8 b0 = *(const bf16x8*)(Bp + k);
        bf16x8 b1 = *(const bf16x8*)(Bp + (size_t)16 * K + k);
        bf16x8 b2 = *(const bf16x8*)(Bp + (size_t)32 * K + k);
        bf16x8 b3 = *(const bf16x8*)(Bp + (size_t)48 * K + k);
        acc[0][0] = __builtin_amdgcn_mfma_f32_16x16x32_bf16(a0, b0, acc[0][0], 0, 0, 0);
        acc[0][1] = __builtin_amdgcn_mfma_f32_16x16x32_bf16(a0, b1, acc[0][1], 0, 0, 0);
        acc[0][2] = __builtin_amdgcn_mfma_f32_16x16x32_bf16(a0, b2, acc[0][2], 0, 0, 0);
        acc[0][3] = __builtin_amdgcn_mfma_f32_16x16x32_bf16(a0, b3, acc[0][3], 0, 0, 0);
        acc[1][0] = __builtin_amdgcn_mfma_f32_16x16x32_bf16(a1, b0, acc[1][0], 0, 0, 0);
        acc[1][1] = __builtin_amdgcn_mfma_f32_16x16x32_bf16(a1, b1, acc[1][1], 0, 0, 0);
        acc[1][2] = __builtin_amdgcn_mfma_f32_16x16x32_bf16(a1, b2, acc[1][2], 0, 0, 0);
        acc[1][3] = __builtin_amdgcn_mfma_f32_16x16x32_bf16(a1, b3, acc[1][3], 0, 0, 0);
    }

#pragma unroll
    for (int mt = 0; mt < 2; ++mt)
#pragma unroll
        for (int nt = 0; nt < 4; ++nt) {
            int o = oB + wm * 32 + mt * 16 + 4 * g;
            int n = nB + wn * 64 + nt * 16 + l15;
            f32x4 v = acc[mt][nt];
            v += *(const f32x4*)(bias + o);
            if (MODE == 2) v += *(const f32x4*)(res + (size_t)n * 192 + o);
            if (MODE == 3) {
                unsigned short* op = (unsigned short*)out + (size_t)n * ldOut + colOff + o;
                *(unsigned long long*)op = pk4(v[0], v[1], v[2], v[3]);
            } else {
                float* op = (float*)out + (size_t)n * ldOut + colOff + o;
                *(f32x4*)op = v;
            }
        }
}

// ---------------------------------------------------------------------------
// q/k projection GEMM with fused per-head L2 norm. BM=64 == one head, so the
// norm over head-channels is block-local: shfl over g, LDS over the 2 o-waves.
// Output bf16 [n][512].
// ---------------------------------------------------------------------------
__global__ __launch_bounds__(256) void mgemm_l2_kernel(
    const unsigned short* __restrict__ A, const unsigned short* __restrict__ B,
    const int K, unsigned short* __restrict__ out)
{
    __shared__ float ssq[2][2][4][16];   // [wm][wn][nt][l15]
    int nB = blockIdx.x * 128, oB = blockIdx.y * 64;
    int w = threadIdx.x >> 6, lane = threadIdx.x & 63;
    int l15 = lane & 15, g = lane >> 4;
    int wm = w & 1, wn = w >> 1;
    const unsigned short* Ap = A + (size_t)(oB + wm * 32 + l15) * K + 8 * g;
    const unsigned short* Bp = B + (size_t)(nB + wn * 64 + l15) * K + 8 * g;

    f32x4 acc[2][4];
#pragma unroll
    for (int mt = 0; mt < 2; ++mt)
#pragma unroll
        for (int nt = 0; nt < 4; ++nt) acc[mt][nt] = (f32x4){0.f,0.f,0.f,0.f};

#pragma unroll 2
    for (int k = 0; k < K; k += 32) {
        bf16x8 a0 = *(const bf16x8*)(Ap + k);
        bf16x8 a1 = *(const bf16x8*)(Ap + (size_t)16 * K + k);
        bf16x8 b0 = *(const bf16x8*)(Bp + k);
        bf16x8 b1 = *(const bf16x8*)(Bp + (size_t)16 * K + k);
        bf16x8 b2 = *(const bf16x8*)(Bp + (size_t)32 * K + k);
        bf16x8 b3 = *(const bf16x8*)(Bp + (size_t)48 * K + k);
        acc[0][0] = __builtin_amdgcn_mfma_f32_16x16x32_bf16(a0, b0, acc[0][0], 0, 0, 0);
        acc[0][1] = __builtin_amdgcn_mfma_f32_16x16x32_bf16(a0, b1, acc[0][1], 0, 0, 0);
        acc[0][2] = __builtin_amdgcn_mfma_f32_16x16x32_bf16(a0, b2, acc[0][2], 0, 0, 0);
        acc[0][3] = __builtin_amdgcn_mfma_f32_16x16x32_bf16(a0, b3, acc[0][3], 0, 0, 0);
        acc[1][0] = __builtin_amdgcn_mfma_f32_16x16x32_bf16(a1, b0, acc[1][0], 0, 0, 0);
        acc[1][1] = __builtin_amdgcn_mfma_f32_16x16x32_bf16(a1, b1, acc[1][1], 0, 0, 0);
        acc[1][2] = __builtin_amdgcn_mfma_f32_16x16x32_bf16(a1, b2, acc[1][2], 0, 0, 0);
        acc[1][3] = __builtin_amdgcn_mfma_f32_16x16x32_bf16(a1, b3, acc[1][3], 0, 0, 0);
    }

    // per-pixel sum of squares over this wave's 32 o-channels
#pragma unroll
    for (int nt = 0; nt < 4; ++nt) {
        float s = 0.f;
#pragma unroll
        for (int mt = 0; mt < 2; ++mt) {
            f32x4 a = acc[mt][nt];
            s += (a[0]*a[0] + a[1]*a[1]) + (a[2]*a[2] + a[3]*a[3]);
        }
        s += __shfl_xor(s, 16);
        s += __shfl_xor(s, 32);
        if (g == 0) ssq[wm][wn][nt][l15] = s;
    }
    __syncthreads();

#pragma unroll
    for (int nt = 0; nt < 4; ++nt) {
        float ss = ssq[0][wn][nt][l15] + ssq[1][wn][nt][l15];
        float sc = 1.0f / fmaxf(sqrtf(ss), 1e-12f);
        int n = nB + wn * 64 + nt * 16 + l15;
#pragma unroll
        for (int mt = 0; mt < 2; ++mt) {
            int o = oB + wm * 32 + mt * 16 + 4 * g;
            f32x4 v = acc[mt][nt];
            *(unsigned long long*)(out + (size_t)n * kHID + o) =
                pk4(v[0]*sc, v[1]*sc, v[2]*sc, v[3]*sc);
        }
    }
}

// out[bh][h][hc] = sum_w buf[n][nh*64+hc]   (buf bf16 [n][512])
__global__ void sum_w_kernel(const unsigned short* __restrict__ buf, float* __restrict__ out)
{
    int h = blockIdx.x, bh = blockIdx.y, hc = threadIdx.x;
    int b = bh >> 3, nh = bh & 7;
    const unsigned short* p = buf + (size_t)(b * kHW + h * kW) * kHID + nh * kHC + hc;
    float s = 0.f;
    for (int w = 0; w < kW; ++w) s += bf2f(p[(size_t)w * kHID]);
    out[((size_t)bh * kH + h) * kHC + hc] = s;
}

// out[bh][w][hc] = sum_h
__global__ void sum_h_kernel(const unsigned short* __restrict__ buf, float* __restrict__ out)
{
    int w = blockIdx.x, bh = blockIdx.y, hc = threadIdx.x;
    int b = bh >> 3, nh = bh & 7;
    const unsigned short* p = buf + (size_t)(b * kHW + w) * kHID + nh * kHC + hc;
    float s = 0.f;
    for (int h = 0; h < kH; ++h) s += bf2f(p[(size_t)h * kW * kHID]);
    out[((size_t)bh * kW + w) * kHC + hc] = s;
}

__global__ void qs_kernel(const float* __restrict__ qsum_h, float* __restrict__ qs)
{
    int bh = blockIdx.x, hc = threadIdx.x;
    float s = 0.f;
    for (int h = 0; h < kH; ++h) s += qsum_h[((size_t)bh * kH + h) * kHC + hc];
    qs[bh * kHC + hc] = s;
}

__global__ void score_kernel(const float* __restrict__ qs, const float* __restrict__ ks,
                             float* __restrict__ sc)
{
    int bh = blockIdx.x; int i = threadIdx.x;   // 128 threads
    float s = 0.f;
    for (int hc = 0; hc < kHC; ++hc) s += qs[bh * kHC + hc] * ks[((size_t)bh * 128 + i) * kHC + hc];
    sc[bh * 128 + i] = s;
}

// ---------------------------------------------------------------------------
// Parallel top-16, tie -> lower index (matches lax.top_k).
// ---------------------------------------------------------------------------
__global__ void topk_kernel(const float* __restrict__ hsc, const float* __restrict__ wsc,
                            int* __restrict__ hidx, int* __restrict__ widx)
{
    int bh = blockIdx.x >> 1, sel = blockIdx.x & 1;
    const float* s = (sel ? wsc : hsc) + bh * 128;
    int* out = (sel ? widx : hidx) + bh * kP;
    int lane = threadIdx.x;
    float v0 = s[lane], v1 = s[lane + 64];
    int i0 = lane, i1 = lane + 64;
    for (int p = 0; p < kP; ++p) {
        float bv; int bi;
        if (v1 > v0) { bv = v1; bi = i1; } else { bv = v0; bi = i0; }
#pragma unroll
        for (int off = 1; off < 64; off <<= 1) {
            float ov = __shfl_xor(bv, off);
            int   oi = __shfl_xor(bi, off);
            if (ov > bv || (ov == bv && oi < bi)) { bv = ov; bi = oi; }
        }
        if (lane == 0) out[p] = bi;
        if (i0 == bi) v0 = -INFINITY;
        if (i1 == bi) v1 = -INFINITY;
    }
}

// ---------------------------------------------------------------------------
// Gather kf bf16 [bh][256][64] (u16 copy from bf16 K); lazy-project vfT bf16
// [bh][64][256] from XNb/wv.
// ---------------------------------------------------------------------------
__global__ void gather_kv_kernel(const unsigned short* __restrict__ kpb,
                                 const unsigned short* __restrict__ xnb,
                                 const float* __restrict__ wv,
                                 const int* __restrict__ hidx, const int* __restrict__ widx,
                                 unsigned short* __restrict__ kf, unsigned short* __restrict__ vfT)
{
    int bh = blockIdx.y, p1 = blockIdx.x;
    int b = bh >> 3, nh = bh & 7;
    int hc = threadIdx.x & 63, pg = threadIdx.x >> 6;
    int hrow = hidx[bh * kP + p1];
    int o = nh * kHC + hc;
    const float* wvp = wv + (size_t)o * kC;
    for (int p2 = pg; p2 < kP; p2 += 4) {
        int wcol = widx[bh * kP + p2];
        int n = b * kHW + hrow * kW + wcol;
        int kidx = p1 * kP + p2;
        kf[((size_t)bh * 256 + kidx) * 64 + hc] = kpb[(size_t)n * kHID + nh * kHC + hc];
        const unsigned int* xr = (const unsigned int*)(xnb + (size_t)n * kC);
        float s = 0.f;
        for (int c2 = 0; c2 < kC / 2; ++c2) {
            unsigned int u = xr[c2];
            s += wvp[c2 * 2]     * bf2f((unsigned short)(u & 0xffff));
            s += wvp[c2 * 2 + 1] * bf2f((unsigned short)(u >> 16));
        }
        vfT[((size_t)bh * 64 + hc) * 256 + kidx] = f2bf(s);
    }
}

// ---------------------------------------------------------------------------
// MFMA attention. Block = 64 queries x 1 head, 4 waves.
// Q read as bf16 fragments straight from global. P staged in LDS with row
// stride 272 shorts (136 dwords = 8 mod 32 -> bank-balanced for both the 8B
// writes and 16B reads; no XOR swizzle).
// ---------------------------------------------------------------------------
__global__ __launch_bounds__(256) void attn_kernel(
    const unsigned short* __restrict__ qpb, unsigned short* __restrict__ ob,
    const unsigned short* __restrict__ kf, const unsigned short* __restrict__ vfT)
{
    __shared__ unsigned short pls[64 * 272];
    __shared__ float lred[4][4][16];

    int bh = blockIdx.y; int b = bh >> 3, nh = bh & 7;
    int n0 = b * kHW + blockIdx.x * 64;
    int tid = threadIdx.x;
    int w = tid >> 6, lane = tid & 63, l15 = lane & 15, g = lane >> 4;

    bf16x8 bq[4][2];
#pragma unroll
    for (int nt = 0; nt < 4; ++nt)
#pragma unroll
        for (int kt = 0; kt < 2; ++kt)
            bq[nt][kt] = *(const bf16x8*)(qpb + (size_t)(n0 + nt * 16 + l15) * kHID
                                          + nh * kHC + kt * 32 + 8 * g);

    const unsigned short* kfb = kf + (size_t)bh * 256 * 64;
    bf16x8 ak[4][2];
#pragma unroll
    for (int mt = 0; mt < 4; ++mt)
#pragma unroll
        for (int kt = 0; kt < 2; ++kt)
            ak[mt][kt] = *(const bf16x8*)&kfb[(size_t)(w * 64 + mt * 16 + l15) * 64 + kt * 32 + 8 * g];

    f32x4 acc[4][4];
#pragma unroll
    for (int mt = 0; mt < 4; ++mt)
#pragma unroll
        for (int nt = 0; nt < 4; ++nt) acc[mt][nt] = (f32x4){0.f,0.f,0.f,0.f};

#pragma unroll
    for (int kt = 0; kt < 2; ++kt)
#pragma unroll
        for (int mt = 0; mt < 4; ++mt)
#pragma unroll
            for (int nt = 0; nt < 4; ++nt)
                acc[mt][nt] = __builtin_amdgcn_mfma_f32_16x16x32_bf16(
                    ak[mt][kt], bq[nt][kt], acc[mt][nt], 0, 0, 0);

    float lpart[4] = {0.f, 0.f, 0.f, 0.f};
#pragma unroll
    for (int mt = 0; mt < 4; ++mt)
#pragma unroll
        for (int nt = 0; nt < 4; ++nt) {
            float e0 = __expf(acc[mt][nt][0]);
            float e1 = __expf(acc[mt][nt][1]);
            float e2 = __expf(acc[mt][nt][2]);
            float e3 = __expf(acc[mt][nt][3]);
            lpart[nt] += (e0 + e1) + (e2 + e3);
            int qq = nt * 16 + l15;
            int k0 = w * 64 + mt * 16 + 4 * g;
            *(unsigned long long*)&pls[qq * 272 + k0] = pk4(e0, e1, e2, e3);
        }
#pragma unroll
    for (int nt = 0; nt < 4; ++nt) {
        lpart[nt] += __shfl_xor(lpart[nt], 16);
        lpart[nt] += __shfl_xor(lpart[nt], 32);
    }
    if (g == 0)
#pragma unroll
        for (int nt = 0; nt < 4; ++nt) lred[w][nt][l15] = lpart[nt];
    __syncthreads();

    const unsigned short* vfb = vfT + (size_t)bh * 64 * 256;
    f32x4 oacc[4];
#pragma unroll
    for (int nt = 0; nt < 4; ++nt) oacc[nt] = (f32x4){0.f,0.f,0.f,0.f};

#pragma unroll
    for (int ks = 0; ks < 8; ++ks) {
        bf16x8 av = *(const bf16x8*)&vfb[(size_t)(w * 16 + l15) * 256 + ks * 32 + 8 * g];
#pragma unroll
        for (int nt = 0; nt < 4; ++nt) {
            bf16x8 bp = *(const bf16x8*)&pls[(nt * 16 + l15) * 272 + ks * 32 + 8 * g];
            oacc[nt] = __builtin_amdgcn_mfma_f32_16x16x32_bf16(av, bp, oacc[nt], 0, 0, 0);
        }
    }

#pragma unroll
    for (int nt = 0; nt < 4; ++nt) {
        float l = lred[0][nt][l15] + lred[1][nt][l15] + lred[2][nt][l15] + lred[3][nt][l15];
        float inv = 1.0f / l;
        int qq = nt * 16 + l15;
        int hc0 = w * 16 + 4 * g;
        *(unsigned long long*)(ob + (size_t)(n0 + qq) * kHID + nh * kHC + hc0) =
            pk4(oacc[nt][0] * inv, oacc[nt][1] * inv, oacc[nt][2] * inv, oacc[nt][3] * inv);
    }
}

// ---------------------------------------------------------------------------
// Depthwise 3x3 SAME conv, pixel-major fp32 in.
// ---------------------------------------------------------------------------
template<int OUTBF16>
__global__ void dwconv_pm_kernel(const float* __restrict__ in, void* __restrict__ out,
                                 const int ldOut, const int colOff,
                                 const float* __restrict__ wt, const float* __restrict__ bias)
{
    int idx = blockIdx.x * 256 + threadIdx.x;      // kN*48
    int n = idx / 48;
    int c0 = (idx - n * 48) * 4;
    int hw = n & (kHW - 1);
    int h = hw >> 7, ww = hw & 127;
    f32x4 s = *(const f32x4*)(bias + c0);
#pragma unroll
    for (int dy = -1; dy <= 1; ++dy) {
        int hh = h + dy;
        if (hh < 0 || hh >= kH) continue;
#pragma unroll
        for (int dx = -1; dx <= 1; ++dx) {
            int wx = ww + dx;
            if (wx < 0 || wx >= kW) continue;
            f32x4 v = *(const f32x4*)(in + (size_t)(n + dy * kW + dx) * kC + c0);
            int t = (dy + 1) * 3 + (dx + 1);
            s[0] += v[0] * wt[(c0 + 0) * 9 + t];
            s[1] += v[1] * wt[(c0 + 1) * 9 + t];
            s[2] += v[2] * wt[(c0 + 2) * 9 + t];
            s[3] += v[3] * wt[(c0 + 3) * 9 + t];
        }
    }
    if (OUTBF16) {
        unsigned short* op = (unsigned short*)out + (size_t)n * ldOut + colOff + c0;
        *(unsigned long long*)op = pk4(s[0], s[1], s[2], s[3]);
    } else {
        *(f32x4*)((float*)out + (size_t)n * ldOut + colOff + c0) = s;
    }
}

// ---------------------------------------------------------------------------
// Instance-norm stats via per-chunk atomics.
// ---------------------------------------------------------------------------
__global__ void istats_pm_kernel(const float* __restrict__ in, float* __restrict__ acc)
{
    int n0 = blockIdx.x * 64;
    int b = n0 >> 14;
    int c = threadIdx.x;
    float s = 0.f, ss = 0.f;
    for (int p = 0; p < 64; ++p) {
        float v = in[(size_t)(n0 + p) * kC + c];
        s += v; ss += v * v;
    }
    atomicAdd(&acc[(size_t)(b * kC + c) * 2],     s);
    atomicAdd(&acc[(size_t)(b * kC + c) * 2 + 1], ss);
}

__global__ void istats_fin_kernel(const float* __restrict__ acc, float* __restrict__ stats)
{
    int t = threadIdx.x;           // 384
    int c = t >> 1, b = t & 1;
    float s  = acc[(size_t)(b * kC + c) * 2];
    float ss = acc[(size_t)(b * kC + c) * 2 + 1];
    float m = s * (1.0f / kHW);
    float var = ss * (1.0f / kHW) - m * m;
    stats[(c * 2 + b) * 2]     = m;
    stats[(c * 2 + b) * 2 + 1] = rsqrtf(var + kEPS);
}

// MODE 0: gelu(inorm(in)) -> fp32.  MODE 1: gelu(inorm(in)) + add -> bf16.
template<int MODE>
__global__ void apply_pm_kernel(const float* __restrict__ in, const float* __restrict__ stats,
                                void* __restrict__ out, const float* __restrict__ addsrc)
{
    int idx = blockIdx.x * 256 + threadIdx.x;      // kN*48
    int n = idx / 48;
    int c0 = (idx - n * 48) * 4;
    int b = n >> 14;
    f32x4 v = *(const f32x4*)(in + (size_t)n * kC + c0);
    f32x4 r;
#pragma unroll
    for (int j = 0; j < 4; ++j) {
        int cb = (c0 + j) * 2 + b;
        float m = stats[cb * 2], rs = stats[cb * 2 + 1];
        float x = (v[j] - m) * rs;
        r[j] = 0.5f * x * (1.0f + erff(x * 0.70710678118654752f));
    }
    if (MODE == 1) {
        r += *(const f32x4*)(addsrc + (size_t)n * kC + c0);
        unsigned short* op = (unsigned short*)out + (size_t)n * kC + c0;
        *(unsigned long long*)op = pk4(r[0], r[1], r[2], r[3]);
    } else {
        *(f32x4*)((float*)out + (size_t)n * kC + c0) = r;
    }
}

// Final inorm, pixel-major fp32 in -> NCHW fp32 d_out.
__global__ void final_kernel(const float* __restrict__ in, const float* __restrict__ stats,
                             float* __restrict__ out)
{
    int id = blockIdx.x * 256 + threadIdx.x;       // kC*kN/4
    int oid = id * 4;
    int q = oid >> 14;
    int hw = oid & (kHW - 1);
    int b = (q >= kC) ? 1 : 0;
    int c = q - b * kC;
    int cb = c * 2 + b;
    float m = stats[cb * 2], rs = stats[cb * 2 + 1];
    int n = b * kHW + hw;
    f32x4 o;
#pragma unroll
    for (int j = 0; j < 4; ++j)
        o[j] = (in[(size_t)(n + j) * kC + c] - m) * rs;
    *(f32x4*)(out + (size_t)oid) = o;
}

// ---------------------------------------------------------------------------
extern "C" void kernel_launch(void* const* d_in, const int* in_sizes, int n_in,
                              void* d_out, int out_size, void* d_ws, size_t ws_size,
                              hipStream_t stream)
{
    const float* x     = (const float*)d_in[0];
    const float* ln1_g = (const float*)d_in[1];
    const float* ln1_b = (const float*)d_in[2];
    const float* wq    = (const float*)d_in[3];
    const float* wk    = (const float*)d_in[4];
    const float* wv    = (const float*)d_in[5];
    const float* wo    = (const float*)d_in[6];
    const float* bo    = (const float*)d_in[7];
    const float* dw_w  = (const float*)d_in[8];
    const float* dw_b  = (const float*)d_in[9];
    const float* mlp_w = (const float*)d_in[10];
    const float* mlp_b = (const float*)d_in[11];
    const float* ln2_g = (const float*)d_in[12];
    const float* ln2_b = (const float*)d_in[13];
    const float* c1_w  = (const float*)d_in[14];
    const float* c1_b  = (const float*)d_in[15];
    const float* res_w = (const float*)d_in[16];
    const float* res_b = (const float*)d_in[17];
    const float* c2_w  = (const float*)d_in[18];
    const float* c2_b  = (const float*)d_in[19];

    char* base = (char*)d_ws;
    // region 0: XP fp32 [n][192] (25 MB); later T1/R fp32
    float* XP  = (float*)(base);
    float* T1  = XP;
    // region 1: XNb bf16 [n][192] (12.5 MB) -- xn, later Y1
    unsigned short* XNb = (unsigned short*)(base + 25165824);
    // region 2: QPb bf16 [n][512] (32 MB); later F/T2 fp32 [n][192] (25 MB)
    unsigned short* QPb = (unsigned short*)(base + 37748736);
    float* F  = (float*)QPb;
    float* T2 = (float*)QPb;
    // region 3: KPb bf16 [n][512] (32 MB); OB alias; later Y2 fp32 (25 MB)
    unsigned short* KPb = (unsigned short*)(base + 71303168);
    unsigned short* OB  = KPb;
    float* Y2 = (float*)KPb;
    // region 4: CATb bf16 [n][384] (25 MB); Y3 alias bf16 [n][192]
    unsigned short* CATb = (unsigned short*)(base + 104857600);
    unsigned short* Y3   = CATb;
    // smalls
    char* sm = base + 130023424;
    float* qsum_h = (float*)(sm);                 sm += 524288;
    float* ksum_h = (float*)(sm);                 sm += 524288;
    float* ksum_w = (float*)(sm);                 sm += 524288;
    float* qs     = (float*)(sm);                 sm += 4096;
    float* hsc    = (float*)(sm);                 sm += 8192;
    float* wsc    = (float*)(sm);                 sm += 8192;
    float* stats  = (float*)(sm);                 sm += 3072;
    float* acc0   = (float*)(sm);                 sm += 3072;
    float* acc1   = (float*)(sm);                 sm += 3072;
    float* acc2   = (float*)(sm);                 sm += 3072;
    unsigned short* kf   = (unsigned short*)(sm); sm += 524288;
    unsigned short* vfT  = (unsigned short*)(sm); sm += 524288;
    unsigned short* wqb  = (unsigned short*)(sm); sm += 196608;
    unsigned short* wkb  = (unsigned short*)(sm); sm += 196608;
    unsigned short* wob  = (unsigned short*)(sm); sm += 196608;
    unsigned short* mlpb = (unsigned short*)(sm); sm += 147456;
    unsigned short* c1b  = (unsigned short*)(sm); sm += 73728;
    unsigned short* c2b  = (unsigned short*)(sm); sm += 73728;
    int* hidx = (int*)(sm);                       sm += 1024;
    int* widx = (int*)(sm);

    // --- prep ---
    zero_kernel<<<9, 256, 0, stream>>>(acc0, 2304);   // acc0..acc2 contiguous
    cvt_kernel<<<384, 256, 0, stream>>>(wq,    wqb,  kHID * kC);
    cvt_kernel<<<384, 256, 0, stream>>>(wk,    wkb,  kHID * kC);
    cvt_kernel<<<384, 256, 0, stream>>>(wo,    wob,  kC * kHID);
    cvt_kernel<<<288, 256, 0, stream>>>(mlp_w, mlpb, kC * 2 * kC);
    cvt_kernel<<<144, 256, 0, stream>>>(c1_w,  c1b,  kC * kC);
    cvt_kernel<<<144, 256, 0, stream>>>(c2_w,  c2b,  kC * kC);
    transpose_x_kernel<<<dim3(kHW / 64, 3, kB), 256, 0, stream>>>(x, XP);

    // --- attention branch ---
    ln_pm_kernel<<<kN / 256, 256, 0, stream>>>(XP, XNb, ln1_g, ln1_b);
    mgemm_l2_kernel<<<dim3(kN / 128, kHID / 64), 256, 0, stream>>>(wqb, XNb, kC, QPb);
    mgemm_l2_kernel<<<dim3(kN / 128, kHID / 64), 256, 0, stream>>>(wkb, XNb, kC, KPb);
    sum_w_kernel<<<dim3(kH, 16), 64, 0, stream>>>(QPb, qsum_h);
    sum_w_kernel<<<dim3(kH, 16), 64, 0, stream>>>(KPb, ksum_h);
    sum_h_kernel<<<dim3(kW, 16), 64, 0, stream>>>(KPb, ksum_w);
    qs_kernel<<<16, 64, 0, stream>>>(qsum_h, qs);
    score_kernel<<<16, 128, 0, stream>>>(qs, ksum_h, hsc);
    score_kernel<<<16, 128, 0, stream>>>(qs, ksum_w, wsc);
    topk_kernel<<<32, 64, 0, stream>>>(hsc, wsc, hidx, widx);
    gather_kv_kernel<<<dim3(kP, 16), 256, 0, stream>>>(KPb, XNb, wv, hidx, widx, kf, vfT);
    attn_kernel<<<dim3(kHW / 64, 16), 256, 0, stream>>>(QPb, OB, kf, vfT);
    mgemm_kernel<3><<<dim3(kN / 128, kC / 64), 256, 0, stream>>>(wob, OB, kHID, CATb, 2 * kC, kC, bo, nullptr);

    // --- local branch + mlp ---
    dwconv_pm_kernel<1><<<(kN * 48) / 256, 256, 0, stream>>>(XP, CATb, 2 * kC, 0, dw_w, dw_b);
    mgemm_kernel<2><<<dim3(kN / 128, kC / 64), 256, 0, stream>>>(mlpb, CATb, 2 * kC, F, kC, 0, mlp_b, XP);

    // --- tail ---
    ln_pm_kernel<<<kN / 256, 256, 0, stream>>>(F, XNb, ln2_g, ln2_b);          // Y1 = XNb
    mgemm_kernel<1><<<dim3(kN / 128, kC / 64), 256, 0, stream>>>(c1b, XNb, kC, T1, kC, 0, c1_b, nullptr);
    istats_pm_kernel<<<kN / 64, 192, 0, stream>>>(T1, acc0);
    istats_fin_kernel<<<1, 384, 0, stream>>>(acc0, stats);
    apply_pm_kernel<0><<<(kN * 48) / 256, 256, 0, stream>>>(T1, stats, Y2, nullptr);
    dwconv_pm_kernel<0><<<(kN * 48) / 256, 256, 0, stream>>>(Y2, T1, kC, 0, res_w, res_b);  // R = T1
    istats_pm_kernel<<<kN / 64, 192, 0, stream>>>(T1, acc1);
    istats_fin_kernel<<<1, 384, 0, stream>>>(acc1, stats);
    apply_pm_kernel<1><<<(kN * 48) / 256, 256, 0, stream>>>(T1, stats, Y3, Y2);
    mgemm_kernel<1><<<dim3(kN / 128, kC / 64), 256, 0, stream>>>(c2b, Y3, kC, T2, kC, 0, c2_b, nullptr);
    istats_pm_kernel<<<kN / 64, 192, 0, stream>>>(T2, acc2);
    istats_fin_kernel<<<1, 384, 0, stream>>>(acc2, stats);
    final_kernel<<<(kC * kN / 4) / 256, 256, 0, stream>>>(T2, stats, (float*)d_out);
}

// Round 5
// 580.376 us; speedup vs baseline: 3.4932x; 1.0590x over previous
//
#include <hip/hip_runtime.h>
#include <math.h>

constexpr int kC   = 192;
constexpr int kNH  = 8;
constexpr int kHC  = 64;
constexpr int kHID = 512;
constexpr int kP   = 16;
constexpr int kB   = 2;
constexpr int kH   = 128;
constexpr int kW   = 128;
constexpr int kHW  = kH * kW;      // 16384
constexpr int kN   = kB * kHW;     // 32768
constexpr float kEPS = 1e-5f;

typedef __attribute__((ext_vector_type(8))) short bf16x8;
typedef __attribute__((ext_vector_type(4))) float f32x4;

__device__ inline unsigned short f2bf(float f) {
    unsigned int u = __builtin_bit_cast(unsigned int, f);
    unsigned int r = (u + 0x7FFFu + ((u >> 16) & 1u)) >> 16;   // RNE
    return (unsigned short)r;
}
__device__ inline float bf2f(unsigned short u) {
    return __builtin_bit_cast(float, (unsigned int)u << 16);
}
// HW packed f32->bf16 (RNE), 1 VALU op for 2 values
__device__ inline unsigned int cvtpk(float lo, float hi) {
    unsigned int r;
    asm("v_cvt_pk_bf16_f32 %0, %1, %2" : "=v"(r) : "v"(lo), "v"(hi));
    return r;
}
__device__ inline unsigned long long pk4(float a, float b, float c, float d) {
    return (unsigned long long)cvtpk(a, b) | ((unsigned long long)cvtpk(c, d) << 32);
}

// ---------------------------------------------------------------------------
// Prep: zero istats accumulators + convert all 6 weight matrices to bf16.
// ---------------------------------------------------------------------------
__global__ void prep_kernel(float* __restrict__ acc,
                            const float* wq, const float* wk, const float* wo,
                            const float* wm, const float* c1, const float* c2,
                            unsigned short* wqb, unsigned short* wkb, unsigned short* wob,
                            unsigned short* wmb, unsigned short* c1b, unsigned short* c2b)
{
    int i = blockIdx.x * 256 + threadIdx.x;
    if (i < 2304) { acc[i] = 0.f; return; }
    i -= 2304;
    if (i < 98304) { wqb[i] = f2bf(wq[i]); return; }
    i -= 98304;
    if (i < 98304) { wkb[i] = f2bf(wk[i]); return; }
    i -= 98304;
    if (i < 98304) { wob[i] = f2bf(wo[i]); return; }
    i -= 98304;
    if (i < 73728) { wmb[i] = f2bf(wm[i]); return; }
    i -= 73728;
    if (i < 36864) { c1b[i] = f2bf(c1[i]); return; }
    i -= 36864;
    if (i < 36864) { c2b[i] = f2bf(c2[i]); return; }
}

// ---------------------------------------------------------------------------
// Transpose x NCHW fp32 -> XP pixel-major fp32 [n][192]
// ---------------------------------------------------------------------------
__global__ __launch_bounds__(256) void transpose_x_kernel(const float* __restrict__ x,
                                                          float* __restrict__ xp)
{
    __shared__ float tile[64][65];
    int hw0 = blockIdx.x * 64;
    int c0  = blockIdx.y * 64;
    int b   = blockIdx.z;
    int tid = threadIdx.x;
    for (int i = tid; i < 64 * 64; i += 256) {
        int row = i >> 6, p = i & 63;
        tile[row][p] = x[((size_t)(b * kC + c0 + row)) * kHW + hw0 + p];
    }
    __syncthreads();
    for (int i = tid; i < 64 * 64; i += 256) {
        int pp = i >> 6, cc = i & 63;
        xp[((size_t)(b * kHW + hw0 + pp)) * kC + c0 + cc] = tile[cc][pp];
    }
}

// ---------------------------------------------------------------------------
// LayerNorm over channels, pixel-major fp32 in -> bf16 out.
// ---------------------------------------------------------------------------
__global__ void ln_pm_kernel(const float* __restrict__ in, unsigned short* __restrict__ out,
                             const float* __restrict__ g, const float* __restrict__ bb)
{
    int n = blockIdx.x * 256 + threadIdx.x;
    if (n >= kN) return;
    const f32x4* ip = (const f32x4*)(in + (size_t)n * kC);
    float s = 0.f, ss = 0.f;
#pragma unroll
    for (int r = 0; r < 48; ++r) {
        f32x4 v = ip[r];
        s  += (v[0] + v[1]) + (v[2] + v[3]);
        ss += (v[0]*v[0] + v[1]*v[1]) + (v[2]*v[2] + v[3]*v[3]);
    }
    float m  = s * (1.0f / kC);
    float var = ss * (1.0f / kC) - m * m;
    float rs = rsqrtf(var + kEPS);
    unsigned short* op = out + (size_t)n * kC;
#pragma unroll
    for (int r = 0; r < 48; ++r) {
        f32x4 v = ip[r];
        f32x4 gg = *(const f32x4*)(g + r * 4);
        f32x4 bv = *(const f32x4*)(bb + r * 4);
        *(unsigned long long*)(op + r * 4) =
            pk4((v[0]-m)*rs*gg[0] + bv[0], (v[1]-m)*rs*gg[1] + bv[1],
                (v[2]-m)*rs*gg[2] + bv[2], (v[3]-m)*rs*gg[3] + bv[3]);
    }
}

// ---------------------------------------------------------------------------
// MFMA GEMM, LDS-free. A [O][K] bf16 (weights), B [n][K] bf16 pixel-major.
// MODE: 1 = f32+bias; 2 = f32+bias+res(fp32 [n][192]); 3 = bf16+bias.
// ---------------------------------------------------------------------------
template<int MODE>
__global__ __launch_bounds__(256) void mgemm_kernel(
    const unsigned short* __restrict__ A, const unsigned short* __restrict__ B,
    const int K, void* __restrict__ out, const int ldOut, const int colOff,
    const float* __restrict__ bias, const float* __restrict__ res)
{
    int nB = blockIdx.x * 128, oB = blockIdx.y * 64;
    int w = threadIdx.x >> 6, lane = threadIdx.x & 63;
    int l15 = lane & 15, g = lane >> 4;
    int wm = w & 1, wn = w >> 1;
    const unsigned short* Ap = A + (size_t)(oB + wm * 32 + l15) * K + 8 * g;
    const unsigned short* Bp = B + (size_t)(nB + wn * 64 + l15) * K + 8 * g;

    f32x4 acc[2][4];
#pragma unroll
    for (int mt = 0; mt < 2; ++mt)
#pragma unroll
        for (int nt = 0; nt < 4; ++nt) acc[mt][nt] = (f32x4){0.f,0.f,0.f,0.f};

#pragma unroll 2
    for (int k = 0; k < K; k += 32) {
        bf16x8 a0 = *(const bf16x8*)(Ap + k);
        bf16x8 a1 = *(const bf16x8*)(Ap + (size_t)16 * K + k);
        bf16x8 b0 = *(const bf16x8*)(Bp + k);
        bf16x8 b1 = *(const bf16x8*)(Bp + (size_t)16 * K + k);
        bf16x8 b2 = *(const bf16x8*)(Bp + (size_t)32 * K + k);
        bf16x8 b3 = *(const bf16x8*)(Bp + (size_t)48 * K + k);
        acc[0][0] = __builtin_amdgcn_mfma_f32_16x16x32_bf16(a0, b0, acc[0][0], 0, 0, 0);
        acc[0][1] = __builtin_amdgcn_mfma_f32_16x16x32_bf16(a0, b1, acc[0][1], 0, 0, 0);
        acc[0][2] = __builtin_amdgcn_mfma_f32_16x16x32_bf16(a0, b2, acc[0][2], 0, 0, 0);
        acc[0][3] = __builtin_amdgcn_mfma_f32_16x16x32_bf16(a0, b3, acc[0][3], 0, 0, 0);
        acc[1][0] = __builtin_amdgcn_mfma_f32_16x16x32_bf16(a1, b0, acc[1][0], 0, 0, 0);
        acc[1][1] = __builtin_amdgcn_mfma_f32_16x16x32_bf16(a1, b1, acc[1][1], 0, 0, 0);
        acc[1][2] = __builtin_amdgcn_mfma_f32_16x16x32_bf16(a1, b2, acc[1][2], 0, 0, 0);
        acc[1][3] = __builtin_amdgcn_mfma_f32_16x16x32_bf16(a1, b3, acc[1][3], 0, 0, 0);
    }

#pragma unroll
    for (int mt = 0; mt < 2; ++mt)
#pragma unroll
        for (int nt = 0; nt < 4; ++nt) {
            int o = oB + wm * 32 + mt * 16 + 4 * g;
            int n = nB + wn * 64 + nt * 16 + l15;
            f32x4 v = acc[mt][nt];
            v += *(const f32x4*)(bias + o);
            if (MODE == 2) v += *(const f32x4*)(res + (size_t)n * 192 + o);
            if (MODE == 3) {
                unsigned short* op = (unsigned short*)out + (size_t)n * ldOut + colOff + o;
                *(unsigned long long*)op = pk4(v[0], v[1], v[2], v[3]);
            } else {
                float* op = (float*)out + (size_t)n * ldOut + colOff + o;
                *(f32x4*)op = v;
            }
        }
}

// ---------------------------------------------------------------------------
// q/k projection GEMM with fused per-head L2 norm + fused row-sum reduction.
// BM=64 == one head, BN=128 == one (b,h) image row, so:
//   red_out[(bh*128 + row)*64 + hc] = sum over the row's 128 pixels of the
//   normalized values. For K this IS ksum_h; for Q these are qs partials.
// Output bf16 [n][512].
// ---------------------------------------------------------------------------
__global__ __launch_bounds__(256) void mgemm_l2_kernel(
    const unsigned short* __restrict__ A, const unsigned short* __restrict__ B,
    const int K, unsigned short* __restrict__ out, float* __restrict__ red_out)
{
    __shared__ float ssq[2][2][4][16];       // [wm][wn][nt][l15]
    __shared__ float rbuf[2][2][4][2][4];    // [wm][wn][g][mt][r]
    int nB = blockIdx.x * 128, oB = blockIdx.y * 64;
    int w = threadIdx.x >> 6, lane = threadIdx.x & 63;
    int l15 = lane & 15, g = lane >> 4;
    int wm = w & 1, wn = w >> 1;
    const unsigned short* Ap = A + (size_t)(oB + wm * 32 + l15) * K + 8 * g;
    const unsigned short* Bp = B + (size_t)(nB + wn * 64 + l15) * K + 8 * g;

    f32x4 acc[2][4];
#pragma unroll
    for (int mt = 0; mt < 2; ++mt)
#pragma unroll
        for (int nt = 0; nt < 4; ++nt) acc[mt][nt] = (f32x4){0.f,0.f,0.f,0.f};

#pragma unroll 2
    for (int k = 0; k < K; k += 32) {
        bf16x8 a0 = *(const bf16x8*)(Ap + k);
        bf16x8 a1 = *(const bf16x8*)(Ap + (size_t)16 * K + k);
        bf16x8 b0 = *(const bf16x8*)(Bp + k);
        bf16x8 b1 = *(const bf16x8*)(Bp + (size_t)16 * K + k);
        bf16x8 b2 = *(const bf16x8*)(Bp + (size_t)32 * K + k);
        bf16x8 b3 = *(const bf16x8*)(Bp + (size_t)48 * K + k);
        acc[0][0] = __builtin_amdgcn_mfma_f32_16x16x32_bf16(a0, b0, acc[0][0], 0, 0, 0);
        acc[0][1] = __builtin_amdgcn_mfma_f32_16x16x32_bf16(a0, b1, acc[0][1], 0, 0, 0);
        acc[0][2] = __builtin_amdgcn_mfma_f32_16x16x32_bf16(a0, b2, acc[0][2], 0, 0, 0);
        acc[0][3] = __builtin_amdgcn_mfma_f32_16x16x32_bf16(a0, b3, acc[0][3], 0, 0, 0);
        acc[1][0] = __builtin_amdgcn_mfma_f32_16x16x32_bf16(a1, b0, acc[1][0], 0, 0, 0);
        acc[1][1] = __builtin_amdgcn_mfma_f32_16x16x32_bf16(a1, b1, acc[1][1], 0, 0, 0);
        acc[1][2] = __builtin_amdgcn_mfma_f32_16x16x32_bf16(a1, b2, acc[1][2], 0, 0, 0);
        acc[1][3] = __builtin_amdgcn_mfma_f32_16x16x32_bf16(a1, b3, acc[1][3], 0, 0, 0);
    }

    // per-pixel sum of squares over this wave's 32 o-channels
#pragma unroll
    for (int nt = 0; nt < 4; ++nt) {
        float s = 0.f;
#pragma unroll
        for (int mt = 0; mt < 2; ++mt) {
            f32x4 a = acc[mt][nt];
            s += (a[0]*a[0] + a[1]*a[1]) + (a[2]*a[2] + a[3]*a[3]);
        }
        s += __shfl_xor(s, 16);
        s += __shfl_xor(s, 32);
        if (g == 0) ssq[wm][wn][nt][l15] = s;
    }
    __syncthreads();

    float sc[4];
#pragma unroll
    for (int nt = 0; nt < 4; ++nt) {
        float ss2 = ssq[0][wn][nt][l15] + ssq[1][wn][nt][l15];
        sc[nt] = 1.0f / fmaxf(sqrtf(ss2), 1e-12f);
    }

    // normalized bf16 output
#pragma unroll
    for (int nt = 0; nt < 4; ++nt) {
        int n = nB + wn * 64 + nt * 16 + l15;
#pragma unroll
        for (int mt = 0; mt < 2; ++mt) {
            int o = oB + wm * 32 + mt * 16 + 4 * g;
            f32x4 v = acc[mt][nt];
            *(unsigned long long*)(out + (size_t)n * kHID + o) =
                pk4(v[0]*sc[nt], v[1]*sc[nt], v[2]*sc[nt], v[3]*sc[nt]);
        }
    }

    // fused row-sum of normalized values
    float sred[2][4] = {};
#pragma unroll
    for (int nt = 0; nt < 4; ++nt)
#pragma unroll
        for (int mt = 0; mt < 2; ++mt) {
            f32x4 a = acc[mt][nt];
            sred[mt][0] += a[0] * sc[nt];
            sred[mt][1] += a[1] * sc[nt];
            sred[mt][2] += a[2] * sc[nt];
            sred[mt][3] += a[3] * sc[nt];
        }
#pragma unroll
    for (int off = 1; off < 16; off <<= 1)
#pragma unroll
        for (int mt = 0; mt < 2; ++mt)
#pragma unroll
            for (int r = 0; r < 4; ++r)
                sred[mt][r] += __shfl_xor(sred[mt][r], off);
    if (l15 == 0)
#pragma unroll
        for (int mt = 0; mt < 2; ++mt)
#pragma unroll
            for (int r = 0; r < 4; ++r)
                rbuf[wm][wn][g][mt][r] = sred[mt][r];
    __syncthreads();
    if (threadIdx.x < 64) {
        int o = threadIdx.x;
        int wm2 = o >> 5, mt2 = (o >> 4) & 1, g2 = (o >> 2) & 3, r2 = o & 3;
        float v = rbuf[wm2][0][g2][mt2][r2] + rbuf[wm2][1][g2][mt2][r2];
        int row = (nB & (kHW - 1)) >> 7;
        int b = nB >> 14;
        int bh = b * 8 + blockIdx.y;
        red_out[((size_t)(bh * 128 + row)) * 64 + o] = v;
    }
}

// ksum_w[bh][w][hc] = sum_h k  (reads bf16 K [n][512])
__global__ void sum_h_kernel(const unsigned short* __restrict__ buf, float* __restrict__ out)
{
    int w = blockIdx.x, bh = blockIdx.y, hc = threadIdx.x;
    int b = bh >> 3, nh = bh & 7;
    const unsigned short* p = buf + (size_t)(b * kHW + w) * kHID + nh * kHC + hc;
    float s = 0.f;
    for (int h = 0; h < kH; ++h) s += bf2f(p[(size_t)h * kW * kHID]);
    out[((size_t)bh * kW + w) * kHC + hc] = s;
}

// ---------------------------------------------------------------------------
// Fused qs-reduce + h/w scores + top-16 (tie -> lower index). Block per bh.
// ---------------------------------------------------------------------------
__global__ void score_topk_kernel(const float* __restrict__ qpart,
                                  const float* __restrict__ ksum_h,
                                  const float* __restrict__ ksum_w,
                                  int* __restrict__ hidx, int* __restrict__ widx)
{
    __shared__ float qsl[2][64];
    __shared__ float hs[128], ws[128];
    int bh = blockIdx.x;
    int tid = threadIdx.x;               // 128
    int hc = tid & 63, grp = tid >> 6;
    {
        const float* qp = qpart + ((size_t)bh * 128 + grp * 64) * 64 + hc;
        float s = 0.f;
        for (int i = 0; i < 64; ++i) s += qp[(size_t)i * 64];
        qsl[grp][hc] = s;
    }
    __syncthreads();
    if (tid < 64) qsl[0][tid] += qsl[1][tid];
    __syncthreads();
    {
        const float* kh = ksum_h + ((size_t)bh * 128 + tid) * 64;
        const float* kw = ksum_w + ((size_t)bh * 128 + tid) * 64;
        float sh = 0.f, sw = 0.f;
        for (int c = 0; c < 64; ++c) {
            float q = qsl[0][c];
            sh += q * kh[c];
            sw += q * kw[c];
        }
        hs[tid] = sh; ws[tid] = sw;
    }
    __syncthreads();
    int sel = tid >> 6;                  // wave 0 -> h, wave 1 -> w
    const float* sc = sel ? ws : hs;
    int* out = (sel ? widx : hidx) + bh * kP;
    int lane = tid & 63;
    float v0 = sc[lane], v1 = sc[lane + 64];
    int i0 = lane, i1 = lane + 64;
    for (int p = 0; p < kP; ++p) {
        float bv; int bi;
        if (v1 > v0) { bv = v1; bi = i1; } else { bv = v0; bi = i0; }
#pragma unroll
        for (int off = 1; off < 64; off <<= 1) {
            float ov = __shfl_xor(bv, off);
            int   oi = __shfl_xor(bi, off);
            if (ov > bv || (ov == bv && oi < bi)) { bv = ov; bi = oi; }
        }
        if (lane == 0) out[p] = bi;
        if (i0 == bi) v0 = -INFINITY;
        if (i1 == bi) v1 = -INFINITY;
    }
}

// ---------------------------------------------------------------------------
// Gather kf bf16 [bh][256][64]; lazy-project vfT bf16 [bh][64][256].
// ---------------------------------------------------------------------------
__global__ void gather_kv_kernel(const unsigned short* __restrict__ kpb,
                                 const unsigned short* __restrict__ xnb,
                                 const float* __restrict__ wv,
                                 const int* __restrict__ hidx, const int* __restrict__ widx,
                                 unsigned short* __restrict__ kf, unsigned short* __restrict__ vfT)
{
    int bh = blockIdx.y, p1 = blockIdx.x;
    int b = bh >> 3, nh = bh & 7;
    int hc = threadIdx.x & 63, pg = threadIdx.x >> 6;
    int hrow = hidx[bh * kP + p1];
    int o = nh * kHC + hc;
    const float* wvp = wv + (size_t)o * kC;
    for (int p2 = pg; p2 < kP; p2 += 4) {
        int wcol = widx[bh * kP + p2];
        int n = b * kHW + hrow * kW + wcol;
        int kidx = p1 * kP + p2;
        kf[((size_t)bh * 256 + kidx) * 64 + hc] = kpb[(size_t)n * kHID + nh * kHC + hc];
        const unsigned int* xr = (const unsigned int*)(xnb + (size_t)n * kC);
        float s = 0.f;
        for (int c2 = 0; c2 < kC / 2; ++c2) {
            unsigned int u = xr[c2];
            s += wvp[c2 * 2]     * bf2f((unsigned short)(u & 0xffff));
            s += wvp[c2 * 2 + 1] * bf2f((unsigned short)(u >> 16));
        }
        vfT[((size_t)bh * 64 + hc) * 256 + kidx] = f2bf(s);
    }
}

// ---------------------------------------------------------------------------
// MFMA attention. Block = 64 queries x 1 head, 4 waves.
// P staged in LDS, row stride 272 shorts (bank-balanced writes & reads).
// ---------------------------------------------------------------------------
__global__ __launch_bounds__(256) void attn_kernel(
    const unsigned short* __restrict__ qpb, unsigned short* __restrict__ ob,
    const unsigned short* __restrict__ kf, const unsigned short* __restrict__ vfT)
{
    __shared__ unsigned short pls[64 * 272];
    __shared__ float lred[4][4][16];

    int bh = blockIdx.y; int b = bh >> 3, nh = bh & 7;
    int n0 = b * kHW + blockIdx.x * 64;
    int tid = threadIdx.x;
    int w = tid >> 6, lane = tid & 63, l15 = lane & 15, g = lane >> 4;

    bf16x8 bq[4][2];
#pragma unroll
    for (int nt = 0; nt < 4; ++nt)
#pragma unroll
        for (int kt = 0; kt < 2; ++kt)
            bq[nt][kt] = *(const bf16x8*)(qpb + (size_t)(n0 + nt * 16 + l15) * kHID
                                          + nh * kHC + kt * 32 + 8 * g);

    const unsigned short* kfb = kf + (size_t)bh * 256 * 64;
    bf16x8 ak[4][2];
#pragma unroll
    for (int mt = 0; mt < 4; ++mt)
#pragma unroll
        for (int kt = 0; kt < 2; ++kt)
            ak[mt][kt] = *(const bf16x8*)&kfb[(size_t)(w * 64 + mt * 16 + l15) * 64 + kt * 32 + 8 * g];

    f32x4 acc[4][4];
#pragma unroll
    for (int mt = 0; mt < 4; ++mt)
#pragma unroll
        for (int nt = 0; nt < 4; ++nt) acc[mt][nt] = (f32x4){0.f,0.f,0.f,0.f};

#pragma unroll
    for (int kt = 0; kt < 2; ++kt)
#pragma unroll
        for (int mt = 0; mt < 4; ++mt)
#pragma unroll
            for (int nt = 0; nt < 4; ++nt)
                acc[mt][nt] = __builtin_amdgcn_mfma_f32_16x16x32_bf16(
                    ak[mt][kt], bq[nt][kt], acc[mt][nt], 0, 0, 0);

    float lpart[4] = {0.f, 0.f, 0.f, 0.f};
#pragma unroll
    for (int mt = 0; mt < 4; ++mt)
#pragma unroll
        for (int nt = 0; nt < 4; ++nt) {
            float e0 = __expf(acc[mt][nt][0]);
            float e1 = __expf(acc[mt][nt][1]);
            float e2 = __expf(acc[mt][nt][2]);
            float e3 = __expf(acc[mt][nt][3]);
            lpart[nt] += (e0 + e1) + (e2 + e3);
            int qq = nt * 16 + l15;
            int k0 = w * 64 + mt * 16 + 4 * g;
            *(unsigned long long*)&pls[qq * 272 + k0] = pk4(e0, e1, e2, e3);
        }
#pragma unroll
    for (int nt = 0; nt < 4; ++nt) {
        lpart[nt] += __shfl_xor(lpart[nt], 16);
        lpart[nt] += __shfl_xor(lpart[nt], 32);
    }
    if (g == 0)
#pragma unroll
        for (int nt = 0; nt < 4; ++nt) lred[w][nt][l15] = lpart[nt];
    __syncthreads();

    const unsigned short* vfb = vfT + (size_t)bh * 64 * 256;
    f32x4 oacc[4];
#pragma unroll
    for (int nt = 0; nt < 4; ++nt) oacc[nt] = (f32x4){0.f,0.f,0.f,0.f};

#pragma unroll
    for (int ks = 0; ks < 8; ++ks) {
        bf16x8 av = *(const bf16x8*)&vfb[(size_t)(w * 16 + l15) * 256 + ks * 32 + 8 * g];
#pragma unroll
        for (int nt = 0; nt < 4; ++nt) {
            bf16x8 bp = *(const bf16x8*)&pls[(nt * 16 + l15) * 272 + ks * 32 + 8 * g];
            oacc[nt] = __builtin_amdgcn_mfma_f32_16x16x32_bf16(av, bp, oacc[nt], 0, 0, 0);
        }
    }

#pragma unroll
    for (int nt = 0; nt < 4; ++nt) {
        float l = lred[0][nt][l15] + lred[1][nt][l15] + lred[2][nt][l15] + lred[3][nt][l15];
        float inv = 1.0f / l;
        int qq = nt * 16 + l15;
        int hc0 = w * 16 + 4 * g;
        *(unsigned long long*)(ob + (size_t)(n0 + qq) * kHID + nh * kHC + hc0) =
            pk4(oacc[nt][0] * inv, oacc[nt][1] * inv, oacc[nt][2] * inv, oacc[nt][3] * inv);
    }
}

// ---------------------------------------------------------------------------
// Depthwise 3x3 SAME conv, pixel-major fp32 in.
// ---------------------------------------------------------------------------
template<int OUTBF16>
__global__ void dwconv_pm_kernel(const float* __restrict__ in, void* __restrict__ out,
                                 const int ldOut, const int colOff,
                                 const float* __restrict__ wt, const float* __restrict__ bias)
{
    int idx = blockIdx.x * 256 + threadIdx.x;      // kN*48
    int n = idx / 48;
    int c0 = (idx - n * 48) * 4;
    int hw = n & (kHW - 1);
    int h = hw >> 7, ww = hw & 127;
    f32x4 s = *(const f32x4*)(bias + c0);
#pragma unroll
    for (int dy = -1; dy <= 1; ++dy) {
        int hh = h + dy;
        if (hh < 0 || hh >= kH) continue;
#pragma unroll
        for (int dx = -1; dx <= 1; ++dx) {
            int wx = ww + dx;
            if (wx < 0 || wx >= kW) continue;
            f32x4 v = *(const f32x4*)(in + (size_t)(n + dy * kW + dx) * kC + c0);
            int t = (dy + 1) * 3 + (dx + 1);
            s[0] += v[0] * wt[(c0 + 0) * 9 + t];
            s[1] += v[1] * wt[(c0 + 1) * 9 + t];
            s[2] += v[2] * wt[(c0 + 2) * 9 + t];
            s[3] += v[3] * wt[(c0 + 3) * 9 + t];
        }
    }
    if (OUTBF16) {
        unsigned short* op = (unsigned short*)out + (size_t)n * ldOut + colOff + c0;
        *(unsigned long long*)op = pk4(s[0], s[1], s[2], s[3]);
    } else {
        *(f32x4*)((float*)out + (size_t)n * ldOut + colOff + c0) = s;
    }
}

// ---------------------------------------------------------------------------
// Instance-norm stats via per-chunk atomics into acc[(b*kC+c)*2 + {0,1}].
// ---------------------------------------------------------------------------
__global__ void istats_pm_kernel(const float* __restrict__ in, float* __restrict__ acc)
{
    int n0 = blockIdx.x * 64;
    int b = n0 >> 14;
    int c = threadIdx.x;
    float s = 0.f, ss = 0.f;
    for (int p = 0; p < 64; ++p) {
        float v = in[(size_t)(n0 + p) * kC + c];
        s += v; ss += v * v;
    }
    atomicAdd(&acc[(size_t)(b * kC + c) * 2],     s);
    atomicAdd(&acc[(size_t)(b * kC + c) * 2 + 1], ss);
}

__device__ inline void inorm_ms(const float* acc, int b, int c, float& m, float& rs)
{
    float s  = acc[(size_t)(b * kC + c) * 2];
    float ss = acc[(size_t)(b * kC + c) * 2 + 1];
    m = s * (1.0f / kHW);
    float var = ss * (1.0f / kHW) - m * m;
    rs = rsqrtf(var + kEPS);
}

// MODE 0: gelu(inorm(in)) -> fp32.  MODE 1: gelu(inorm(in)) + add -> bf16.
template<int MODE>
__global__ void apply_pm_kernel(const float* __restrict__ in, const float* __restrict__ acc,
                                void* __restrict__ out, const float* __restrict__ addsrc)
{
    int idx = blockIdx.x * 256 + threadIdx.x;      // kN*48
    int n = idx / 48;
    int c0 = (idx - n * 48) * 4;
    int b = n >> 14;
    f32x4 v = *(const f32x4*)(in + (size_t)n * kC + c0);
    f32x4 r;
#pragma unroll
    for (int j = 0; j < 4; ++j) {
        float m, rs;
        inorm_ms(acc, b, c0 + j, m, rs);
        float x = (v[j] - m) * rs;
        r[j] = 0.5f * x * (1.0f + erff(x * 0.70710678118654752f));
    }
    if (MODE == 1) {
        r += *(const f32x4*)(addsrc + (size_t)n * kC + c0);
        unsigned short* op = (unsigned short*)out + (size_t)n * kC + c0;
        *(unsigned long long*)op = pk4(r[0], r[1], r[2], r[3]);
    } else {
        *(f32x4*)((float*)out + (size_t)n * kC + c0) = r;
    }
}

// Final inorm, pixel-major fp32 in -> NCHW fp32 d_out.
__global__ void final_kernel(const float* __restrict__ in, const float* __restrict__ acc,
                             float* __restrict__ out)
{
    int id = blockIdx.x * 256 + threadIdx.x;       // kC*kN/4
    int oid = id * 4;
    int q = oid >> 14;
    int hw = oid & (kHW - 1);
    int b = (q >= kC) ? 1 : 0;
    int c = q - b * kC;
    float m, rs;
    inorm_ms(acc, b, c, m, rs);
    int n = b * kHW + hw;
    f32x4 o;
#pragma unroll
    for (int j = 0; j < 4; ++j)
        o[j] = (in[(size_t)(n + j) * kC + c] - m) * rs;
    *(f32x4*)(out + (size_t)oid) = o;
}

// ---------------------------------------------------------------------------
extern "C" void kernel_launch(void* const* d_in, const int* in_sizes, int n_in,
                              void* d_out, int out_size, void* d_ws, size_t ws_size,
                              hipStream_t stream)
{
    const float* x     = (const float*)d_in[0];
    const float* ln1_g = (const float*)d_in[1];
    const float* ln1_b = (const float*)d_in[2];
    const float* wq    = (const float*)d_in[3];
    const float* wk    = (const float*)d_in[4];
    const float* wv    = (const float*)d_in[5];
    const float* wo    = (const float*)d_in[6];
    const float* bo    = (const float*)d_in[7];
    const float* dw_w  = (const float*)d_in[8];
    const float* dw_b  = (const float*)d_in[9];
    const float* mlp_w = (const float*)d_in[10];
    const float* mlp_b = (const float*)d_in[11];
    const float* ln2_g = (const float*)d_in[12];
    const float* ln2_b = (const float*)d_in[13];
    const float* c1_w  = (const float*)d_in[14];
    const float* c1_b  = (const float*)d_in[15];
    const float* res_w = (const float*)d_in[16];
    const float* res_b = (const float*)d_in[17];
    const float* c2_w  = (const float*)d_in[18];
    const float* c2_b  = (const float*)d_in[19];

    char* base = (char*)d_ws;
    float* XP  = (float*)(base);                         // fp32 [n][192]; later T1/R
    float* T1  = XP;
    unsigned short* XNb = (unsigned short*)(base + 25165824);   // bf16 [n][192]
    unsigned short* QPb = (unsigned short*)(base + 37748736);   // bf16 [n][512]; later F/T2 fp32
    float* F  = (float*)QPb;
    float* T2 = (float*)QPb;
    unsigned short* KPb = (unsigned short*)(base + 71303168);   // bf16 [n][512]; OB alias; later Y2 fp32
    unsigned short* OB  = KPb;
    float* Y2 = (float*)KPb;
    unsigned short* CATb = (unsigned short*)(base + 104857600); // bf16 [n][384]; Y3 alias
    unsigned short* Y3   = CATb;
    char* sm = base + 130023424;
    float* qpart  = (float*)(sm);                 sm += 524288;   // [16][128][64]
    float* ksum_h = (float*)(sm);                 sm += 524288;
    float* ksum_w = (float*)(sm);                 sm += 524288;
    float* acc0   = (float*)(sm);                 sm += 3072;     // 768 f32 each
    float* acc1   = (float*)(sm);                 sm += 3072;
    float* acc2   = (float*)(sm);                 sm += 3072;
    unsigned short* kf   = (unsigned short*)(sm); sm += 524288;
    unsigned short* vfT  = (unsigned short*)(sm); sm += 524288;
    unsigned short* wqb  = (unsigned short*)(sm); sm += 196608;
    unsigned short* wkb  = (unsigned short*)(sm); sm += 196608;
    unsigned short* wob  = (unsigned short*)(sm); sm += 196608;
    unsigned short* mlpb = (unsigned short*)(sm); sm += 147456;
    unsigned short* c1b  = (unsigned short*)(sm); sm += 73728;
    unsigned short* c2b  = (unsigned short*)(sm); sm += 73728;
    int* hidx = (int*)(sm);                       sm += 1024;
    int* widx = (int*)(sm);

    // --- prep: zero accs + all weight conversions (1 kernel) ---
    prep_kernel<<<1737, 256, 0, stream>>>(acc0, wq, wk, wo, mlp_w, c1_w, c2_w,
                                          wqb, wkb, wob, mlpb, c1b, c2b);
    transpose_x_kernel<<<dim3(kHW / 64, 3, kB), 256, 0, stream>>>(x, XP);

    // --- attention branch ---
    ln_pm_kernel<<<kN / 256, 256, 0, stream>>>(XP, XNb, ln1_g, ln1_b);
    mgemm_l2_kernel<<<dim3(kN / 128, kNH), 256, 0, stream>>>(wqb, XNb, kC, QPb, qpart);
    mgemm_l2_kernel<<<dim3(kN / 128, kNH), 256, 0, stream>>>(wkb, XNb, kC, KPb, ksum_h);
    sum_h_kernel<<<dim3(kW, 16), 64, 0, stream>>>(KPb, ksum_w);
    score_topk_kernel<<<16, 128, 0, stream>>>(qpart, ksum_h, ksum_w, hidx, widx);
    gather_kv_kernel<<<dim3(kP, 16), 256, 0, stream>>>(KPb, XNb, wv, hidx, widx, kf, vfT);
    attn_kernel<<<dim3(kHW / 64, 16), 256, 0, stream>>>(QPb, OB, kf, vfT);
    mgemm_kernel<3><<<dim3(kN / 128, kC / 64), 256, 0, stream>>>(wob, OB, kHID, CATb, 2 * kC, kC, bo, nullptr);

    // --- local branch + mlp ---
    dwconv_pm_kernel<1><<<(kN * 48) / 256, 256, 0, stream>>>(XP, CATb, 2 * kC, 0, dw_w, dw_b);
    mgemm_kernel<2><<<dim3(kN / 128, kC / 64), 256, 0, stream>>>(mlpb, CATb, 2 * kC, F, kC, 0, mlp_b, XP);

    // --- tail ---
    ln_pm_kernel<<<kN / 256, 256, 0, stream>>>(F, XNb, ln2_g, ln2_b);          // Y1 = XNb
    mgemm_kernel<1><<<dim3(kN / 128, kC / 64), 256, 0, stream>>>(c1b, XNb, kC, T1, kC, 0, c1_b, nullptr);
    istats_pm_kernel<<<kN / 64, 192, 0, stream>>>(T1, acc0);
    apply_pm_kernel<0><<<(kN * 48) / 256, 256, 0, stream>>>(T1, acc0, Y2, nullptr);
    dwconv_pm_kernel<0><<<(kN * 48) / 256, 256, 0, stream>>>(Y2, T1, kC, 0, res_w, res_b);  // R = T1
    istats_pm_kernel<<<kN / 64, 192, 0, stream>>>(T1, acc1);
    apply_pm_kernel<1><<<(kN * 48) / 256, 256, 0, stream>>>(T1, acc1, Y3, Y2);
    mgemm_kernel<1><<<dim3(kN / 128, kC / 64), 256, 0, stream>>>(c2b, Y3, kC, T2, kC, 0, c2_b, nullptr);
    istats_pm_kernel<<<kN / 64, 192, 0, stream>>>(T2, acc2);
    final_kernel<<<(kC * kN / 4) / 256, 256, 0, stream>>>(T2, acc2, (float*)d_out);
}

// Round 6
// 545.990 us; speedup vs baseline: 3.7132x; 1.0630x over previous
//
#include <hip/hip_runtime.h>
#include <math.h>

constexpr int kC   = 192;
constexpr int kNH  = 8;
constexpr int kHC  = 64;
constexpr int kHID = 512;
constexpr int kP   = 16;
constexpr int kB   = 2;
constexpr int kH   = 128;
constexpr int kW   = 128;
constexpr int kHW  = kH * kW;      // 16384
constexpr int kN   = kB * kHW;     // 32768
constexpr float kEPS = 1e-5f;

typedef __attribute__((ext_vector_type(8))) short bf16x8;
typedef __attribute__((ext_vector_type(4))) float f32x4;

__device__ inline unsigned short f2bf(float f) {
    unsigned int u = __builtin_bit_cast(unsigned int, f);
    unsigned int r = (u + 0x7FFFu + ((u >> 16) & 1u)) >> 16;   // RNE
    return (unsigned short)r;
}
__device__ inline float bf2f(unsigned short u) {
    return __builtin_bit_cast(float, (unsigned int)u << 16);
}
__device__ inline unsigned int cvtpk(float lo, float hi) {
    unsigned int r;
    asm("v_cvt_pk_bf16_f32 %0, %1, %2" : "=v"(r) : "v"(lo), "v"(hi));
    return r;
}
__device__ inline unsigned long long pk4(float a, float b, float c, float d) {
    return (unsigned long long)cvtpk(a, b) | ((unsigned long long)cvtpk(c, d) << 32);
}
__device__ inline f32x4 ubf4(unsigned long long u) {
    f32x4 r;
    r[0] = bf2f((unsigned short)u);
    r[1] = bf2f((unsigned short)(u >> 16));
    r[2] = bf2f((unsigned short)(u >> 32));
    r[3] = bf2f((unsigned short)(u >> 48));
    return r;
}

// ---------------------------------------------------------------------------
// Prep: zero istats accumulators + bf16 weight conversions.
// ---------------------------------------------------------------------------
__global__ void prep_kernel(float* __restrict__ acc,
                            const float* wq, const float* wk, const float* wm,
                            const float* c1, const float* c2,
                            unsigned short* wqb, unsigned short* wkb,
                            unsigned short* mlpb1, unsigned short* c1b, unsigned short* c2b)
{
    int i = blockIdx.x * 256 + threadIdx.x;
    if (i < 2304) { acc[i] = 0.f; return; }
    i -= 2304;
    if (i < 98304) { wqb[i] = f2bf(wq[i]); return; }
    i -= 98304;
    if (i < 98304) { wkb[i] = f2bf(wk[i]); return; }
    i -= 98304;
    if (i < 36864) { int o = i / 192, k = i - o * 192; mlpb1[i] = f2bf(wm[o * 384 + k]); return; }
    i -= 36864;
    if (i < 36864) { c1b[i] = f2bf(c1[i]); return; }
    i -= 36864;
    if (i < 36864) { c2b[i] = f2bf(c2[i]); return; }
}

// ---------------------------------------------------------------------------
// Fused weight: W2'[o][j] = sum_c mlp_w[o][192+c]*wo[c][j]  (bf16 out)
//               bp2[o]    = mlp_b[o] + sum_c mlp_w[o][192+c]*bo[c]
// ---------------------------------------------------------------------------
__global__ void wfuse_kernel(const float* __restrict__ mlp_w, const float* __restrict__ wo,
                             const float* __restrict__ mlp_b, const float* __restrict__ bo,
                             unsigned short* __restrict__ w2pb, float* __restrict__ bp2)
{
    int i = blockIdx.x * 256 + threadIdx.x;   // 98304
    int o = i >> 9, j = i & 511;
    const float* a = mlp_w + o * 384 + 192;
    float s = 0.f;
    for (int c = 0; c < 192; ++c) s += a[c] * wo[c * 512 + j];
    w2pb[o * 512 + j] = f2bf(s);
    if (j == 0) {
        float t = mlp_b[o];
        for (int c = 0; c < 192; ++c) t += a[c] * bo[c];
        bp2[o] = t;
    }
}

// ---------------------------------------------------------------------------
// Fused transpose + ln1: x NCHW fp32 -> XP raw fp32 [n][192] + XNb bf16 [n][192]
// ---------------------------------------------------------------------------
__global__ __launch_bounds__(256) void txln_kernel(const float* __restrict__ x,
                                                   float* __restrict__ xp,
                                                   unsigned short* __restrict__ xnb,
                                                   const float* __restrict__ g,
                                                   const float* __restrict__ bb)
{
    __shared__ float tile[192][65];
    __shared__ float red[2][4][64];
    __shared__ float pms[64], prs[64];
    int hw0 = blockIdx.x * 64;
    int b   = blockIdx.y;
    int tid = threadIdx.x;
    for (int i = tid; i < 192 * 64; i += 256) {
        int c = i >> 6, p = i & 63;
        tile[c][p] = x[(size_t)(b * kC + c) * kHW + hw0 + p];
    }
    __syncthreads();
    {
        int p = tid & 63, qt = tid >> 6;
        float s = 0.f, ss = 0.f;
        for (int c = qt * 48; c < qt * 48 + 48; ++c) {
            float v = tile[c][p]; s += v; ss += v * v;
        }
        red[0][qt][p] = s; red[1][qt][p] = ss;
    }
    __syncthreads();
    if (tid < 64) {
        float s  = red[0][0][tid] + red[0][1][tid] + red[0][2][tid] + red[0][3][tid];
        float ss = red[1][0][tid] + red[1][1][tid] + red[1][2][tid] + red[1][3][tid];
        float m = s * (1.0f / kC);
        float var = ss * (1.0f / kC) - m * m;
        pms[tid] = m;
        prs[tid] = rsqrtf(var + kEPS);
    }
    __syncthreads();
    for (int i = tid; i < 64 * 192; i += 256) {
        int p = i / 192, c = i - p * 192;
        float raw = tile[c][p];
        size_t oi = (size_t)(b * kHW + hw0 + p) * kC + c;
        xp[oi] = raw;
        xnb[oi] = f2bf((raw - pms[p]) * prs[p] * g[c] + bb[c]);
    }
}

// ---------------------------------------------------------------------------
// LayerNorm over channels, bf16 in -> bf16 out (ln2).
// ---------------------------------------------------------------------------
__global__ void ln_pm_bf16_kernel(const unsigned short* __restrict__ in,
                                  unsigned short* __restrict__ out,
                                  const float* __restrict__ g, const float* __restrict__ bb)
{
    int n = blockIdx.x * 256 + threadIdx.x;
    if (n >= kN) return;
    const unsigned long long* ip = (const unsigned long long*)(in + (size_t)n * kC);
    float s = 0.f, ss = 0.f;
    f32x4 vals[48];
#pragma unroll
    for (int r = 0; r < 48; ++r) {
        f32x4 v = ubf4(ip[r]);
        vals[r] = v;
        s  += (v[0] + v[1]) + (v[2] + v[3]);
        ss += (v[0]*v[0] + v[1]*v[1]) + (v[2]*v[2] + v[3]*v[3]);
    }
    float m  = s * (1.0f / kC);
    float var = ss * (1.0f / kC) - m * m;
    float rs = rsqrtf(var + kEPS);
    unsigned long long* op = (unsigned long long*)(out + (size_t)n * kC);
#pragma unroll
    for (int r = 0; r < 48; ++r) {
        f32x4 v = vals[r];
        f32x4 gg = *(const f32x4*)(g + r * 4);
        f32x4 bv = *(const f32x4*)(bb + r * 4);
        op[r] = pk4((v[0]-m)*rs*gg[0] + bv[0], (v[1]-m)*rs*gg[1] + bv[1],
                    (v[2]-m)*rs*gg[2] + bv[2], (v[3]-m)*rs*gg[3] + bv[3]);
    }
}

#define MGEMM_CORE(KVAL, APTR, BPTR)                                              \
    {                                                                             \
        const unsigned short* Ap = APTR;                                          \
        const unsigned short* Bp = BPTR;                                          \
        _Pragma("unroll 2")                                                       \
        for (int k = 0; k < KVAL; k += 32) {                                      \
            bf16x8 a0 = *(const bf16x8*)(Ap + k);                                 \
            bf16x8 a1 = *(const bf16x8*)(Ap + (size_t)16 * KVAL + k);             \
            bf16x8 b0 = *(const bf16x8*)(Bp + k);                                 \
            bf16x8 b1 = *(const bf16x8*)(Bp + (size_t)16 * KVAL + k);             \
            bf16x8 b2 = *(const bf16x8*)(Bp + (size_t)32 * KVAL + k);             \
            bf16x8 b3 = *(const bf16x8*)(Bp + (size_t)48 * KVAL + k);             \
            acc[0][0] = __builtin_amdgcn_mfma_f32_16x16x32_bf16(a0, b0, acc[0][0], 0, 0, 0); \
            acc[0][1] = __builtin_amdgcn_mfma_f32_16x16x32_bf16(a0, b1, acc[0][1], 0, 0, 0); \
            acc[0][2] = __builtin_amdgcn_mfma_f32_16x16x32_bf16(a0, b2, acc[0][2], 0, 0, 0); \
            acc[0][3] = __builtin_amdgcn_mfma_f32_16x16x32_bf16(a0, b3, acc[0][3], 0, 0, 0); \
            acc[1][0] = __builtin_amdgcn_mfma_f32_16x16x32_bf16(a1, b0, acc[1][0], 0, 0, 0); \
            acc[1][1] = __builtin_amdgcn_mfma_f32_16x16x32_bf16(a1, b1, acc[1][1], 0, 0, 0); \
            acc[1][2] = __builtin_amdgcn_mfma_f32_16x16x32_bf16(a1, b2, acc[1][2], 0, 0, 0); \
            acc[1][3] = __builtin_amdgcn_mfma_f32_16x16x32_bf16(a1, b3, acc[1][3], 0, 0, 0); \
        }                                                                         \
    }

// ---------------------------------------------------------------------------
// c1/c2 GEMM: bf16 out [n][192] + bias + fused instance-norm partial stats.
// ---------------------------------------------------------------------------
__global__ __launch_bounds__(256) void mgemm_is_kernel(
    const unsigned short* __restrict__ A, const unsigned short* __restrict__ B,
    unsigned short* __restrict__ out, const float* __restrict__ bias,
    float* __restrict__ accp)
{
    __shared__ float sa[2][64], qa[2][64];
    int nB = blockIdx.x * 128, oB = blockIdx.y * 64;
    int w = threadIdx.x >> 6, lane = threadIdx.x & 63;
    int l15 = lane & 15, g = lane >> 4;
    int wm = w & 1, wn = w >> 1;

    f32x4 acc[2][4];
#pragma unroll
    for (int mt = 0; mt < 2; ++mt)
#pragma unroll
        for (int nt = 0; nt < 4; ++nt) acc[mt][nt] = (f32x4){0.f,0.f,0.f,0.f};

    MGEMM_CORE(192, A + (size_t)(oB + wm * 32 + l15) * 192 + 8 * g,
                    B + (size_t)(nB + wn * 64 + l15) * 192 + 8 * g);

    f32x4 vv[2][4];
#pragma unroll
    for (int mt = 0; mt < 2; ++mt)
#pragma unroll
        for (int nt = 0; nt < 4; ++nt) {
            int o = oB + wm * 32 + mt * 16 + 4 * g;
            int n = nB + wn * 64 + nt * 16 + l15;
            f32x4 v = acc[mt][nt] + *(const f32x4*)(bias + o);
            vv[mt][nt] = v;
            *(unsigned long long*)(out + (size_t)n * kC + o) = pk4(v[0], v[1], v[2], v[3]);
        }
    // per-channel partial sums over this block's 128 pixels
    float s2[2][4] = {}, q2[2][4] = {};
#pragma unroll
    for (int mt = 0; mt < 2; ++mt)
#pragma unroll
        for (int nt = 0; nt < 4; ++nt)
#pragma unroll
            for (int r = 0; r < 4; ++r) {
                float v = vv[mt][nt][r];
                s2[mt][r] += v; q2[mt][r] += v * v;
            }
#pragma unroll
    for (int off = 1; off < 16; off <<= 1)
#pragma unroll
        for (int mt = 0; mt < 2; ++mt)
#pragma unroll
            for (int r = 0; r < 4; ++r) {
                s2[mt][r] += __shfl_xor(s2[mt][r], off);
                q2[mt][r] += __shfl_xor(q2[mt][r], off);
            }
    if (l15 == 0)
#pragma unroll
        for (int mt = 0; mt < 2; ++mt)
#pragma unroll
            for (int r = 0; r < 4; ++r) {
                int ol = wm * 32 + mt * 16 + 4 * g + r;
                sa[wn][ol] = s2[mt][r];
                qa[wn][ol] = q2[mt][r];
            }
    __syncthreads();
    if (threadIdx.x < 128) {
        int ol = threadIdx.x & 63, st = threadIdx.x >> 6;
        float v = st ? (qa[0][ol] + qa[1][ol]) : (sa[0][ol] + sa[1][ol]);
        int b = nB >> 14;
        atomicAdd(&accp[(size_t)(b * kC + oB + ol) * 2 + st], v);
    }
}

// ---------------------------------------------------------------------------
// Fused MLP: F = mlp_w1@LB + W2'@OB + bp2 + x   (bf16 out [n][192])
// ---------------------------------------------------------------------------
__global__ __launch_bounds__(256) void mgemm_mlp_kernel(
    const unsigned short* __restrict__ A1, const unsigned short* __restrict__ B1,
    const unsigned short* __restrict__ A2, const unsigned short* __restrict__ B2,
    unsigned short* __restrict__ out, const float* __restrict__ bp2,
    const float* __restrict__ res)
{
    int nB = blockIdx.x * 128, oB = blockIdx.y * 64;
    int w = threadIdx.x >> 6, lane = threadIdx.x & 63;
    int l15 = lane & 15, g = lane >> 4;
    int wm = w & 1, wn = w >> 1;

    f32x4 acc[2][4];
#pragma unroll
    for (int mt = 0; mt < 2; ++mt)
#pragma unroll
        for (int nt = 0; nt < 4; ++nt) acc[mt][nt] = (f32x4){0.f,0.f,0.f,0.f};

    MGEMM_CORE(192, A1 + (size_t)(oB + wm * 32 + l15) * 192 + 8 * g,
                    B1 + (size_t)(nB + wn * 64 + l15) * 192 + 8 * g);
    MGEMM_CORE(512, A2 + (size_t)(oB + wm * 32 + l15) * 512 + 8 * g,
                    B2 + (size_t)(nB + wn * 64 + l15) * 512 + 8 * g);

#pragma unroll
    for (int mt = 0; mt < 2; ++mt)
#pragma unroll
        for (int nt = 0; nt < 4; ++nt) {
            int o = oB + wm * 32 + mt * 16 + 4 * g;
            int n = nB + wn * 64 + nt * 16 + l15;
            f32x4 v = acc[mt][nt];
            v[0] += bp2[o]; v[1] += bp2[o+1]; v[2] += bp2[o+2]; v[3] += bp2[o+3];
            v += *(const f32x4*)(res + (size_t)n * kC + o);
            *(unsigned long long*)(out + (size_t)n * kC + o) = pk4(v[0], v[1], v[2], v[3]);
        }
}

// ---------------------------------------------------------------------------
// q/k projection GEMM + fused per-head L2 norm + fused row-sum reduction.
// ---------------------------------------------------------------------------
__global__ __launch_bounds__(256) void mgemm_l2_kernel(
    const unsigned short* __restrict__ A, const unsigned short* __restrict__ B,
    unsigned short* __restrict__ out, float* __restrict__ red_out)
{
    __shared__ float ssq[2][2][4][16];
    __shared__ float rbuf[2][2][4][2][4];
    int nB = blockIdx.x * 128, oB = blockIdx.y * 64;
    int w = threadIdx.x >> 6, lane = threadIdx.x & 63;
    int l15 = lane & 15, g = lane >> 4;
    int wm = w & 1, wn = w >> 1;

    f32x4 acc[2][4];
#pragma unroll
    for (int mt = 0; mt < 2; ++mt)
#pragma unroll
        for (int nt = 0; nt < 4; ++nt) acc[mt][nt] = (f32x4){0.f,0.f,0.f,0.f};

    MGEMM_CORE(192, A + (size_t)(oB + wm * 32 + l15) * 192 + 8 * g,
                    B + (size_t)(nB + wn * 64 + l15) * 192 + 8 * g);

#pragma unroll
    for (int nt = 0; nt < 4; ++nt) {
        float s = 0.f;
#pragma unroll
        for (int mt = 0; mt < 2; ++mt) {
            f32x4 a = acc[mt][nt];
            s += (a[0]*a[0] + a[1]*a[1]) + (a[2]*a[2] + a[3]*a[3]);
        }
        s += __shfl_xor(s, 16);
        s += __shfl_xor(s, 32);
        if (g == 0) ssq[wm][wn][nt][l15] = s;
    }
    __syncthreads();

    float sc[4];
#pragma unroll
    for (int nt = 0; nt < 4; ++nt) {
        float ss2 = ssq[0][wn][nt][l15] + ssq[1][wn][nt][l15];
        sc[nt] = 1.0f / fmaxf(sqrtf(ss2), 1e-12f);
    }

#pragma unroll
    for (int nt = 0; nt < 4; ++nt) {
        int n = nB + wn * 64 + nt * 16 + l15;
#pragma unroll
        for (int mt = 0; mt < 2; ++mt) {
            int o = oB + wm * 32 + mt * 16 + 4 * g;
            f32x4 v = acc[mt][nt];
            *(unsigned long long*)(out + (size_t)n * kHID + o) =
                pk4(v[0]*sc[nt], v[1]*sc[nt], v[2]*sc[nt], v[3]*sc[nt]);
        }
    }

    float sred[2][4] = {};
#pragma unroll
    for (int nt = 0; nt < 4; ++nt)
#pragma unroll
        for (int mt = 0; mt < 2; ++mt) {
            f32x4 a = acc[mt][nt];
            sred[mt][0] += a[0] * sc[nt];
            sred[mt][1] += a[1] * sc[nt];
            sred[mt][2] += a[2] * sc[nt];
            sred[mt][3] += a[3] * sc[nt];
        }
#pragma unroll
    for (int off = 1; off < 16; off <<= 1)
#pragma unroll
        for (int mt = 0; mt < 2; ++mt)
#pragma unroll
            for (int r = 0; r < 4; ++r)
                sred[mt][r] += __shfl_xor(sred[mt][r], off);
    if (l15 == 0)
#pragma unroll
        for (int mt = 0; mt < 2; ++mt)
#pragma unroll
            for (int r = 0; r < 4; ++r)
                rbuf[wm][wn][g][mt][r] = sred[mt][r];
    __syncthreads();
    if (threadIdx.x < 64) {
        int o = threadIdx.x;
        int wm2 = o >> 5, mt2 = (o >> 4) & 1, g2 = (o >> 2) & 3, r2 = o & 3;
        float v = rbuf[wm2][0][g2][mt2][r2] + rbuf[wm2][1][g2][mt2][r2];
        int row = (nB & (kHW - 1)) >> 7;
        int b = nB >> 14;
        int bh = b * 8 + blockIdx.y;
        red_out[((size_t)(bh * 128 + row)) * 64 + o] = v;
    }
}

// ksum_w[bh][w][hc] = sum_h k
__global__ void sum_h_kernel(const unsigned short* __restrict__ buf, float* __restrict__ out)
{
    int w = blockIdx.x, bh = blockIdx.y, hc = threadIdx.x;
    int b = bh >> 3, nh = bh & 7;
    const unsigned short* p = buf + (size_t)(b * kHW + w) * kHID + nh * kHC + hc;
    float s = 0.f;
    for (int h = 0; h < kH; ++h) s += bf2f(p[(size_t)h * kW * kHID]);
    out[((size_t)bh * kW + w) * kHC + hc] = s;
}

// ---------------------------------------------------------------------------
// Fused qs-reduce + scores + top-16 (tie -> lower index).
// ---------------------------------------------------------------------------
__global__ void score_topk_kernel(const float* __restrict__ qpart,
                                  const float* __restrict__ ksum_h,
                                  const float* __restrict__ ksum_w,
                                  int* __restrict__ hidx, int* __restrict__ widx)
{
    __shared__ float qsl[2][64];
    __shared__ float hs[128], ws[128];
    int bh = blockIdx.x;
    int tid = threadIdx.x;               // 128
    int hc = tid & 63, grp = tid >> 6;
    {
        const float* qp = qpart + ((size_t)bh * 128 + grp * 64) * 64 + hc;
        float s = 0.f;
        for (int i = 0; i < 64; ++i) s += qp[(size_t)i * 64];
        qsl[grp][hc] = s;
    }
    __syncthreads();
    if (tid < 64) qsl[0][tid] += qsl[1][tid];
    __syncthreads();
    {
        const float* kh = ksum_h + ((size_t)bh * 128 + tid) * 64;
        const float* kw = ksum_w + ((size_t)bh * 128 + tid) * 64;
        float sh = 0.f, sw = 0.f;
        for (int c = 0; c < 64; ++c) {
            float q = qsl[0][c];
            sh += q * kh[c];
            sw += q * kw[c];
        }
        hs[tid] = sh; ws[tid] = sw;
    }
    __syncthreads();
    int sel = tid >> 6;
    const float* sc = sel ? ws : hs;
    int* out = (sel ? widx : hidx) + bh * kP;
    int lane = tid & 63;
    float v0 = sc[lane], v1 = sc[lane + 64];
    int i0 = lane, i1 = lane + 64;
    for (int p = 0; p < kP; ++p) {
        float bv; int bi;
        if (v1 > v0) { bv = v1; bi = i1; } else { bv = v0; bi = i0; }
#pragma unroll
        for (int off = 1; off < 64; off <<= 1) {
            float ov = __shfl_xor(bv, off);
            int   oi = __shfl_xor(bi, off);
            if (ov > bv || (ov == bv && oi < bi)) { bv = ov; bi = oi; }
        }
        if (lane == 0) out[p] = bi;
        if (i0 == bi) v0 = -INFINITY;
        if (i1 == bi) v1 = -INFINITY;
    }
}

// ---------------------------------------------------------------------------
// Gather kf; lazy-project vfT.
// ---------------------------------------------------------------------------
__global__ void gather_kv_kernel(const unsigned short* __restrict__ kpb,
                                 const unsigned short* __restrict__ xnb,
                                 const float* __restrict__ wv,
                                 const int* __restrict__ hidx, const int* __restrict__ widx,
                                 unsigned short* __restrict__ kf, unsigned short* __restrict__ vfT)
{
    int bh = blockIdx.y, p1 = blockIdx.x;
    int b = bh >> 3, nh = bh & 7;
    int hc = threadIdx.x & 63, pg = threadIdx.x >> 6;
    int hrow = hidx[bh * kP + p1];
    int o = nh * kHC + hc;
    const float* wvp = wv + (size_t)o * kC;
    for (int p2 = pg; p2 < kP; p2 += 4) {
        int wcol = widx[bh * kP + p2];
        int n = b * kHW + hrow * kW + wcol;
        int kidx = p1 * kP + p2;
        kf[((size_t)bh * 256 + kidx) * 64 + hc] = kpb[(size_t)n * kHID + nh * kHC + hc];
        const unsigned int* xr = (const unsigned int*)(xnb + (size_t)n * kC);
        float s = 0.f;
        for (int c2 = 0; c2 < kC / 2; ++c2) {
            unsigned int u = xr[c2];
            s += wvp[c2 * 2]     * bf2f((unsigned short)(u & 0xffff));
            s += wvp[c2 * 2 + 1] * bf2f((unsigned short)(u >> 16));
        }
        vfT[((size_t)bh * 64 + hc) * 256 + kidx] = f2bf(s);
    }
}

// ---------------------------------------------------------------------------
// MFMA attention, 2-round P staging (halved LDS -> higher occupancy).
// ---------------------------------------------------------------------------
__global__ __launch_bounds__(256) void attn_kernel(
    const unsigned short* __restrict__ qpb, unsigned short* __restrict__ ob,
    const unsigned short* __restrict__ kf, const unsigned short* __restrict__ vfT)
{
    __shared__ unsigned short pls[64 * 136];
    __shared__ float lred[4][4][16];

    int bh = blockIdx.y; int b = bh >> 3, nh = bh & 7;
    int n0 = b * kHW + blockIdx.x * 64;
    int tid = threadIdx.x;
    int w = tid >> 6, lane = tid & 63, l15 = lane & 15, g = lane >> 4;

    bf16x8 bq[4][2];
#pragma unroll
    for (int nt = 0; nt < 4; ++nt)
#pragma unroll
        for (int kt = 0; kt < 2; ++kt)
            bq[nt][kt] = *(const bf16x8*)(qpb + (size_t)(n0 + nt * 16 + l15) * kHID
                                          + nh * kHC + kt * 32 + 8 * g);

    const unsigned short* kfb = kf + (size_t)bh * 256 * 64;
    bf16x8 ak[4][2];
#pragma unroll
    for (int mt = 0; mt < 4; ++mt)
#pragma unroll
        for (int kt = 0; kt < 2; ++kt)
            ak[mt][kt] = *(const bf16x8*)&kfb[(size_t)(w * 64 + mt * 16 + l15) * 64 + kt * 32 + 8 * g];

    f32x4 acc[4][4];
#pragma unroll
    for (int mt = 0; mt < 4; ++mt)
#pragma unroll
        for (int nt = 0; nt < 4; ++nt) acc[mt][nt] = (f32x4){0.f,0.f,0.f,0.f};

#pragma unroll
    for (int kt = 0; kt < 2; ++kt)
#pragma unroll
        for (int mt = 0; mt < 4; ++mt)
#pragma unroll
            for (int nt = 0; nt < 4; ++nt)
                acc[mt][nt] = __builtin_amdgcn_mfma_f32_16x16x32_bf16(
                    ak[mt][kt], bq[nt][kt], acc[mt][nt], 0, 0, 0);

    // exp + denominators; waves 0,1 write their P (keys 0..127) now
    float lpart[4] = {0.f, 0.f, 0.f, 0.f};
#pragma unroll
    for (int mt = 0; mt < 4; ++mt)
#pragma unroll
        for (int nt = 0; nt < 4; ++nt) {
            float e0 = __expf(acc[mt][nt][0]);
            float e1 = __expf(acc[mt][nt][1]);
            float e2 = __expf(acc[mt][nt][2]);
            float e3 = __expf(acc[mt][nt][3]);
            lpart[nt] += (e0 + e1) + (e2 + e3);
            if (w < 2) {
                int qq = nt * 16 + l15;
                int k0 = (w & 1) * 64 + mt * 16 + 4 * g;
                *(unsigned long long*)&pls[qq * 136 + k0] = pk4(e0, e1, e2, e3);
            }
        }
#pragma unroll
    for (int nt = 0; nt < 4; ++nt) {
        lpart[nt] += __shfl_xor(lpart[nt], 16);
        lpart[nt] += __shfl_xor(lpart[nt], 32);
    }
    if (g == 0)
#pragma unroll
        for (int nt = 0; nt < 4; ++nt) lred[w][nt][l15] = lpart[nt];
    __syncthreads();

    const unsigned short* vfb = vfT + (size_t)bh * 64 * 256;
    f32x4 oacc[4];
#pragma unroll
    for (int nt = 0; nt < 4; ++nt) oacc[nt] = (f32x4){0.f,0.f,0.f,0.f};

    // PV round 0 (keys 0..127)
#pragma unroll
    for (int ks = 0; ks < 4; ++ks) {
        bf16x8 av = *(const bf16x8*)&vfb[(size_t)(w * 16 + l15) * 256 + ks * 32 + 8 * g];
#pragma unroll
        for (int nt = 0; nt < 4; ++nt) {
            bf16x8 bp = *(const bf16x8*)&pls[(nt * 16 + l15) * 136 + ks * 32 + 8 * g];
            oacc[nt] = __builtin_amdgcn_mfma_f32_16x16x32_bf16(av, bp, oacc[nt], 0, 0, 0);
        }
    }
    __syncthreads();
    // waves 2,3 write their P (keys 128..255); exp recomputed from live acc
    if (w >= 2) {
#pragma unroll
        for (int mt = 0; mt < 4; ++mt)
#pragma unroll
            for (int nt = 0; nt < 4; ++nt) {
                float e0 = __expf(acc[mt][nt][0]);
                float e1 = __expf(acc[mt][nt][1]);
                float e2 = __expf(acc[mt][nt][2]);
                float e3 = __expf(acc[mt][nt][3]);
                int qq = nt * 16 + l15;
                int k0 = (w & 1) * 64 + mt * 16 + 4 * g;
                *(unsigned long long*)&pls[qq * 136 + k0] = pk4(e0, e1, e2, e3);
            }
    }
    __syncthreads();
    // PV round 1 (keys 128..255)
#pragma unroll
    for (int ks = 0; ks < 4; ++ks) {
        bf16x8 av = *(const bf16x8*)&vfb[(size_t)(w * 16 + l15) * 256 + 128 + ks * 32 + 8 * g];
#pragma unroll
        for (int nt = 0; nt < 4; ++nt) {
            bf16x8 bp = *(const bf16x8*)&pls[(nt * 16 + l15) * 136 + ks * 32 + 8 * g];
            oacc[nt] = __builtin_amdgcn_mfma_f32_16x16x32_bf16(av, bp, oacc[nt], 0, 0, 0);
        }
    }

#pragma unroll
    for (int nt = 0; nt < 4; ++nt) {
        float l = lred[0][nt][l15] + lred[1][nt][l15] + lred[2][nt][l15] + lred[3][nt][l15];
        float inv = 1.0f / l;
        int qq = nt * 16 + l15;
        int hc0 = w * 16 + 4 * g;
        *(unsigned long long*)(ob + (size_t)(n0 + qq) * kHID + nh * kHC + hc0) =
            pk4(oacc[nt][0] * inv, oacc[nt][1] * inv, oacc[nt][2] * inv, oacc[nt][3] * inv);
    }
}

// ---------------------------------------------------------------------------
// Depthwise 3x3 SAME conv, pixel-major; fp32 or bf16 input, bf16 out [n][192].
// ---------------------------------------------------------------------------
template<int INBF16>
__global__ void dwconv_pm_kernel(const void* __restrict__ in, unsigned short* __restrict__ out,
                                 const float* __restrict__ wt, const float* __restrict__ bias)
{
    int idx = blockIdx.x * 256 + threadIdx.x;      // kN*48
    int n = idx / 48;
    int c0 = (idx - n * 48) * 4;
    int hw = n & (kHW - 1);
    int h = hw >> 7, ww = hw & 127;
    f32x4 s = *(const f32x4*)(bias + c0);
#pragma unroll
    for (int dy = -1; dy <= 1; ++dy) {
        int hh = h + dy;
        if (hh < 0 || hh >= kH) continue;
#pragma unroll
        for (int dx = -1; dx <= 1; ++dx) {
            int wx = ww + dx;
            if (wx < 0 || wx >= kW) continue;
            f32x4 v;
            if (INBF16)
                v = ubf4(*(const unsigned long long*)((const unsigned short*)in
                          + (size_t)(n + dy * kW + dx) * kC + c0));
            else
                v = *(const f32x4*)((const float*)in + (size_t)(n + dy * kW + dx) * kC + c0);
            int t = (dy + 1) * 3 + (dx + 1);
            s[0] += v[0] * wt[(c0 + 0) * 9 + t];
            s[1] += v[1] * wt[(c0 + 1) * 9 + t];
            s[2] += v[2] * wt[(c0 + 2) * 9 + t];
            s[3] += v[3] * wt[(c0 + 3) * 9 + t];
        }
    }
    *(unsigned long long*)(out + (size_t)n * kC + c0) = pk4(s[0], s[1], s[2], s[3]);
}

// ---------------------------------------------------------------------------
// Instance-norm stats (bf16 input) via per-chunk atomics.
// ---------------------------------------------------------------------------
__global__ void istats_bf16_kernel(const unsigned short* __restrict__ in, float* __restrict__ acc)
{
    int n0 = blockIdx.x * 64;
    int b = n0 >> 14;
    int c = threadIdx.x;
    float s = 0.f, ss = 0.f;
    for (int p = 0; p < 64; ++p) {
        float v = bf2f(in[(size_t)(n0 + p) * kC + c]);
        s += v; ss += v * v;
    }
    atomicAdd(&acc[(size_t)(b * kC + c) * 2],     s);
    atomicAdd(&acc[(size_t)(b * kC + c) * 2 + 1], ss);
}

__device__ inline void inorm_ms(const float* acc, int b, int c, float& m, float& rs)
{
    float s  = acc[(size_t)(b * kC + c) * 2];
    float ss = acc[(size_t)(b * kC + c) * 2 + 1];
    m = s * (1.0f / kHW);
    float var = ss * (1.0f / kHW) - m * m;
    rs = rsqrtf(var + kEPS);
}

// MODE 0: gelu(inorm(in)) -> bf16.  MODE 1: gelu(inorm(in)) + add -> bf16.
template<int MODE>
__global__ void apply_pm_kernel(const unsigned short* __restrict__ in, const float* __restrict__ acc,
                                unsigned short* __restrict__ out, const unsigned short* __restrict__ addsrc)
{
    int idx = blockIdx.x * 256 + threadIdx.x;      // kN*48
    int n = idx / 48;
    int c0 = (idx - n * 48) * 4;
    int b = n >> 14;
    f32x4 v = ubf4(*(const unsigned long long*)(in + (size_t)n * kC + c0));
    f32x4 r;
#pragma unroll
    for (int j = 0; j < 4; ++j) {
        float m, rs;
        inorm_ms(acc, b, c0 + j, m, rs);
        float x = (v[j] - m) * rs;
        r[j] = 0.5f * x * (1.0f + erff(x * 0.70710678118654752f));
    }
    if (MODE == 1)
        r += ubf4(*(const unsigned long long*)(addsrc + (size_t)n * kC + c0));
    *(unsigned long long*)(out + (size_t)n * kC + c0) = pk4(r[0], r[1], r[2], r[3]);
}

// Final inorm, bf16 in -> NCHW fp32 d_out.
__global__ void final_kernel(const unsigned short* __restrict__ in, const float* __restrict__ acc,
                             float* __restrict__ out)
{
    int id = blockIdx.x * 256 + threadIdx.x;       // kC*kN/4
    int oid = id * 4;
    int q = oid >> 14;
    int hw = oid & (kHW - 1);
    int b = (q >= kC) ? 1 : 0;
    int c = q - b * kC;
    float m, rs;
    inorm_ms(acc, b, c, m, rs);
    int n = b * kHW + hw;
    f32x4 o;
#pragma unroll
    for (int j = 0; j < 4; ++j)
        o[j] = (bf2f(in[(size_t)(n + j) * kC + c]) - m) * rs;
    *(f32x4*)(out + (size_t)oid) = o;
}

// ---------------------------------------------------------------------------
extern "C" void kernel_launch(void* const* d_in, const int* in_sizes, int n_in,
                              void* d_out, int out_size, void* d_ws, size_t ws_size,
                              hipStream_t stream)
{
    const float* x     = (const float*)d_in[0];
    const float* ln1_g = (const float*)d_in[1];
    const float* ln1_b = (const float*)d_in[2];
    const float* wq    = (const float*)d_in[3];
    const float* wk    = (const float*)d_in[4];
    const float* wv    = (const float*)d_in[5];
    const float* wo    = (const float*)d_in[6];
    const float* bo    = (const float*)d_in[7];
    const float* dw_w  = (const float*)d_in[8];
    const float* dw_b  = (const float*)d_in[9];
    const float* mlp_w = (const float*)d_in[10];
    const float* mlp_b = (const float*)d_in[11];
    const float* ln2_g = (const float*)d_in[12];
    const float* ln2_b = (const float*)d_in[13];
    const float* c1_w  = (const float*)d_in[14];
    const float* c1_b  = (const float*)d_in[15];
    const float* res_w = (const float*)d_in[16];
    const float* res_b = (const float*)d_in[17];
    const float* c2_w  = (const float*)d_in[18];
    const float* c2_b  = (const float*)d_in[19];

    char* base = (char*)d_ws;
    float* XP = (float*)(base);                                  // fp32 [n][192] raw x
    unsigned short* XNb = (unsigned short*)(base + 25165824);    // bf16 [n][192] xn / Y1
    unsigned short* QPb = (unsigned short*)(base + 37748736);    // bf16 [n][512]; later F / T2
    unsigned short* F   = QPb;
    unsigned short* T2  = QPb;
    unsigned short* KPb = (unsigned short*)(base + 71303168);    // bf16 [n][512]; OB alias; later Y2
    unsigned short* OB  = KPb;
    unsigned short* Y2  = KPb;
    unsigned short* LB  = (unsigned short*)(base + 104857600);   // bf16 [n][192] local; later Y3
    unsigned short* Y3  = LB;
    unsigned short* T1  = (unsigned short*)(base + 117440512);   // bf16 [n][192]; later R
    unsigned short* R   = T1;
    char* sm = base + 130023424;
    float* qpart  = (float*)(sm);                 sm += 524288;   // [16][128][64]
    float* ksum_h = (float*)(sm);                 sm += 524288;
    float* ksum_w = (float*)(sm);                 sm += 524288;
    float* acc0   = (float*)(sm);                 sm += 3072;
    float* acc1   = (float*)(sm);                 sm += 3072;
    float* acc2   = (float*)(sm);                 sm += 3072;
    unsigned short* kf   = (unsigned short*)(sm); sm += 524288;
    unsigned short* vfT  = (unsigned short*)(sm); sm += 524288;
    unsigned short* wqb  = (unsigned short*)(sm); sm += 196608;
    unsigned short* wkb  = (unsigned short*)(sm); sm += 196608;
    unsigned short* mlpb1= (unsigned short*)(sm); sm += 73728;
    unsigned short* c1b  = (unsigned short*)(sm); sm += 73728;
    unsigned short* c2b  = (unsigned short*)(sm); sm += 73728;
    unsigned short* w2pb = (unsigned short*)(sm); sm += 196608;
    float* bp2 = (float*)(sm);                    sm += 1024;
    int* hidx = (int*)(sm);                       sm += 1024;
    int* widx = (int*)(sm);

    // --- prep ---
    prep_kernel<<<1209, 256, 0, stream>>>(acc0, wq, wk, mlp_w, c1_w, c2_w,
                                          wqb, wkb, mlpb1, c1b, c2b);
    wfuse_kernel<<<384, 256, 0, stream>>>(mlp_w, wo, mlp_b, bo, w2pb, bp2);
    txln_kernel<<<dim3(kHW / 64, kB), 256, 0, stream>>>(x, XP, XNb, ln1_g, ln1_b);

    // --- attention branch ---
    mgemm_l2_kernel<<<dim3(kN / 128, kNH), 256, 0, stream>>>(wqb, XNb, QPb, qpart);
    mgemm_l2_kernel<<<dim3(kN / 128, kNH), 256, 0, stream>>>(wkb, XNb, KPb, ksum_h);
    sum_h_kernel<<<dim3(kW, 16), 64, 0, stream>>>(KPb, ksum_w);
    score_topk_kernel<<<16, 128, 0, stream>>>(qpart, ksum_h, ksum_w, hidx, widx);
    gather_kv_kernel<<<dim3(kP, 16), 256, 0, stream>>>(KPb, XNb, wv, hidx, widx, kf, vfT);
    attn_kernel<<<dim3(kHW / 64, 16), 256, 0, stream>>>(QPb, OB, kf, vfT);

    // --- local branch + fused mlp (wo folded in) ---
    dwconv_pm_kernel<0><<<(kN * 48) / 256, 256, 0, stream>>>(XP, LB, dw_w, dw_b);
    mgemm_mlp_kernel<<<dim3(kN / 128, kC / 64), 256, 0, stream>>>(mlpb1, LB, w2pb, OB, F, bp2, XP);

    // --- tail ---
    ln_pm_bf16_kernel<<<kN / 256, 256, 0, stream>>>(F, XNb, ln2_g, ln2_b);     // Y1 = XNb
    mgemm_is_kernel<<<dim3(kN / 128, kC / 64), 256, 0, stream>>>(c1b, XNb, T1, c1_b, acc0);
    apply_pm_kernel<0><<<(kN * 48) / 256, 256, 0, stream>>>(T1, acc0, Y2, nullptr);
    dwconv_pm_kernel<1><<<(kN * 48) / 256, 256, 0, stream>>>(Y2, R, res_w, res_b);
    istats_bf16_kernel<<<kN / 64, 192, 0, stream>>>(R, acc1);
    apply_pm_kernel<1><<<(kN * 48) / 256, 256, 0, stream>>>(R, acc1, Y3, Y2);
    mgemm_is_kernel<<<dim3(kN / 128, kC / 64), 256, 0, stream>>>(c2b, Y3, T2, c2_b, acc2);
    final_kernel<<<(kC * kN / 4) / 256, 256, 0, stream>>>(T2, acc2, (float*)d_out);
}

// Round 7
// 497.234 us; speedup vs baseline: 4.0773x; 1.0981x over previous
//
#include <hip/hip_runtime.h>
#include <math.h>

constexpr int kC   = 192;
constexpr int kNH  = 8;
constexpr int kHC  = 64;
constexpr int kHID = 512;
constexpr int kP   = 16;
constexpr int kB   = 2;
constexpr int kH   = 128;
constexpr int kW   = 128;
constexpr int kHW  = kH * kW;      // 16384
constexpr int kN   = kB * kHW;     // 32768
constexpr float kEPS = 1e-5f;

typedef __attribute__((ext_vector_type(8))) short bf16x8;
typedef __attribute__((ext_vector_type(4))) float f32x4;

__device__ inline unsigned short f2bf(float f) {
    unsigned int u = __builtin_bit_cast(unsigned int, f);
    unsigned int r = (u + 0x7FFFu + ((u >> 16) & 1u)) >> 16;   // RNE
    return (unsigned short)r;
}
__device__ inline float bf2f(unsigned short u) {
    return __builtin_bit_cast(float, (unsigned int)u << 16);
}
__device__ inline unsigned int cvtpk(float lo, float hi) {
    unsigned int r;
    asm("v_cvt_pk_bf16_f32 %0, %1, %2" : "=v"(r) : "v"(lo), "v"(hi));
    return r;
}
__device__ inline unsigned long long pk4(float a, float b, float c, float d) {
    return (unsigned long long)cvtpk(a, b) | ((unsigned long long)cvtpk(c, d) << 32);
}
__device__ inline f32x4 ubf4(unsigned long long u) {
    f32x4 r;
    r[0] = bf2f((unsigned short)u);
    r[1] = bf2f((unsigned short)(u >> 16));
    r[2] = bf2f((unsigned short)(u >> 32));
    r[3] = bf2f((unsigned short)(u >> 48));
    return r;
}

// ---------------------------------------------------------------------------
// Prep: zero istats accumulators + bf16 weight conversions.
// ---------------------------------------------------------------------------
__global__ void prep_kernel(float* __restrict__ acc,
                            const float* wq, const float* wk, const float* wm,
                            const float* c1, const float* c2,
                            unsigned short* wqb, unsigned short* wkb,
                            unsigned short* mlpb1, unsigned short* c1b, unsigned short* c2b)
{
    int i = blockIdx.x * 256 + threadIdx.x;
    if (i < 2304) { acc[i] = 0.f; return; }
    i -= 2304;
    if (i < 98304) { wqb[i] = f2bf(wq[i]); return; }
    i -= 98304;
    if (i < 98304) { wkb[i] = f2bf(wk[i]); return; }
    i -= 98304;
    if (i < 36864) { int o = i / 192, k = i - o * 192; mlpb1[i] = f2bf(wm[o * 384 + k]); return; }
    i -= 36864;
    if (i < 36864) { c1b[i] = f2bf(c1[i]); return; }
    i -= 36864;
    if (i < 36864) { c2b[i] = f2bf(c2[i]); return; }
}

// ---------------------------------------------------------------------------
// Fused weight: W2'[o][j] = sum_c mlp_w[o][192+c]*wo[c][j]  (bf16 out)
//               bp2[o]    = mlp_b[o] + sum_c mlp_w[o][192+c]*bo[c]
// ---------------------------------------------------------------------------
__global__ void wfuse_kernel(const float* __restrict__ mlp_w, const float* __restrict__ wo,
                             const float* __restrict__ mlp_b, const float* __restrict__ bo,
                             unsigned short* __restrict__ w2pb, float* __restrict__ bp2)
{
    int i = blockIdx.x * 256 + threadIdx.x;   // 98304
    int o = i >> 9, j = i & 511;
    const float* a = mlp_w + o * 384 + 192;
    float s = 0.f;
    for (int c = 0; c < 192; ++c) s += a[c] * wo[c * 512 + j];
    w2pb[o * 512 + j] = f2bf(s);
    if (j == 0) {
        float t = mlp_b[o];
        for (int c = 0; c < 192; ++c) t += a[c] * bo[c];
        bp2[o] = t;
    }
}

// ---------------------------------------------------------------------------
// Fused transpose + ln1: x NCHW fp32 -> XP raw fp32 [n][192] + XNb bf16 [n][192]
// ---------------------------------------------------------------------------
__global__ __launch_bounds__(256) void txln_kernel(const float* __restrict__ x,
                                                   float* __restrict__ xp,
                                                   unsigned short* __restrict__ xnb,
                                                   const float* __restrict__ g,
                                                   const float* __restrict__ bb)
{
    __shared__ float tile[192][65];
    __shared__ float red[2][4][64];
    __shared__ float pms[64], prs[64];
    int hw0 = blockIdx.x * 64;
    int b   = blockIdx.y;
    int tid = threadIdx.x;
    for (int i = tid; i < 192 * 64; i += 256) {
        int c = i >> 6, p = i & 63;
        tile[c][p] = x[(size_t)(b * kC + c) * kHW + hw0 + p];
    }
    __syncthreads();
    {
        int p = tid & 63, qt = tid >> 6;
        float s = 0.f, ss = 0.f;
        for (int c = qt * 48; c < qt * 48 + 48; ++c) {
            float v = tile[c][p]; s += v; ss += v * v;
        }
        red[0][qt][p] = s; red[1][qt][p] = ss;
    }
    __syncthreads();
    if (tid < 64) {
        float s  = red[0][0][tid] + red[0][1][tid] + red[0][2][tid] + red[0][3][tid];
        float ss = red[1][0][tid] + red[1][1][tid] + red[1][2][tid] + red[1][3][tid];
        float m = s * (1.0f / kC);
        float var = ss * (1.0f / kC) - m * m;
        pms[tid] = m;
        prs[tid] = rsqrtf(var + kEPS);
    }
    __syncthreads();
    for (int i = tid; i < 64 * 192; i += 256) {
        int p = i / 192, c = i - p * 192;
        float raw = tile[c][p];
        size_t oi = (size_t)(b * kHW + hw0 + p) * kC + c;
        xp[oi] = raw;
        xnb[oi] = f2bf((raw - pms[p]) * prs[p] * g[c] + bb[c]);
    }
}

// ---------------------------------------------------------------------------
// LayerNorm over channels, bf16 in -> bf16 out (ln2). Two-pass re-read (second
// pass hits L1/L2) -- NO register caching (a 48x f32x4 array spills to scratch).
// ---------------------------------------------------------------------------
__global__ void ln_pm_bf16_kernel(const unsigned short* __restrict__ in,
                                  unsigned short* __restrict__ out,
                                  const float* __restrict__ g, const float* __restrict__ bb)
{
    int n = blockIdx.x * 256 + threadIdx.x;
    if (n >= kN) return;
    const unsigned long long* ip = (const unsigned long long*)(in + (size_t)n * kC);
    float s = 0.f, ss = 0.f;
#pragma unroll
    for (int r = 0; r < 48; ++r) {
        f32x4 v = ubf4(ip[r]);
        s  += (v[0] + v[1]) + (v[2] + v[3]);
        ss += (v[0]*v[0] + v[1]*v[1]) + (v[2]*v[2] + v[3]*v[3]);
    }
    float m  = s * (1.0f / kC);
    float var = ss * (1.0f / kC) - m * m;
    float rs = rsqrtf(var + kEPS);
    unsigned long long* op = (unsigned long long*)(out + (size_t)n * kC);
#pragma unroll
    for (int r = 0; r < 48; ++r) {
        f32x4 v = ubf4(ip[r]);
        f32x4 gg = *(const f32x4*)(g + r * 4);
        f32x4 bv = *(const f32x4*)(bb + r * 4);
        op[r] = pk4((v[0]-m)*rs*gg[0] + bv[0], (v[1]-m)*rs*gg[1] + bv[1],
                    (v[2]-m)*rs*gg[2] + bv[2], (v[3]-m)*rs*gg[3] + bv[3]);
    }
}

#define MGEMM_CORE(KVAL, APTR, BPTR)                                              \
    {                                                                             \
        const unsigned short* Ap = APTR;                                          \
        const unsigned short* Bp = BPTR;                                          \
        _Pragma("unroll 2")                                                       \
        for (int k = 0; k < KVAL; k += 32) {                                      \
            bf16x8 a0 = *(const bf16x8*)(Ap + k);                                 \
            bf16x8 a1 = *(const bf16x8*)(Ap + (size_t)16 * KVAL + k);             \
            bf16x8 b0 = *(const bf16x8*)(Bp + k);                                 \
            bf16x8 b1 = *(const bf16x8*)(Bp + (size_t)16 * KVAL + k);             \
            bf16x8 b2 = *(const bf16x8*)(Bp + (size_t)32 * KVAL + k);             \
            bf16x8 b3 = *(const bf16x8*)(Bp + (size_t)48 * KVAL + k);             \
            acc[0][0] = __builtin_amdgcn_mfma_f32_16x16x32_bf16(a0, b0, acc[0][0], 0, 0, 0); \
            acc[0][1] = __builtin_amdgcn_mfma_f32_16x16x32_bf16(a0, b1, acc[0][1], 0, 0, 0); \
            acc[0][2] = __builtin_amdgcn_mfma_f32_16x16x32_bf16(a0, b2, acc[0][2], 0, 0, 0); \
            acc[0][3] = __builtin_amdgcn_mfma_f32_16x16x32_bf16(a0, b3, acc[0][3], 0, 0, 0); \
            acc[1][0] = __builtin_amdgcn_mfma_f32_16x16x32_bf16(a1, b0, acc[1][0], 0, 0, 0); \
            acc[1][1] = __builtin_amdgcn_mfma_f32_16x16x32_bf16(a1, b1, acc[1][1], 0, 0, 0); \
            acc[1][2] = __builtin_amdgcn_mfma_f32_16x16x32_bf16(a1, b2, acc[1][2], 0, 0, 0); \
            acc[1][3] = __builtin_amdgcn_mfma_f32_16x16x32_bf16(a1, b3, acc[1][3], 0, 0, 0); \
        }                                                                         \
    }

// ---------------------------------------------------------------------------
// c1/c2 GEMM: bf16 out [n][192] + bias + fused instance-norm partial stats.
// ---------------------------------------------------------------------------
__global__ __launch_bounds__(256) void mgemm_is_kernel(
    const unsigned short* __restrict__ A, const unsigned short* __restrict__ B,
    unsigned short* __restrict__ out, const float* __restrict__ bias,
    float* __restrict__ accp)
{
    __shared__ float sa[2][64], qa[2][64];
    int nB = blockIdx.x * 128, oB = blockIdx.y * 64;
    int w = threadIdx.x >> 6, lane = threadIdx.x & 63;
    int l15 = lane & 15, g = lane >> 4;
    int wm = w & 1, wn = w >> 1;

    f32x4 acc[2][4];
#pragma unroll
    for (int mt = 0; mt < 2; ++mt)
#pragma unroll
        for (int nt = 0; nt < 4; ++nt) acc[mt][nt] = (f32x4){0.f,0.f,0.f,0.f};

    MGEMM_CORE(192, A + (size_t)(oB + wm * 32 + l15) * 192 + 8 * g,
                    B + (size_t)(nB + wn * 64 + l15) * 192 + 8 * g);

    f32x4 vv[2][4];
#pragma unroll
    for (int mt = 0; mt < 2; ++mt)
#pragma unroll
        for (int nt = 0; nt < 4; ++nt) {
            int o = oB + wm * 32 + mt * 16 + 4 * g;
            int n = nB + wn * 64 + nt * 16 + l15;
            f32x4 v = acc[mt][nt] + *(const f32x4*)(bias + o);
            vv[mt][nt] = v;
            *(unsigned long long*)(out + (size_t)n * kC + o) = pk4(v[0], v[1], v[2], v[3]);
        }
    float s2[2][4] = {}, q2[2][4] = {};
#pragma unroll
    for (int mt = 0; mt < 2; ++mt)
#pragma unroll
        for (int nt = 0; nt < 4; ++nt)
#pragma unroll
            for (int r = 0; r < 4; ++r) {
                float v = vv[mt][nt][r];
                s2[mt][r] += v; q2[mt][r] += v * v;
            }
#pragma unroll
    for (int off = 1; off < 16; off <<= 1)
#pragma unroll
        for (int mt = 0; mt < 2; ++mt)
#pragma unroll
            for (int r = 0; r < 4; ++r) {
                s2[mt][r] += __shfl_xor(s2[mt][r], off);
                q2[mt][r] += __shfl_xor(q2[mt][r], off);
            }
    if (l15 == 0)
#pragma unroll
        for (int mt = 0; mt < 2; ++mt)
#pragma unroll
            for (int r = 0; r < 4; ++r) {
                int ol = wm * 32 + mt * 16 + 4 * g + r;
                sa[wn][ol] = s2[mt][r];
                qa[wn][ol] = q2[mt][r];
            }
    __syncthreads();
    if (threadIdx.x < 128) {
        int ol = threadIdx.x & 63, st = threadIdx.x >> 6;
        float v = st ? (qa[0][ol] + qa[1][ol]) : (sa[0][ol] + sa[1][ol]);
        int b = nB >> 14;
        atomicAdd(&accp[(size_t)(b * kC + oB + ol) * 2 + st], v);
    }
}

// ---------------------------------------------------------------------------
// Fused MLP: F = mlp_w1@LB + W2'@OB + bp2 + x   (bf16 out [n][192])
// ---------------------------------------------------------------------------
__global__ __launch_bounds__(256) void mgemm_mlp_kernel(
    const unsigned short* __restrict__ A1, const unsigned short* __restrict__ B1,
    const unsigned short* __restrict__ A2, const unsigned short* __restrict__ B2,
    unsigned short* __restrict__ out, const float* __restrict__ bp2,
    const float* __restrict__ res)
{
    int nB = blockIdx.x * 128, oB = blockIdx.y * 64;
    int w = threadIdx.x >> 6, lane = threadIdx.x & 63;
    int l15 = lane & 15, g = lane >> 4;
    int wm = w & 1, wn = w >> 1;

    f32x4 acc[2][4];
#pragma unroll
    for (int mt = 0; mt < 2; ++mt)
#pragma unroll
        for (int nt = 0; nt < 4; ++nt) acc[mt][nt] = (f32x4){0.f,0.f,0.f,0.f};

    MGEMM_CORE(192, A1 + (size_t)(oB + wm * 32 + l15) * 192 + 8 * g,
                    B1 + (size_t)(nB + wn * 64 + l15) * 192 + 8 * g);
    MGEMM_CORE(512, A2 + (size_t)(oB + wm * 32 + l15) * 512 + 8 * g,
                    B2 + (size_t)(nB + wn * 64 + l15) * 512 + 8 * g);

#pragma unroll
    for (int mt = 0; mt < 2; ++mt)
#pragma unroll
        for (int nt = 0; nt < 4; ++nt) {
            int o = oB + wm * 32 + mt * 16 + 4 * g;
            int n = nB + wn * 64 + nt * 16 + l15;
            f32x4 v = acc[mt][nt];
            v[0] += bp2[o]; v[1] += bp2[o+1]; v[2] += bp2[o+2]; v[3] += bp2[o+3];
            v += *(const f32x4*)(res + (size_t)n * kC + o);
            *(unsigned long long*)(out + (size_t)n * kC + o) = pk4(v[0], v[1], v[2], v[3]);
        }
}

// ---------------------------------------------------------------------------
// q/k projection GEMM + fused per-head L2 norm + fused row-sum reduction.
// ---------------------------------------------------------------------------
__global__ __launch_bounds__(256) void mgemm_l2_kernel(
    const unsigned short* __restrict__ A, const unsigned short* __restrict__ B,
    unsigned short* __restrict__ out, float* __restrict__ red_out)
{
    __shared__ float ssq[2][2][4][16];
    __shared__ float rbuf[2][2][4][2][4];
    int nB = blockIdx.x * 128, oB = blockIdx.y * 64;
    int w = threadIdx.x >> 6, lane = threadIdx.x & 63;
    int l15 = lane & 15, g = lane >> 4;
    int wm = w & 1, wn = w >> 1;

    f32x4 acc[2][4];
#pragma unroll
    for (int mt = 0; mt < 2; ++mt)
#pragma unroll
        for (int nt = 0; nt < 4; ++nt) acc[mt][nt] = (f32x4){0.f,0.f,0.f,0.f};

    MGEMM_CORE(192, A + (size_t)(oB + wm * 32 + l15) * 192 + 8 * g,
                    B + (size_t)(nB + wn * 64 + l15) * 192 + 8 * g);

#pragma unroll
    for (int nt = 0; nt < 4; ++nt) {
        float s = 0.f;
#pragma unroll
        for (int mt = 0; mt < 2; ++mt) {
            f32x4 a = acc[mt][nt];
            s += (a[0]*a[0] + a[1]*a[1]) + (a[2]*a[2] + a[3]*a[3]);
        }
        s += __shfl_xor(s, 16);
        s += __shfl_xor(s, 32);
        if (g == 0) ssq[wm][wn][nt][l15] = s;
    }
    __syncthreads();

    float sc[4];
#pragma unroll
    for (int nt = 0; nt < 4; ++nt) {
        float ss2 = ssq[0][wn][nt][l15] + ssq[1][wn][nt][l15];
        sc[nt] = 1.0f / fmaxf(sqrtf(ss2), 1e-12f);
    }

#pragma unroll
    for (int nt = 0; nt < 4; ++nt) {
        int n = nB + wn * 64 + nt * 16 + l15;
#pragma unroll
        for (int mt = 0; mt < 2; ++mt) {
            int o = oB + wm * 32 + mt * 16 + 4 * g;
            f32x4 v = acc[mt][nt];
            *(unsigned long long*)(out + (size_t)n * kHID + o) =
                pk4(v[0]*sc[nt], v[1]*sc[nt], v[2]*sc[nt], v[3]*sc[nt]);
        }
    }

    float sred[2][4] = {};
#pragma unroll
    for (int nt = 0; nt < 4; ++nt)
#pragma unroll
        for (int mt = 0; mt < 2; ++mt) {
            f32x4 a = acc[mt][nt];
            sred[mt][0] += a[0] * sc[nt];
            sred[mt][1] += a[1] * sc[nt];
            sred[mt][2] += a[2] * sc[nt];
            sred[mt][3] += a[3] * sc[nt];
        }
#pragma unroll
    for (int off = 1; off < 16; off <<= 1)
#pragma unroll
        for (int mt = 0; mt < 2; ++mt)
#pragma unroll
            for (int r = 0; r < 4; ++r)
                sred[mt][r] += __shfl_xor(sred[mt][r], off);
    if (l15 == 0)
#pragma unroll
        for (int mt = 0; mt < 2; ++mt)
#pragma unroll
            for (int r = 0; r < 4; ++r)
                rbuf[wm][wn][g][mt][r] = sred[mt][r];
    __syncthreads();
    if (threadIdx.x < 64) {
        int o = threadIdx.x;
        int wm2 = o >> 5, mt2 = (o >> 4) & 1, g2 = (o >> 2) & 3, r2 = o & 3;
        float v = rbuf[wm2][0][g2][mt2][r2] + rbuf[wm2][1][g2][mt2][r2];
        int row = (nB & (kHW - 1)) >> 7;
        int b = nB >> 14;
        int bh = b * 8 + blockIdx.y;
        red_out[((size_t)(bh * 128 + row)) * 64 + o] = v;
    }
}

// ksum_w[bh][w][hc] = sum_h k
__global__ void sum_h_kernel(const unsigned short* __restrict__ buf, float* __restrict__ out)
{
    int w = blockIdx.x, bh = blockIdx.y, hc = threadIdx.x;
    int b = bh >> 3, nh = bh & 7;
    const unsigned short* p = buf + (size_t)(b * kHW + w) * kHID + nh * kHC + hc;
    float s = 0.f;
    for (int h = 0; h < kH; ++h) s += bf2f(p[(size_t)h * kW * kHID]);
    out[((size_t)bh * kW + w) * kHC + hc] = s;
}

// ---------------------------------------------------------------------------
// Fused qs-reduce + scores + top-16 (tie -> lower index).
// ---------------------------------------------------------------------------
__global__ void score_topk_kernel(const float* __restrict__ qpart,
                                  const float* __restrict__ ksum_h,
                                  const float* __restrict__ ksum_w,
                                  int* __restrict__ hidx, int* __restrict__ widx)
{
    __shared__ float qsl[2][64];
    __shared__ float hs[128], ws[128];
    int bh = blockIdx.x;
    int tid = threadIdx.x;               // 128
    int hc = tid & 63, grp = tid >> 6;
    {
        const float* qp = qpart + ((size_t)bh * 128 + grp * 64) * 64 + hc;
        float s = 0.f;
        for (int i = 0; i < 64; ++i) s += qp[(size_t)i * 64];
        qsl[grp][hc] = s;
    }
    __syncthreads();
    if (tid < 64) qsl[0][tid] += qsl[1][tid];
    __syncthreads();
    {
        const float* kh = ksum_h + ((size_t)bh * 128 + tid) * 64;
        const float* kw = ksum_w + ((size_t)bh * 128 + tid) * 64;
        float sh = 0.f, sw = 0.f;
        for (int c = 0; c < 64; ++c) {
            float q = qsl[0][c];
            sh += q * kh[c];
            sw += q * kw[c];
        }
        hs[tid] = sh; ws[tid] = sw;
    }
    __syncthreads();
    int sel = tid >> 6;
    const float* sc = sel ? ws : hs;
    int* out = (sel ? widx : hidx) + bh * kP;
    int lane = tid & 63;
    float v0 = sc[lane], v1 = sc[lane + 64];
    int i0 = lane, i1 = lane + 64;
    for (int p = 0; p < kP; ++p) {
        float bv; int bi;
        if (v1 > v0) { bv = v1; bi = i1; } else { bv = v0; bi = i0; }
#pragma unroll
        for (int off = 1; off < 64; off <<= 1) {
            float ov = __shfl_xor(bv, off);
            int   oi = __shfl_xor(bi, off);
            if (ov > bv || (ov == bv && oi < bi)) { bv = ov; bi = oi; }
        }
        if (lane == 0) out[p] = bi;
        if (i0 == bi) v0 = -INFINITY;
        if (i1 == bi) v1 = -INFINITY;
    }
}

// ---------------------------------------------------------------------------
// Gather kf; lazy-project vfT.
// ---------------------------------------------------------------------------
__global__ void gather_kv_kernel(const unsigned short* __restrict__ kpb,
                                 const unsigned short* __restrict__ xnb,
                                 const float* __restrict__ wv,
                                 const int* __restrict__ hidx, const int* __restrict__ widx,
                                 unsigned short* __restrict__ kf, unsigned short* __restrict__ vfT)
{
    int bh = blockIdx.y, p1 = blockIdx.x;
    int b = bh >> 3, nh = bh & 7;
    int hc = threadIdx.x & 63, pg = threadIdx.x >> 6;
    int hrow = hidx[bh * kP + p1];
    int o = nh * kHC + hc;
    const float* wvp = wv + (size_t)o * kC;
    for (int p2 = pg; p2 < kP; p2 += 4) {
        int wcol = widx[bh * kP + p2];
        int n = b * kHW + hrow * kW + wcol;
        int kidx = p1 * kP + p2;
        kf[((size_t)bh * 256 + kidx) * 64 + hc] = kpb[(size_t)n * kHID + nh * kHC + hc];
        const unsigned int* xr = (const unsigned int*)(xnb + (size_t)n * kC);
        float s = 0.f;
        for (int c2 = 0; c2 < kC / 2; ++c2) {
            unsigned int u = xr[c2];
            s += wvp[c2 * 2]     * bf2f((unsigned short)(u & 0xffff));
            s += wvp[c2 * 2 + 1] * bf2f((unsigned short)(u >> 16));
        }
        vfT[((size_t)bh * 64 + hc) * 256 + kidx] = f2bf(s);
    }
}

// ---------------------------------------------------------------------------
// MFMA attention (round-5 structure: single P stage, stride-272 LDS).
// ---------------------------------------------------------------------------
__global__ __launch_bounds__(256) void attn_kernel(
    const unsigned short* __restrict__ qpb, unsigned short* __restrict__ ob,
    const unsigned short* __restrict__ kf, const unsigned short* __restrict__ vfT)
{
    __shared__ unsigned short pls[64 * 272];
    __shared__ float lred[4][4][16];

    int bh = blockIdx.y; int b = bh >> 3, nh = bh & 7;
    int n0 = b * kHW + blockIdx.x * 64;
    int tid = threadIdx.x;
    int w = tid >> 6, lane = tid & 63, l15 = lane & 15, g = lane >> 4;

    bf16x8 bq[4][2];
#pragma unroll
    for (int nt = 0; nt < 4; ++nt)
#pragma unroll
        for (int kt = 0; kt < 2; ++kt)
            bq[nt][kt] = *(const bf16x8*)(qpb + (size_t)(n0 + nt * 16 + l15) * kHID
                                          + nh * kHC + kt * 32 + 8 * g);

    const unsigned short* kfb = kf + (size_t)bh * 256 * 64;
    bf16x8 ak[4][2];
#pragma unroll
    for (int mt = 0; mt < 4; ++mt)
#pragma unroll
        for (int kt = 0; kt < 2; ++kt)
            ak[mt][kt] = *(const bf16x8*)&kfb[(size_t)(w * 64 + mt * 16 + l15) * 64 + kt * 32 + 8 * g];

    f32x4 acc[4][4];
#pragma unroll
    for (int mt = 0; mt < 4; ++mt)
#pragma unroll
        for (int nt = 0; nt < 4; ++nt) acc[mt][nt] = (f32x4){0.f,0.f,0.f,0.f};

#pragma unroll
    for (int kt = 0; kt < 2; ++kt)
#pragma unroll
        for (int mt = 0; mt < 4; ++mt)
#pragma unroll
            for (int nt = 0; nt < 4; ++nt)
                acc[mt][nt] = __builtin_amdgcn_mfma_f32_16x16x32_bf16(
                    ak[mt][kt], bq[nt][kt], acc[mt][nt], 0, 0, 0);

    float lpart[4] = {0.f, 0.f, 0.f, 0.f};
#pragma unroll
    for (int mt = 0; mt < 4; ++mt)
#pragma unroll
        for (int nt = 0; nt < 4; ++nt) {
            float e0 = __expf(acc[mt][nt][0]);
            float e1 = __expf(acc[mt][nt][1]);
            float e2 = __expf(acc[mt][nt][2]);
            float e3 = __expf(acc[mt][nt][3]);
            lpart[nt] += (e0 + e1) + (e2 + e3);
            int qq = nt * 16 + l15;
            int k0 = w * 64 + mt * 16 + 4 * g;
            *(unsigned long long*)&pls[qq * 272 + k0] = pk4(e0, e1, e2, e3);
        }
#pragma unroll
    for (int nt = 0; nt < 4; ++nt) {
        lpart[nt] += __shfl_xor(lpart[nt], 16);
        lpart[nt] += __shfl_xor(lpart[nt], 32);
    }
    if (g == 0)
#pragma unroll
        for (int nt = 0; nt < 4; ++nt) lred[w][nt][l15] = lpart[nt];
    __syncthreads();

    const unsigned short* vfb = vfT + (size_t)bh * 64 * 256;
    f32x4 oacc[4];
#pragma unroll
    for (int nt = 0; nt < 4; ++nt) oacc[nt] = (f32x4){0.f,0.f,0.f,0.f};

#pragma unroll
    for (int ks = 0; ks < 8; ++ks) {
        bf16x8 av = *(const bf16x8*)&vfb[(size_t)(w * 16 + l15) * 256 + ks * 32 + 8 * g];
#pragma unroll
        for (int nt = 0; nt < 4; ++nt) {
            bf16x8 bp = *(const bf16x8*)&pls[(nt * 16 + l15) * 272 + ks * 32 + 8 * g];
            oacc[nt] = __builtin_amdgcn_mfma_f32_16x16x32_bf16(av, bp, oacc[nt], 0, 0, 0);
        }
    }

#pragma unroll
    for (int nt = 0; nt < 4; ++nt) {
        float l = lred[0][nt][l15] + lred[1][nt][l15] + lred[2][nt][l15] + lred[3][nt][l15];
        float inv = 1.0f / l;
        int qq = nt * 16 + l15;
        int hc0 = w * 16 + 4 * g;
        *(unsigned long long*)(ob + (size_t)(n0 + qq) * kHID + nh * kHC + hc0) =
            pk4(oacc[nt][0] * inv, oacc[nt][1] * inv, oacc[nt][2] * inv, oacc[nt][3] * inv);
    }
}

// ---------------------------------------------------------------------------
// Depthwise 3x3 SAME conv, pixel-major; fp32 or bf16 input, bf16 out [n][192].
// ---------------------------------------------------------------------------
template<int INBF16>
__global__ void dwconv_pm_kernel(const void* __restrict__ in, unsigned short* __restrict__ out,
                                 const float* __restrict__ wt, const float* __restrict__ bias)
{
    int idx = blockIdx.x * 256 + threadIdx.x;      // kN*48
    int n = idx / 48;
    int c0 = (idx - n * 48) * 4;
    int hw = n & (kHW - 1);
    int h = hw >> 7, ww = hw & 127;
    f32x4 s = *(const f32x4*)(bias + c0);
#pragma unroll
    for (int dy = -1; dy <= 1; ++dy) {
        int hh = h + dy;
        if (hh < 0 || hh >= kH) continue;
#pragma unroll
        for (int dx = -1; dx <= 1; ++dx) {
            int wx = ww + dx;
            if (wx < 0 || wx >= kW) continue;
            f32x4 v;
            if (INBF16)
                v = ubf4(*(const unsigned long long*)((const unsigned short*)in
                          + (size_t)(n + dy * kW + dx) * kC + c0));
            else
                v = *(const f32x4*)((const float*)in + (size_t)(n + dy * kW + dx) * kC + c0);
            int t = (dy + 1) * 3 + (dx + 1);
            s[0] += v[0] * wt[(c0 + 0) * 9 + t];
            s[1] += v[1] * wt[(c0 + 1) * 9 + t];
            s[2] += v[2] * wt[(c0 + 2) * 9 + t];
            s[3] += v[3] * wt[(c0 + 3) * 9 + t];
        }
    }
    *(unsigned long long*)(out + (size_t)n * kC + c0) = pk4(s[0], s[1], s[2], s[3]);
}

// ---------------------------------------------------------------------------
// Instance-norm stats (bf16 input) via per-chunk atomics.
// ---------------------------------------------------------------------------
__global__ void istats_bf16_kernel(const unsigned short* __restrict__ in, float* __restrict__ acc)
{
    int n0 = blockIdx.x * 64;
    int b = n0 >> 14;
    int c = threadIdx.x;
    float s = 0.f, ss = 0.f;
    for (int p = 0; p < 64; ++p) {
        float v = bf2f(in[(size_t)(n0 + p) * kC + c]);
        s += v; ss += v * v;
    }
    atomicAdd(&acc[(size_t)(b * kC + c) * 2],     s);
    atomicAdd(&acc[(size_t)(b * kC + c) * 2 + 1], ss);
}

__device__ inline void inorm_ms(const float* acc, int b, int c, float& m, float& rs)
{
    float s  = acc[(size_t)(b * kC + c) * 2];
    float ss = acc[(size_t)(b * kC + c) * 2 + 1];
    m = s * (1.0f / kHW);
    float var = ss * (1.0f / kHW) - m * m;
    rs = rsqrtf(var + kEPS);
}

// MODE 0: gelu(inorm(in)) -> bf16.  MODE 1: gelu(inorm(in)) + add -> bf16.
template<int MODE>
__global__ void apply_pm_kernel(const unsigned short* __restrict__ in, const float* __restrict__ acc,
                                unsigned short* __restrict__ out, const unsigned short* __restrict__ addsrc)
{
    int idx = blockIdx.x * 256 + threadIdx.x;      // kN*48
    int n = idx / 48;
    int c0 = (idx - n * 48) * 4;
    int b = n >> 14;
    f32x4 v = ubf4(*(const unsigned long long*)(in + (size_t)n * kC + c0));
    f32x4 r;
#pragma unroll
    for (int j = 0; j < 4; ++j) {
        float m, rs;
        inorm_ms(acc, b, c0 + j, m, rs);
        float x = (v[j] - m) * rs;
        r[j] = 0.5f * x * (1.0f + erff(x * 0.70710678118654752f));
    }
    if (MODE == 1)
        r += ubf4(*(const unsigned long long*)(addsrc + (size_t)n * kC + c0));
    *(unsigned long long*)(out + (size_t)n * kC + c0) = pk4(r[0], r[1], r[2], r[3]);
}

// ---------------------------------------------------------------------------
// Final inorm via LDS transpose: bf16 pixel-major in -> NCHW fp32 d_out.
// Block = 64 pixels x 192 channels; coalesced reads AND writes.
// ---------------------------------------------------------------------------
__global__ __launch_bounds__(256) void final_kernel(const unsigned short* __restrict__ in,
                                                    const float* __restrict__ acc,
                                                    float* __restrict__ out)
{
    __shared__ unsigned short tile[192][68];
    int n0 = blockIdx.x * 64;
    int b = n0 >> 14;
    int hw0 = n0 & (kHW - 1);
    int tid = threadIdx.x;
    // read: 64 pixels x 192 ch, 8B per thread-iter (4 ch)
    for (int i = tid; i < 64 * 48; i += 256) {
        int p = i / 48, cq = i - p * 48;
        unsigned long long u = *(const unsigned long long*)(in + (size_t)(n0 + p) * kC + cq * 4);
        tile[cq * 4 + 0][p] = (unsigned short)u;
        tile[cq * 4 + 1][p] = (unsigned short)(u >> 16);
        tile[cq * 4 + 2][p] = (unsigned short)(u >> 32);
        tile[cq * 4 + 3][p] = (unsigned short)(u >> 48);
    }
    __syncthreads();
    // write: per channel, 64 consecutive hw as f32x4 chunks
    for (int i = tid; i < 192 * 16; i += 256) {
        int c = i >> 4, grp = i & 15;
        float m, rs;
        inorm_ms(acc, b, c, m, rs);
        f32x4 o;
#pragma unroll
        for (int j = 0; j < 4; ++j)
            o[j] = (bf2f(tile[c][grp * 4 + j]) - m) * rs;
        *(f32x4*)(out + (size_t)(b * kC + c) * kHW + hw0 + grp * 4) = o;
    }
}

// ---------------------------------------------------------------------------
extern "C" void kernel_launch(void* const* d_in, const int* in_sizes, int n_in,
                              void* d_out, int out_size, void* d_ws, size_t ws_size,
                              hipStream_t stream)
{
    const float* x     = (const float*)d_in[0];
    const float* ln1_g = (const float*)d_in[1];
    const float* ln1_b = (const float*)d_in[2];
    const float* wq    = (const float*)d_in[3];
    const float* wk    = (const float*)d_in[4];
    const float* wv    = (const float*)d_in[5];
    const float* wo    = (const float*)d_in[6];
    const float* bo    = (const float*)d_in[7];
    const float* dw_w  = (const float*)d_in[8];
    const float* dw_b  = (const float*)d_in[9];
    const float* mlp_w = (const float*)d_in[10];
    const float* mlp_b = (const float*)d_in[11];
    const float* ln2_g = (const float*)d_in[12];
    const float* ln2_b = (const float*)d_in[13];
    const float* c1_w  = (const float*)d_in[14];
    const float* c1_b  = (const float*)d_in[15];
    const float* res_w = (const float*)d_in[16];
    const float* res_b = (const float*)d_in[17];
    const float* c2_w  = (const float*)d_in[18];
    const float* c2_b  = (const float*)d_in[19];

    char* base = (char*)d_ws;
    float* XP = (float*)(base);                                  // fp32 [n][192] raw x
    unsigned short* XNb = (unsigned short*)(base + 25165824);    // bf16 [n][192] xn / Y1
    unsigned short* QPb = (unsigned short*)(base + 37748736);    // bf16 [n][512]; later F / T2
    unsigned short* F   = QPb;
    unsigned short* T2  = QPb;
    unsigned short* KPb = (unsigned short*)(base + 71303168);    // bf16 [n][512]; OB alias; later Y2
    unsigned short* OB  = KPb;
    unsigned short* Y2  = KPb;
    unsigned short* LB  = (unsigned short*)(base + 104857600);   // bf16 [n][192] local; later Y3
    unsigned short* Y3  = LB;
    unsigned short* T1  = (unsigned short*)(base + 117440512);   // bf16 [n][192]; later R
    unsigned short* R   = T1;
    char* sm = base + 130023424;
    float* qpart  = (float*)(sm);                 sm += 524288;   // [16][128][64]
    float* ksum_h = (float*)(sm);                 sm += 524288;
    float* ksum_w = (float*)(sm);                 sm += 524288;
    float* acc0   = (float*)(sm);                 sm += 3072;
    float* acc1   = (float*)(sm);                 sm += 3072;
    float* acc2   = (float*)(sm);                 sm += 3072;
    unsigned short* kf   = (unsigned short*)(sm); sm += 524288;
    unsigned short* vfT  = (unsigned short*)(sm); sm += 524288;
    unsigned short* wqb  = (unsigned short*)(sm); sm += 196608;
    unsigned short* wkb  = (unsigned short*)(sm); sm += 196608;
    unsigned short* mlpb1= (unsigned short*)(sm); sm += 73728;
    unsigned short* c1b  = (unsigned short*)(sm); sm += 73728;
    unsigned short* c2b  = (unsigned short*)(sm); sm += 73728;
    unsigned short* w2pb = (unsigned short*)(sm); sm += 196608;
    float* bp2 = (float*)(sm);                    sm += 1024;
    int* hidx = (int*)(sm);                       sm += 1024;
    int* widx = (int*)(sm);

    // --- prep ---
    prep_kernel<<<1209, 256, 0, stream>>>(acc0, wq, wk, mlp_w, c1_w, c2_w,
                                          wqb, wkb, mlpb1, c1b, c2b);
    wfuse_kernel<<<384, 256, 0, stream>>>(mlp_w, wo, mlp_b, bo, w2pb, bp2);
    txln_kernel<<<dim3(kHW / 64, kB), 256, 0, stream>>>(x, XP, XNb, ln1_g, ln1_b);

    // --- attention branch ---
    mgemm_l2_kernel<<<dim3(kN / 128, kNH), 256, 0, stream>>>(wqb, XNb, QPb, qpart);
    mgemm_l2_kernel<<<dim3(kN / 128, kNH), 256, 0, stream>>>(wkb, XNb, KPb, ksum_h);
    sum_h_kernel<<<dim3(kW, 16), 64, 0, stream>>>(KPb, ksum_w);
    score_topk_kernel<<<16, 128, 0, stream>>>(qpart, ksum_h, ksum_w, hidx, widx);
    gather_kv_kernel<<<dim3(kP, 16), 256, 0, stream>>>(KPb, XNb, wv, hidx, widx, kf, vfT);
    attn_kernel<<<dim3(kHW / 64, 16), 256, 0, stream>>>(QPb, OB, kf, vfT);

    // --- local branch + fused mlp (wo folded in) ---
    dwconv_pm_kernel<0><<<(kN * 48) / 256, 256, 0, stream>>>(XP, LB, dw_w, dw_b);
    mgemm_mlp_kernel<<<dim3(kN / 128, kC / 64), 256, 0, stream>>>(mlpb1, LB, w2pb, OB, F, bp2, XP);

    // --- tail ---
    ln_pm_bf16_kernel<<<kN / 256, 256, 0, stream>>>(F, XNb, ln2_g, ln2_b);     // Y1 = XNb
    mgemm_is_kernel<<<dim3(kN / 128, kC / 64), 256, 0, stream>>>(c1b, XNb, T1, c1_b, acc0);
    apply_pm_kernel<0><<<(kN * 48) / 256, 256, 0, stream>>>(T1, acc0, Y2, nullptr);
    dwconv_pm_kernel<1><<<(kN * 48) / 256, 256, 0, stream>>>(Y2, R, res_w, res_b);
    istats_bf16_kernel<<<kN / 64, 192, 0, stream>>>(R, acc1);
    apply_pm_kernel<1><<<(kN * 48) / 256, 256, 0, stream>>>(R, acc1, Y3, Y2);
    mgemm_is_kernel<<<dim3(kN / 128, kC / 64), 256, 0, stream>>>(c2b, Y3, T2, c2_b, acc2);
    final_kernel<<<kN / 64, 256, 0, stream>>>(T2, acc2, (float*)d_out);
}

// Round 8
// 490.009 us; speedup vs baseline: 4.1375x; 1.0147x over previous
//
#include <hip/hip_runtime.h>
#include <math.h>

constexpr int kC   = 192;
constexpr int kNH  = 8;
constexpr int kHC  = 64;
constexpr int kHID = 512;
constexpr int kP   = 16;
constexpr int kB   = 2;
constexpr int kH   = 128;
constexpr int kW   = 128;
constexpr int kHW  = kH * kW;      // 16384
constexpr int kN   = kB * kHW;     // 32768
constexpr float kEPS = 1e-5f;

typedef __attribute__((ext_vector_type(8))) short bf16x8;
typedef __attribute__((ext_vector_type(4))) float f32x4;

__device__ inline unsigned short f2bf(float f) {
    unsigned int u = __builtin_bit_cast(unsigned int, f);
    unsigned int r = (u + 0x7FFFu + ((u >> 16) & 1u)) >> 16;   // RNE
    return (unsigned short)r;
}
__device__ inline float bf2f(unsigned short u) {
    return __builtin_bit_cast(float, (unsigned int)u << 16);
}
__device__ inline unsigned int cvtpk(float lo, float hi) {
    unsigned int r;
    asm("v_cvt_pk_bf16_f32 %0, %1, %2" : "=v"(r) : "v"(lo), "v"(hi));
    return r;
}
__device__ inline unsigned long long pk4(float a, float b, float c, float d) {
    return (unsigned long long)cvtpk(a, b) | ((unsigned long long)cvtpk(c, d) << 32);
}
__device__ inline f32x4 ubf4(unsigned long long u) {
    f32x4 r;
    r[0] = bf2f((unsigned short)u);
    r[1] = bf2f((unsigned short)(u >> 16));
    r[2] = bf2f((unsigned short)(u >> 32));
    r[3] = bf2f((unsigned short)(u >> 48));
    return r;
}

// ---------------------------------------------------------------------------
// Prep: zero istats accumulators + bf16 weight conversions.
// ---------------------------------------------------------------------------
__global__ void prep_kernel(float* __restrict__ acc,
                            const float* wq, const float* wk, const float* wm,
                            const float* c1, const float* c2,
                            unsigned short* wqb, unsigned short* wkb,
                            unsigned short* mlpb1, unsigned short* c1b, unsigned short* c2b)
{
    int i = blockIdx.x * 256 + threadIdx.x;
    if (i < 2304) { acc[i] = 0.f; return; }
    i -= 2304;
    if (i < 98304) { wqb[i] = f2bf(wq[i]); return; }
    i -= 98304;
    if (i < 98304) { wkb[i] = f2bf(wk[i]); return; }
    i -= 98304;
    if (i < 36864) { int o = i / 192, k = i - o * 192; mlpb1[i] = f2bf(wm[o * 384 + k]); return; }
    i -= 36864;
    if (i < 36864) { c1b[i] = f2bf(c1[i]); return; }
    i -= 36864;
    if (i < 36864) { c2b[i] = f2bf(c2[i]); return; }
}

// ---------------------------------------------------------------------------
// Fused weight: W2'[o][j] = sum_c mlp_w[o][192+c]*wo[c][j]  (bf16 out)
// ---------------------------------------------------------------------------
__global__ void wfuse_kernel(const float* __restrict__ mlp_w, const float* __restrict__ wo,
                             const float* __restrict__ mlp_b, const float* __restrict__ bo,
                             unsigned short* __restrict__ w2pb, float* __restrict__ bp2)
{
    int i = blockIdx.x * 256 + threadIdx.x;   // 98304
    int o = i >> 9, j = i & 511;
    const float* a = mlp_w + o * 384 + 192;
    float s = 0.f;
    for (int c = 0; c < 192; ++c) s += a[c] * wo[c * 512 + j];
    w2pb[o * 512 + j] = f2bf(s);
    if (j == 0) {
        float t = mlp_b[o];
        for (int c = 0; c < 192; ++c) t += a[c] * bo[c];
        bp2[o] = t;
    }
}

// ---------------------------------------------------------------------------
// Fused transpose + ln1: x NCHW fp32 -> XPb raw bf16 [n][192] + XNb bf16 [n][192]
// ---------------------------------------------------------------------------
__global__ __launch_bounds__(256) void txln_kernel(const float* __restrict__ x,
                                                   unsigned short* __restrict__ xpb,
                                                   unsigned short* __restrict__ xnb,
                                                   const float* __restrict__ g,
                                                   const float* __restrict__ bb)
{
    __shared__ float tile[192][65];
    __shared__ float red[2][4][64];
    __shared__ float pms[64], prs[64];
    int hw0 = blockIdx.x * 64;
    int b   = blockIdx.y;
    int tid = threadIdx.x;
    for (int i = tid; i < 192 * 64; i += 256) {
        int c = i >> 6, p = i & 63;
        tile[c][p] = x[(size_t)(b * kC + c) * kHW + hw0 + p];
    }
    __syncthreads();
    {
        int p = tid & 63, qt = tid >> 6;
        float s = 0.f, ss = 0.f;
        for (int c = qt * 48; c < qt * 48 + 48; ++c) {
            float v = tile[c][p]; s += v; ss += v * v;
        }
        red[0][qt][p] = s; red[1][qt][p] = ss;
    }
    __syncthreads();
    if (tid < 64) {
        float s  = red[0][0][tid] + red[0][1][tid] + red[0][2][tid] + red[0][3][tid];
        float ss = red[1][0][tid] + red[1][1][tid] + red[1][2][tid] + red[1][3][tid];
        float m = s * (1.0f / kC);
        float var = ss * (1.0f / kC) - m * m;
        pms[tid] = m;
        prs[tid] = rsqrtf(var + kEPS);
    }
    __syncthreads();
    for (int i = tid; i < 64 * 192; i += 256) {
        int p = i / 192, c = i - p * 192;
        float raw = tile[c][p];
        size_t oi = (size_t)(b * kHW + hw0 + p) * kC + c;
        xpb[oi] = f2bf(raw);
        xnb[oi] = f2bf((raw - pms[p]) * prs[p] * g[c] + bb[c]);
    }
}

// ---------------------------------------------------------------------------
// LayerNorm (ln2), bf16 -> bf16, 4 threads per pixel (48 ch each, shfl reduce).
// ---------------------------------------------------------------------------
__global__ void ln_pm_bf16_kernel(const unsigned short* __restrict__ in,
                                  unsigned short* __restrict__ out,
                                  const float* __restrict__ g, const float* __restrict__ bb)
{
    int t = blockIdx.x * 256 + threadIdx.x;     // kN*4
    int n = t >> 2, q = t & 3;
    const unsigned long long* ip = (const unsigned long long*)(in + (size_t)n * kC) + q * 12;
    f32x4 v[12];
    float s = 0.f, ss = 0.f;
#pragma unroll
    for (int r = 0; r < 12; ++r) {
        v[r] = ubf4(ip[r]);
        s  += (v[r][0] + v[r][1]) + (v[r][2] + v[r][3]);
        ss += (v[r][0]*v[r][0] + v[r][1]*v[r][1]) + (v[r][2]*v[r][2] + v[r][3]*v[r][3]);
    }
    s  += __shfl_xor(s, 1);  s  += __shfl_xor(s, 2);
    ss += __shfl_xor(ss, 1); ss += __shfl_xor(ss, 2);
    float m  = s * (1.0f / kC);
    float var = ss * (1.0f / kC) - m * m;
    float rs = rsqrtf(var + kEPS);
    unsigned long long* op = (unsigned long long*)(out + (size_t)n * kC) + q * 12;
#pragma unroll
    for (int r = 0; r < 12; ++r) {
        f32x4 gg = *(const f32x4*)(g + q * 48 + r * 4);
        f32x4 bv = *(const f32x4*)(bb + q * 48 + r * 4);
        op[r] = pk4((v[r][0]-m)*rs*gg[0] + bv[0], (v[r][1]-m)*rs*gg[1] + bv[1],
                    (v[r][2]-m)*rs*gg[2] + bv[2], (v[r][3]-m)*rs*gg[3] + bv[3]);
    }
}

#define MGEMM_CORE(KVAL, APTR, BPTR)                                              \
    {                                                                             \
        const unsigned short* Ap = APTR;                                          \
        const unsigned short* Bp = BPTR;                                          \
        _Pragma("unroll 2")                                                       \
        for (int k = 0; k < KVAL; k += 32) {                                      \
            bf16x8 a0 = *(const bf16x8*)(Ap + k);                                 \
            bf16x8 a1 = *(const bf16x8*)(Ap + (size_t)16 * KVAL + k);             \
            bf16x8 b0 = *(const bf16x8*)(Bp + k);                                 \
            bf16x8 b1 = *(const bf16x8*)(Bp + (size_t)16 * KVAL + k);             \
            bf16x8 b2 = *(const bf16x8*)(Bp + (size_t)32 * KVAL + k);             \
            bf16x8 b3 = *(const bf16x8*)(Bp + (size_t)48 * KVAL + k);             \
            acc[0][0] = __builtin_amdgcn_mfma_f32_16x16x32_bf16(a0, b0, acc[0][0], 0, 0, 0); \
            acc[0][1] = __builtin_amdgcn_mfma_f32_16x16x32_bf16(a0, b1, acc[0][1], 0, 0, 0); \
            acc[0][2] = __builtin_amdgcn_mfma_f32_16x16x32_bf16(a0, b2, acc[0][2], 0, 0, 0); \
            acc[0][3] = __builtin_amdgcn_mfma_f32_16x16x32_bf16(a0, b3, acc[0][3], 0, 0, 0); \
            acc[1][0] = __builtin_amdgcn_mfma_f32_16x16x32_bf16(a1, b0, acc[1][0], 0, 0, 0); \
            acc[1][1] = __builtin_amdgcn_mfma_f32_16x16x32_bf16(a1, b1, acc[1][1], 0, 0, 0); \
            acc[1][2] = __builtin_amdgcn_mfma_f32_16x16x32_bf16(a1, b2, acc[1][2], 0, 0, 0); \
            acc[1][3] = __builtin_amdgcn_mfma_f32_16x16x32_bf16(a1, b3, acc[1][3], 0, 0, 0); \
        }                                                                         \
    }

// ---------------------------------------------------------------------------
// c1/c2 GEMM: bf16 out [n][192] + bias + fused instance-norm partial stats.
// ---------------------------------------------------------------------------
__global__ __launch_bounds__(256) void mgemm_is_kernel(
    const unsigned short* __restrict__ A, const unsigned short* __restrict__ B,
    unsigned short* __restrict__ out, const float* __restrict__ bias,
    float* __restrict__ accp)
{
    __shared__ float sa[2][64], qa[2][64];
    int nB = blockIdx.x * 128, oB = blockIdx.y * 64;
    int w = threadIdx.x >> 6, lane = threadIdx.x & 63;
    int l15 = lane & 15, g = lane >> 4;
    int wm = w & 1, wn = w >> 1;

    f32x4 acc[2][4];
#pragma unroll
    for (int mt = 0; mt < 2; ++mt)
#pragma unroll
        for (int nt = 0; nt < 4; ++nt) acc[mt][nt] = (f32x4){0.f,0.f,0.f,0.f};

    MGEMM_CORE(192, A + (size_t)(oB + wm * 32 + l15) * 192 + 8 * g,
                    B + (size_t)(nB + wn * 64 + l15) * 192 + 8 * g);

    f32x4 vv[2][4];
#pragma unroll
    for (int mt = 0; mt < 2; ++mt)
#pragma unroll
        for (int nt = 0; nt < 4; ++nt) {
            int o = oB + wm * 32 + mt * 16 + 4 * g;
            int n = nB + wn * 64 + nt * 16 + l15;
            f32x4 v = acc[mt][nt] + *(const f32x4*)(bias + o);
            vv[mt][nt] = v;
            *(unsigned long long*)(out + (size_t)n * kC + o) = pk4(v[0], v[1], v[2], v[3]);
        }
    float s2[2][4] = {}, q2[2][4] = {};
#pragma unroll
    for (int mt = 0; mt < 2; ++mt)
#pragma unroll
        for (int nt = 0; nt < 4; ++nt)
#pragma unroll
            for (int r = 0; r < 4; ++r) {
                float v = vv[mt][nt][r];
                s2[mt][r] += v; q2[mt][r] += v * v;
            }
#pragma unroll
    for (int off = 1; off < 16; off <<= 1)
#pragma unroll
        for (int mt = 0; mt < 2; ++mt)
#pragma unroll
            for (int r = 0; r < 4; ++r) {
                s2[mt][r] += __shfl_xor(s2[mt][r], off);
                q2[mt][r] += __shfl_xor(q2[mt][r], off);
            }
    if (l15 == 0)
#pragma unroll
        for (int mt = 0; mt < 2; ++mt)
#pragma unroll
            for (int r = 0; r < 4; ++r) {
                int ol = wm * 32 + mt * 16 + 4 * g + r;
                sa[wn][ol] = s2[mt][r];
                qa[wn][ol] = q2[mt][r];
            }
    __syncthreads();
    if (threadIdx.x < 128) {
        int ol = threadIdx.x & 63, st = threadIdx.x >> 6;
        float v = st ? (qa[0][ol] + qa[1][ol]) : (sa[0][ol] + sa[1][ol]);
        int b = nB >> 14;
        atomicAdd(&accp[(size_t)(b * kC + oB + ol) * 2 + st], v);
    }
}

// ---------------------------------------------------------------------------
// Fused MLP: F = mlp_w1@LB + W2'@OB + bp2 + x(bf16)   (bf16 out [n][192])
// ---------------------------------------------------------------------------
__global__ __launch_bounds__(256) void mgemm_mlp_kernel(
    const unsigned short* __restrict__ A1, const unsigned short* __restrict__ B1,
    const unsigned short* __restrict__ A2, const unsigned short* __restrict__ B2,
    unsigned short* __restrict__ out, const float* __restrict__ bp2,
    const unsigned short* __restrict__ res)
{
    int nB = blockIdx.x * 128, oB = blockIdx.y * 64;
    int w = threadIdx.x >> 6, lane = threadIdx.x & 63;
    int l15 = lane & 15, g = lane >> 4;
    int wm = w & 1, wn = w >> 1;

    f32x4 acc[2][4];
#pragma unroll
    for (int mt = 0; mt < 2; ++mt)
#pragma unroll
        for (int nt = 0; nt < 4; ++nt) acc[mt][nt] = (f32x4){0.f,0.f,0.f,0.f};

    MGEMM_CORE(192, A1 + (size_t)(oB + wm * 32 + l15) * 192 + 8 * g,
                    B1 + (size_t)(nB + wn * 64 + l15) * 192 + 8 * g);
    MGEMM_CORE(512, A2 + (size_t)(oB + wm * 32 + l15) * 512 + 8 * g,
                    B2 + (size_t)(nB + wn * 64 + l15) * 512 + 8 * g);

#pragma unroll
    for (int mt = 0; mt < 2; ++mt)
#pragma unroll
        for (int nt = 0; nt < 4; ++nt) {
            int o = oB + wm * 32 + mt * 16 + 4 * g;
            int n = nB + wn * 64 + nt * 16 + l15;
            f32x4 v = acc[mt][nt];
            v[0] += bp2[o]; v[1] += bp2[o+1]; v[2] += bp2[o+2]; v[3] += bp2[o+3];
            v += ubf4(*(const unsigned long long*)(res + (size_t)n * kC + o));
            *(unsigned long long*)(out + (size_t)n * kC + o) = pk4(v[0], v[1], v[2], v[3]);
        }
}

// ---------------------------------------------------------------------------
// q/k projection GEMM + fused per-head L2 norm + fused row-sum reduction.
// ---------------------------------------------------------------------------
__global__ __launch_bounds__(256) void mgemm_l2_kernel(
    const unsigned short* __restrict__ A, const unsigned short* __restrict__ B,
    unsigned short* __restrict__ out, float* __restrict__ red_out)
{
    __shared__ float ssq[2][2][4][16];
    __shared__ float rbuf[2][2][4][2][4];
    int nB = blockIdx.x * 128, oB = blockIdx.y * 64;
    int w = threadIdx.x >> 6, lane = threadIdx.x & 63;
    int l15 = lane & 15, g = lane >> 4;
    int wm = w & 1, wn = w >> 1;

    f32x4 acc[2][4];
#pragma unroll
    for (int mt = 0; mt < 2; ++mt)
#pragma unroll
        for (int nt = 0; nt < 4; ++nt) acc[mt][nt] = (f32x4){0.f,0.f,0.f,0.f};

    MGEMM_CORE(192, A + (size_t)(oB + wm * 32 + l15) * 192 + 8 * g,
                    B + (size_t)(nB + wn * 64 + l15) * 192 + 8 * g);

#pragma unroll
    for (int nt = 0; nt < 4; ++nt) {
        float s = 0.f;
#pragma unroll
        for (int mt = 0; mt < 2; ++mt) {
            f32x4 a = acc[mt][nt];
            s += (a[0]*a[0] + a[1]*a[1]) + (a[2]*a[2] + a[3]*a[3]);
        }
        s += __shfl_xor(s, 16);
        s += __shfl_xor(s, 32);
        if (g == 0) ssq[wm][wn][nt][l15] = s;
    }
    __syncthreads();

    float sc[4];
#pragma unroll
    for (int nt = 0; nt < 4; ++nt) {
        float ss2 = ssq[0][wn][nt][l15] + ssq[1][wn][nt][l15];
        sc[nt] = 1.0f / fmaxf(sqrtf(ss2), 1e-12f);
    }

#pragma unroll
    for (int nt = 0; nt < 4; ++nt) {
        int n = nB + wn * 64 + nt * 16 + l15;
#pragma unroll
        for (int mt = 0; mt < 2; ++mt) {
            int o = oB + wm * 32 + mt * 16 + 4 * g;
            f32x4 v = acc[mt][nt];
            *(unsigned long long*)(out + (size_t)n * kHID + o) =
                pk4(v[0]*sc[nt], v[1]*sc[nt], v[2]*sc[nt], v[3]*sc[nt]);
        }
    }

    float sred[2][4] = {};
#pragma unroll
    for (int nt = 0; nt < 4; ++nt)
#pragma unroll
        for (int mt = 0; mt < 2; ++mt) {
            f32x4 a = acc[mt][nt];
            sred[mt][0] += a[0] * sc[nt];
            sred[mt][1] += a[1] * sc[nt];
            sred[mt][2] += a[2] * sc[nt];
            sred[mt][3] += a[3] * sc[nt];
        }
#pragma unroll
    for (int off = 1; off < 16; off <<= 1)
#pragma unroll
        for (int mt = 0; mt < 2; ++mt)
#pragma unroll
            for (int r = 0; r < 4; ++r)
                sred[mt][r] += __shfl_xor(sred[mt][r], off);
    if (l15 == 0)
#pragma unroll
        for (int mt = 0; mt < 2; ++mt)
#pragma unroll
            for (int r = 0; r < 4; ++r)
                rbuf[wm][wn][g][mt][r] = sred[mt][r];
    __syncthreads();
    if (threadIdx.x < 64) {
        int o = threadIdx.x;
        int wm2 = o >> 5, mt2 = (o >> 4) & 1, g2 = (o >> 2) & 3, r2 = o & 3;
        float v = rbuf[wm2][0][g2][mt2][r2] + rbuf[wm2][1][g2][mt2][r2];
        int row = (nB & (kHW - 1)) >> 7;
        int b = nB >> 14;
        int bh = b * 8 + blockIdx.y;
        red_out[((size_t)(bh * 128 + row)) * 64 + o] = v;
    }
}

// ksum_w[bh][w][hc] = sum_h k.  256 threads: 4 h-segments of 32 + LDS reduce.
__global__ void sum_h_kernel(const unsigned short* __restrict__ buf, float* __restrict__ out)
{
    __shared__ float red[4][64];
    int w = blockIdx.x, bh = blockIdx.y;
    int hc = threadIdx.x & 63, seg = threadIdx.x >> 6;
    int b = bh >> 3, nh = bh & 7;
    const unsigned short* p = buf + (size_t)(b * kHW + seg * 32 * kW + w) * kHID + nh * kHC + hc;
    float s = 0.f;
    for (int h = 0; h < 32; ++h) s += bf2f(p[(size_t)h * kW * kHID]);
    red[seg][hc] = s;
    __syncthreads();
    if (threadIdx.x < 64)
        out[((size_t)bh * kW + w) * kHC + threadIdx.x] =
            red[0][threadIdx.x] + red[1][threadIdx.x] + red[2][threadIdx.x] + red[3][threadIdx.x];
}

// ---------------------------------------------------------------------------
// Fused qs-reduce + scores + top-16 (tie -> lower index).
// ---------------------------------------------------------------------------
__global__ void score_topk_kernel(const float* __restrict__ qpart,
                                  const float* __restrict__ ksum_h,
                                  const float* __restrict__ ksum_w,
                                  int* __restrict__ hidx, int* __restrict__ widx)
{
    __shared__ float qsl[2][64];
    __shared__ float hs[128], ws[128];
    int bh = blockIdx.x;
    int tid = threadIdx.x;               // 128
    int hc = tid & 63, grp = tid >> 6;
    {
        const float* qp = qpart + ((size_t)bh * 128 + grp * 64) * 64 + hc;
        float s = 0.f;
        for (int i = 0; i < 64; ++i) s += qp[(size_t)i * 64];
        qsl[grp][hc] = s;
    }
    __syncthreads();
    if (tid < 64) qsl[0][tid] += qsl[1][tid];
    __syncthreads();
    {
        const float* kh = ksum_h + ((size_t)bh * 128 + tid) * 64;
        const float* kw = ksum_w + ((size_t)bh * 128 + tid) * 64;
        float sh = 0.f, sw = 0.f;
        for (int c = 0; c < 64; ++c) {
            float q = qsl[0][c];
            sh += q * kh[c];
            sw += q * kw[c];
        }
        hs[tid] = sh; ws[tid] = sw;
    }
    __syncthreads();
    int sel = tid >> 6;
    const float* sc = sel ? ws : hs;
    int* out = (sel ? widx : hidx) + bh * kP;
    int lane = tid & 63;
    float v0 = sc[lane], v1 = sc[lane + 64];
    int i0 = lane, i1 = lane + 64;
    for (int p = 0; p < kP; ++p) {
        float bv; int bi;
        if (v1 > v0) { bv = v1; bi = i1; } else { bv = v0; bi = i0; }
#pragma unroll
        for (int off = 1; off < 64; off <<= 1) {
            float ov = __shfl_xor(bv, off);
            int   oi = __shfl_xor(bi, off);
            if (ov > bv || (ov == bv && oi < bi)) { bv = ov; bi = oi; }
        }
        if (lane == 0) out[p] = bi;
        if (i0 == bi) v0 = -INFINITY;
        if (i1 == bi) v1 = -INFINITY;
    }
}

// ---------------------------------------------------------------------------
// Gather kf; lazy-project vfT.
// ---------------------------------------------------------------------------
__global__ void gather_kv_kernel(const unsigned short* __restrict__ kpb,
                                 const unsigned short* __restrict__ xnb,
                                 const float* __restrict__ wv,
                                 const int* __restrict__ hidx, const int* __restrict__ widx,
                                 unsigned short* __restrict__ kf, unsigned short* __restrict__ vfT)
{
    int bh = blockIdx.y, p1 = blockIdx.x;
    int b = bh >> 3, nh = bh & 7;
    int hc = threadIdx.x & 63, pg = threadIdx.x >> 6;
    int hrow = hidx[bh * kP + p1];
    int o = nh * kHC + hc;
    const float* wvp = wv + (size_t)o * kC;
    for (int p2 = pg; p2 < kP; p2 += 4) {
        int wcol = widx[bh * kP + p2];
        int n = b * kHW + hrow * kW + wcol;
        int kidx = p1 * kP + p2;
        kf[((size_t)bh * 256 + kidx) * 64 + hc] = kpb[(size_t)n * kHID + nh * kHC + hc];
        const unsigned int* xr = (const unsigned int*)(xnb + (size_t)n * kC);
        float s = 0.f;
        for (int c2 = 0; c2 < kC / 2; ++c2) {
            unsigned int u = xr[c2];
            s += wvp[c2 * 2]     * bf2f((unsigned short)(u & 0xffff));
            s += wvp[c2 * 2 + 1] * bf2f((unsigned short)(u >> 16));
        }
        vfT[((size_t)bh * 64 + hc) * 256 + kidx] = f2bf(s);
    }
}

// ---------------------------------------------------------------------------
// MFMA attention. P in LDS: stride 256 shorts + XOR swizzle
// kx = k0 ^ ((qq&7)<<3) -> provably conflict-free 8B writes and 16B reads.
// ---------------------------------------------------------------------------
__global__ __launch_bounds__(256) void attn_kernel(
    const unsigned short* __restrict__ qpb, unsigned short* __restrict__ ob,
    const unsigned short* __restrict__ kf, const unsigned short* __restrict__ vfT)
{
    __shared__ unsigned short pls[64 * 256];
    __shared__ float lred[4][4][16];

    int bh = blockIdx.y; int b = bh >> 3, nh = bh & 7;
    int n0 = b * kHW + blockIdx.x * 64;
    int tid = threadIdx.x;
    int w = tid >> 6, lane = tid & 63, l15 = lane & 15, g = lane >> 4;

    bf16x8 bq[4][2];
#pragma unroll
    for (int nt = 0; nt < 4; ++nt)
#pragma unroll
        for (int kt = 0; kt < 2; ++kt)
            bq[nt][kt] = *(const bf16x8*)(qpb + (size_t)(n0 + nt * 16 + l15) * kHID
                                          + nh * kHC + kt * 32 + 8 * g);

    const unsigned short* kfb = kf + (size_t)bh * 256 * 64;
    bf16x8 ak[4][2];
#pragma unroll
    for (int mt = 0; mt < 4; ++mt)
#pragma unroll
        for (int kt = 0; kt < 2; ++kt)
            ak[mt][kt] = *(const bf16x8*)&kfb[(size_t)(w * 64 + mt * 16 + l15) * 64 + kt * 32 + 8 * g];

    f32x4 acc[4][4];
#pragma unroll
    for (int mt = 0; mt < 4; ++mt)
#pragma unroll
        for (int nt = 0; nt < 4; ++nt) acc[mt][nt] = (f32x4){0.f,0.f,0.f,0.f};

#pragma unroll
    for (int kt = 0; kt < 2; ++kt)
#pragma unroll
        for (int mt = 0; mt < 4; ++mt)
#pragma unroll
            for (int nt = 0; nt < 4; ++nt)
                acc[mt][nt] = __builtin_amdgcn_mfma_f32_16x16x32_bf16(
                    ak[mt][kt], bq[nt][kt], acc[mt][nt], 0, 0, 0);

    float lpart[4] = {0.f, 0.f, 0.f, 0.f};
#pragma unroll
    for (int mt = 0; mt < 4; ++mt)
#pragma unroll
        for (int nt = 0; nt < 4; ++nt) {
            float e0 = __expf(acc[mt][nt][0]);
            float e1 = __expf(acc[mt][nt][1]);
            float e2 = __expf(acc[mt][nt][2]);
            float e3 = __expf(acc[mt][nt][3]);
            lpart[nt] += (e0 + e1) + (e2 + e3);
            int qq = nt * 16 + l15;
            int k0 = w * 64 + mt * 16 + 4 * g;
            int kx = k0 ^ ((qq & 7) << 3);
            *(unsigned long long*)&pls[qq * 256 + kx] = pk4(e0, e1, e2, e3);
        }
#pragma unroll
    for (int nt = 0; nt < 4; ++nt) {
        lpart[nt] += __shfl_xor(lpart[nt], 16);
        lpart[nt] += __shfl_xor(lpart[nt], 32);
    }
    if (g == 0)
#pragma unroll
        for (int nt = 0; nt < 4; ++nt) lred[w][nt][l15] = lpart[nt];
    __syncthreads();

    const unsigned short* vfb = vfT + (size_t)bh * 64 * 256;
    f32x4 oacc[4];
#pragma unroll
    for (int nt = 0; nt < 4; ++nt) oacc[nt] = (f32x4){0.f,0.f,0.f,0.f};

#pragma unroll
    for (int ks = 0; ks < 8; ++ks) {
        bf16x8 av = *(const bf16x8*)&vfb[(size_t)(w * 16 + l15) * 256 + ks * 32 + 8 * g];
#pragma unroll
        for (int nt = 0; nt < 4; ++nt) {
            int qq = nt * 16 + l15;
            int kx = (ks * 32 + 8 * g) ^ ((qq & 7) << 3);
            bf16x8 bp = *(const bf16x8*)&pls[qq * 256 + kx];
            oacc[nt] = __builtin_amdgcn_mfma_f32_16x16x32_bf16(av, bp, oacc[nt], 0, 0, 0);
        }
    }

#pragma unroll
    for (int nt = 0; nt < 4; ++nt) {
        float l = lred[0][nt][l15] + lred[1][nt][l15] + lred[2][nt][l15] + lred[3][nt][l15];
        float inv = 1.0f / l;
        int qq = nt * 16 + l15;
        int hc0 = w * 16 + 4 * g;
        *(unsigned long long*)(ob + (size_t)(n0 + qq) * kHID + nh * kHC + hc0) =
            pk4(oacc[nt][0] * inv, oacc[nt][1] * inv, oacc[nt][2] * inv, oacc[nt][3] * inv);
    }
}

// ---------------------------------------------------------------------------
// Depthwise 3x3 SAME conv, pixel-major bf16 in, bf16 out [n][192].
// ---------------------------------------------------------------------------
__global__ void dwconv_pm_kernel(const unsigned short* __restrict__ in,
                                 unsigned short* __restrict__ out,
                                 const float* __restrict__ wt, const float* __restrict__ bias)
{
    int idx = blockIdx.x * 256 + threadIdx.x;      // kN*48
    int n = idx / 48;
    int c0 = (idx - n * 48) * 4;
    int hw = n & (kHW - 1);
    int h = hw >> 7, ww = hw & 127;
    f32x4 s = *(const f32x4*)(bias + c0);
#pragma unroll
    for (int dy = -1; dy <= 1; ++dy) {
        int hh = h + dy;
        if (hh < 0 || hh >= kH) continue;
#pragma unroll
        for (int dx = -1; dx <= 1; ++dx) {
            int wx = ww + dx;
            if (wx < 0 || wx >= kW) continue;
            f32x4 v = ubf4(*(const unsigned long long*)(in + (size_t)(n + dy * kW + dx) * kC + c0));
            int t = (dy + 1) * 3 + (dx + 1);
            s[0] += v[0] * wt[(c0 + 0) * 9 + t];
            s[1] += v[1] * wt[(c0 + 1) * 9 + t];
            s[2] += v[2] * wt[(c0 + 2) * 9 + t];
            s[3] += v[3] * wt[(c0 + 3) * 9 + t];
        }
    }
    *(unsigned long long*)(out + (size_t)n * kC + c0) = pk4(s[0], s[1], s[2], s[3]);
}

// ---------------------------------------------------------------------------
// Instance-norm stats (bf16 input) via per-chunk atomics.
// ---------------------------------------------------------------------------
__global__ void istats_bf16_kernel(const unsigned short* __restrict__ in, float* __restrict__ acc)
{
    int n0 = blockIdx.x * 64;
    int b = n0 >> 14;
    int c = threadIdx.x;
    float s = 0.f, ss = 0.f;
    for (int p = 0; p < 64; ++p) {
        float v = bf2f(in[(size_t)(n0 + p) * kC + c]);
        s += v; ss += v * v;
    }
    atomicAdd(&acc[(size_t)(b * kC + c) * 2],     s);
    atomicAdd(&acc[(size_t)(b * kC + c) * 2 + 1], ss);
}

__device__ inline void inorm_ms(const float* acc, int b, int c, float& m, float& rs)
{
    float s  = acc[(size_t)(b * kC + c) * 2];
    float ss = acc[(size_t)(b * kC + c) * 2 + 1];
    m = s * (1.0f / kHW);
    float var = ss * (1.0f / kHW) - m * m;
    rs = rsqrtf(var + kEPS);
}

// MODE 0: gelu(inorm(in)) -> bf16.  MODE 1: gelu(inorm(in)) + add -> bf16.
template<int MODE>
__global__ void apply_pm_kernel(const unsigned short* __restrict__ in, const float* __restrict__ acc,
                                unsigned short* __restrict__ out, const unsigned short* __restrict__ addsrc)
{
    int idx = blockIdx.x * 256 + threadIdx.x;      // kN*48
    int n = idx / 48;
    int c0 = (idx - n * 48) * 4;
    int b = n >> 14;
    f32x4 v = ubf4(*(const unsigned long long*)(in + (size_t)n * kC + c0));
    f32x4 r;
#pragma unroll
    for (int j = 0; j < 4; ++j) {
        float m, rs;
        inorm_ms(acc, b, c0 + j, m, rs);
        float x = (v[j] - m) * rs;
        r[j] = 0.5f * x * (1.0f + erff(x * 0.70710678118654752f));
    }
    if (MODE == 1)
        r += ubf4(*(const unsigned long long*)(addsrc + (size_t)n * kC + c0));
    *(unsigned long long*)(out + (size_t)n * kC + c0) = pk4(r[0], r[1], r[2], r[3]);
}

// ---------------------------------------------------------------------------
// Final inorm via LDS transpose: bf16 pixel-major in -> NCHW fp32 d_out.
// ---------------------------------------------------------------------------
__global__ __launch_bounds__(256) void final_kernel(const unsigned short* __restrict__ in,
                                                    const float* __restrict__ acc,
                                                    float* __restrict__ out)
{
    __shared__ unsigned short tile[192][68];
    int n0 = blockIdx.x * 64;
    int b = n0 >> 14;
    int hw0 = n0 & (kHW - 1);
    int tid = threadIdx.x;
    for (int i = tid; i < 64 * 48; i += 256) {
        int p = i / 48, cq = i - p * 48;
        unsigned long long u = *(const unsigned long long*)(in + (size_t)(n0 + p) * kC + cq * 4);
        tile[cq * 4 + 0][p] = (unsigned short)u;
        tile[cq * 4 + 1][p] = (unsigned short)(u >> 16);
        tile[cq * 4 + 2][p] = (unsigned short)(u >> 32);
        tile[cq * 4 + 3][p] = (unsigned short)(u >> 48);
    }
    __syncthreads();
    for (int i = tid; i < 192 * 16; i += 256) {
        int c = i >> 4, grp = i & 15;
        float m, rs;
        inorm_ms(acc, b, c, m, rs);
        f32x4 o;
#pragma unroll
        for (int j = 0; j < 4; ++j)
            o[j] = (bf2f(tile[c][grp * 4 + j]) - m) * rs;
        *(f32x4*)(out + (size_t)(b * kC + c) * kHW + hw0 + grp * 4) = o;
    }
}

// ---------------------------------------------------------------------------
extern "C" void kernel_launch(void* const* d_in, const int* in_sizes, int n_in,
                              void* d_out, int out_size, void* d_ws, size_t ws_size,
                              hipStream_t stream)
{
    const float* x     = (const float*)d_in[0];
    const float* ln1_g = (const float*)d_in[1];
    const float* ln1_b = (const float*)d_in[2];
    const float* wq    = (const float*)d_in[3];
    const float* wk    = (const float*)d_in[4];
    const float* wv    = (const float*)d_in[5];
    const float* wo    = (const float*)d_in[6];
    const float* bo    = (const float*)d_in[7];
    const float* dw_w  = (const float*)d_in[8];
    const float* dw_b  = (const float*)d_in[9];
    const float* mlp_w = (const float*)d_in[10];
    const float* mlp_b = (const float*)d_in[11];
    const float* ln2_g = (const float*)d_in[12];
    const float* ln2_b = (const float*)d_in[13];
    const float* c1_w  = (const float*)d_in[14];
    const float* c1_b  = (const float*)d_in[15];
    const float* res_w = (const float*)d_in[16];
    const float* res_b = (const float*)d_in[17];
    const float* c2_w  = (const float*)d_in[18];
    const float* c2_b  = (const float*)d_in[19];

    char* base = (char*)d_ws;
    unsigned short* XPb = (unsigned short*)(base);               // bf16 [n][192] raw x
    unsigned short* XNb = (unsigned short*)(base + 25165824);    // bf16 [n][192] xn / Y1
    unsigned short* QPb = (unsigned short*)(base + 37748736);    // bf16 [n][512]; later F / T2
    unsigned short* F   = QPb;
    unsigned short* T2  = QPb;
    unsigned short* KPb = (unsigned short*)(base + 71303168);    // bf16 [n][512]; OB alias; later Y2
    unsigned short* OB  = KPb;
    unsigned short* Y2  = KPb;
    unsigned short* LB  = (unsigned short*)(base + 104857600);   // bf16 [n][192] local; later Y3
    unsigned short* Y3  = LB;
    unsigned short* T1  = (unsigned short*)(base + 117440512);   // bf16 [n][192]; later R
    unsigned short* R   = T1;
    char* sm = base + 130023424;
    float* qpart  = (float*)(sm);                 sm += 524288;   // [16][128][64]
    float* ksum_h = (float*)(sm);                 sm += 524288;
    float* ksum_w = (float*)(sm);                 sm += 524288;
    float* acc0   = (float*)(sm);                 sm += 3072;
    float* acc1   = (float*)(sm);                 sm += 3072;
    float* acc2   = (float*)(sm);                 sm += 3072;
    unsigned short* kf   = (unsigned short*)(sm); sm += 524288;
    unsigned short* vfT  = (unsigned short*)(sm); sm += 524288;
    unsigned short* wqb  = (unsigned short*)(sm); sm += 196608;
    unsigned short* wkb  = (unsigned short*)(sm); sm += 196608;
    unsigned short* mlpb1= (unsigned short*)(sm); sm += 73728;
    unsigned short* c1b  = (unsigned short*)(sm); sm += 73728;
    unsigned short* c2b  = (unsigned short*)(sm); sm += 73728;
    unsigned short* w2pb = (unsigned short*)(sm); sm += 196608;
    float* bp2 = (float*)(sm);                    sm += 1024;
    int* hidx = (int*)(sm);                       sm += 1024;
    int* widx = (int*)(sm);

    // --- prep ---
    prep_kernel<<<1209, 256, 0, stream>>>(acc0, wq, wk, mlp_w, c1_w, c2_w,
                                          wqb, wkb, mlpb1, c1b, c2b);
    wfuse_kernel<<<384, 256, 0, stream>>>(mlp_w, wo, mlp_b, bo, w2pb, bp2);
    txln_kernel<<<dim3(kHW / 64, kB), 256, 0, stream>>>(x, XPb, XNb, ln1_g, ln1_b);

    // --- attention branch ---
    mgemm_l2_kernel<<<dim3(kN / 128, kNH), 256, 0, stream>>>(wqb, XNb, QPb, qpart);
    mgemm_l2_kernel<<<dim3(kN / 128, kNH), 256, 0, stream>>>(wkb, XNb, KPb, ksum_h);
    sum_h_kernel<<<dim3(kW, 16), 256, 0, stream>>>(KPb, ksum_w);
    score_topk_kernel<<<16, 128, 0, stream>>>(qpart, ksum_h, ksum_w, hidx, widx);
    gather_kv_kernel<<<dim3(kP, 16), 256, 0, stream>>>(KPb, XNb, wv, hidx, widx, kf, vfT);
    attn_kernel<<<dim3(kHW / 64, 16), 256, 0, stream>>>(QPb, OB, kf, vfT);

    // --- local branch + fused mlp (wo folded in) ---
    dwconv_pm_kernel<<<(kN * 48) / 256, 256, 0, stream>>>(XPb, LB, dw_w, dw_b);
    mgemm_mlp_kernel<<<dim3(kN / 128, kC / 64), 256, 0, stream>>>(mlpb1, LB, w2pb, OB, F, bp2, XPb);

    // --- tail ---
    ln_pm_bf16_kernel<<<(kN * 4) / 256, 256, 0, stream>>>(F, XNb, ln2_g, ln2_b);   // Y1 = XNb
    mgemm_is_kernel<<<dim3(kN / 128, kC / 64), 256, 0, stream>>>(c1b, XNb, T1, c1_b, acc0);
    apply_pm_kernel<0><<<(kN * 48) / 256, 256, 0, stream>>>(T1, acc0, Y2, nullptr);
    dwconv_pm_kernel<<<(kN * 48) / 256, 256, 0, stream>>>(Y2, R, res_w, res_b);
    istats_bf16_kernel<<<kN / 64, 192, 0, stream>>>(R, acc1);
    apply_pm_kernel<1><<<(kN * 48) / 256, 256, 0, stream>>>(R, acc1, Y3, Y2);
    mgemm_is_kernel<<<dim3(kN / 128, kC / 64), 256, 0, stream>>>(c2b, Y3, T2, c2_b, acc2);
    final_kernel<<<kN / 64, 256, 0, stream>>>(T2, acc2, (float*)d_out);
}